// Round 1
// 806.254 us; speedup vs baseline: 1.0102x; 1.0102x over previous
//
#include <hip/hip_runtime.h>

// ---------------------------------------------------------------------------
// GeoRegionSampler: restructured pipeline
//   X = [bilinear_fea | pts] (bf16, padded 1026->1056); bilinear fused with
//   fmap channel-tile staging in LDS.
//   Wcomb = Wa1 @ Wd   (bf16 MFMA GEMM)
//   Z1 = X @ Wcomb^T ; Z2 = X[fi] @ Wa2^T ; czero = b_diff@Wa1^T + b_agg
//   h[b,s,k] = relu(Z1[idx]-Z1[fi]+Z2[s]+czero) -> LN -> mean_k  (fused;
//   emits fea2 as bf16)
//   final MLP: MFMA GEMMs streaming W as fp32 via global_load_lds (XOR-
//   swizzled LDS) with in-register fp32->bf16 convert; K-split partials +
//   reduce kernels.
// FPS/kNN: fp32 bit-exact (fp contract off), first-index tie-break.
// R5: fps_kernel was the #1 dispatch (99.7us) with a per-iteration serial
//   global store (fi) + dependent global load (centroid) forcing a
//   vmcnt(0) drain on the 128-step chain. Now the butterfly argmax carries
//   the winning point's coords in-register (extra shuffles are latency-free,
//   they pipeline with the bv/bi shuffles) and fi is buffered in registers
//   (statically-indexed hist[]) and stored once at the end. Loop body is
//   pure VALU+ds_swizzle.
// ---------------------------------------------------------------------------

typedef float f32x4 __attribute__((ext_vector_type(4)));
typedef short bf16x8 __attribute__((ext_vector_type(8)));
typedef unsigned short u16;
typedef u16 u16x4 __attribute__((ext_vector_type(4)));
typedef unsigned int u32;
typedef u32 u32x4 __attribute__((ext_vector_type(4)));

typedef const void __attribute__((address_space(1)))* gvp;
typedef void __attribute__((address_space(3)))* svp;

__device__ __forceinline__ u16 f2bf(float f) {
  union { float f; u32 u; } x; x.f = f;
  u32 r = x.u + 0x7fffu + ((x.u >> 16) & 1u);
  return (u16)(r >> 16);
}

#define KP 1056   // padded Dp (1026 -> 33*32)
#define NP0 1152  // padded N for weight-combine GEMM (9*128)

// ------- fused bilinear: stage fmap[b][ct*32..+31][:] in LDS, interp -------
__global__ __launch_bounds__(256, 2) void bilinear_fused_kernel(const float* __restrict__ fmap,
                                                                const float* __restrict__ pts,
                                                                u16* __restrict__ X) {
  __shared__ float fmS[32][580];
  const int ct = blockIdx.x, b = blockIdx.y;
  const int t = threadIdx.x;
  const float* src = fmap + ((size_t)b * 1024 + ct * 32) * 576;
  const int tr = t >> 3, ti = t & 7;
  #pragma unroll
  for (int j = 0; j < 18; ++j) {
    int c4 = j * 8 + ti;
    *(f32x4*)&fmS[tr][c4 * 4] = *(const f32x4*)(src + (size_t)tr * 576 + c4 * 4);
  }
  __syncthreads();
  #pragma unroll
  for (int pass = 0; pass < 2; ++pass) {
    const int n = pass * 256 + t;
    const int pidx = b * 512 + n;
    float p0 = pts[(size_t)pidx * 2], p1 = pts[(size_t)pidx * 2 + 1];
    float gy = p0 * 23.f, gx = p1 * 23.f;
    float y0f = floorf(gy), x0f = floorf(gx);
    float wy = gy - y0f, wx = gx - x0f;
    int y0 = (int)y0f; y0 = y0 < 0 ? 0 : (y0 > 23 ? 23 : y0);
    int x0 = (int)x0f; x0 = x0 < 0 ? 0 : (x0 > 23 ? 23 : x0);
    int y1 = y0 + 1 > 23 ? 23 : y0 + 1;
    int x1 = x0 + 1 > 23 ? 23 : x0 + 1;
    float w00 = (1.f - wy) * (1.f - wx), w01 = (1.f - wy) * wx;
    float w10 = wy * (1.f - wx), w11 = wy * wx;
    const int i00 = y0 * 24 + x0, i01 = y0 * 24 + x1;
    const int i10 = y1 * 24 + x0, i11 = y1 * 24 + x1;
    size_t ro = (size_t)pidx * KP + ct * 32;
    #pragma unroll
    for (int cq = 0; cq < 8; ++cq) {
      u16x4 o4;
      #pragma unroll
      for (int cc = 0; cc < 4; ++cc) {
        int c = cq * 4 + cc;
        float v = w00 * fmS[c][i00] + w01 * fmS[c][i01] +
                  w10 * fmS[c][i10] + w11 * fmS[c][i11];
        o4[cc] = f2bf(v);
      }
      *(u16x4*)(X + ro + cq * 4) = o4;
    }
    if (ct == 31) {
      size_t rb = (size_t)pidx * KP;
      X[rb + 1024] = f2bf(p0);
      X[rb + 1025] = f2bf(p1);
      #pragma unroll
      for (int z = 0; z < 15; ++z) ((u32*)(X + rb + 1026))[z] = 0;
    }
  }
}

// ---------------- FPS: one wave per batch, bit-exact ------------------------
// Serial-chain optimized: no global memory ops inside the S-loop.
//  - centroid coords ride along the butterfly argmax (bx,by shuffles are
//    independent of bv/bi shuffles -> same per-step latency)
//  - fi[] buffered in statically-indexed hist[] registers, stored at end
template <int PPL, int HS>
__global__ void fps_kernel(const float* __restrict__ pts, int* __restrict__ fi,
                           int Np, int S) {
  #pragma clang fp contract(off)
  int b = blockIdx.x;
  int lane = threadIdx.x;
  float px[PPL], py[PPL], dist[PPL];
  #pragma unroll
  for (int j = 0; j < PPL; ++j) {
    int n = j * 64 + lane;
    px[j] = pts[((size_t)b * Np + n) * 2];
    py[j] = pts[((size_t)b * Np + n) * 2 + 1];
    dist[j] = 1e10f;
  }
  int hist[HS];
  #pragma unroll
  for (int h = 0; h < HS; ++h) hist[h] = 0;
  int far = 0;
  float cx = __shfl(px[0], 0);
  float cy = __shfl(py[0], 0);
  for (int s = 0; s < S; ++s) {
    // record current far (static hist index per rule #20)
    #pragma unroll
    for (int h = 0; h < HS; ++h)
      if ((s >> 6) == h && (s & 63) == lane) hist[h] = far;
    float bv = -1.f; int bi = 0; float bx = 0.f, by = 0.f;
    #pragma unroll
    for (int j = 0; j < PPL; ++j) {
      float dx = px[j] - cx, dy = py[j] - cy;
      float d = dx * dx + dy * dy;
      float nd = fminf(dist[j], d);
      dist[j] = nd;
      if (nd > bv) { bv = nd; bi = j * 64 + lane; bx = px[j]; by = py[j]; }
    }
    #pragma unroll
    for (int off = 32; off; off >>= 1) {
      float ov = __shfl_xor(bv, off);
      int oi = __shfl_xor(bi, off);
      float ox = __shfl_xor(bx, off);
      float oy = __shfl_xor(by, off);
      if (ov > bv || (ov == bv && oi < bi)) { bv = ov; bi = oi; bx = ox; by = oy; }
    }
    far = bi; cx = bx; cy = by;
  }
  #pragma unroll
  for (int h = 0; h < HS; ++h) {
    int s = h * 64 + lane;
    if (s < S) fi[b * S + s] = hist[h];
  }
}

// ---------------- kNN: one wave per (b,s), bit-exact ------------------------
template <int PPL>
__global__ __launch_bounds__(256) void knn_kernel(const float* __restrict__ qpts,
                                                  const float* __restrict__ rpts,
                                                  int* __restrict__ idxK, int Np, int S) {
  #pragma clang fp contract(off)
  int lane = threadIdx.x & 63, wv = threadIdx.x >> 6;
  int q = blockIdx.x * 4 + wv;
  int b = q / S;
  float ax = qpts[(size_t)q * 2], ay = qpts[(size_t)q * 2 + 1];
  float a2 = ax * ax + ay * ay;
  float d2[PPL];
  #pragma unroll
  for (int j = 0; j < PPL; ++j) {
    int n = j * 64 + lane;
    float bx = rpts[((size_t)b * Np + n) * 2];
    float by = rpts[((size_t)b * Np + n) * 2 + 1];
    float b2 = bx * bx + by * by;
    float dot = ax * bx + ay * by;
    float t = a2 + b2;
    float m2 = 2.f * dot;
    d2[j] = t - m2;
  }
  for (int k = 0; k < 24; ++k) {
    float bv = 3.4e38f; int bi = 1 << 30;
    #pragma unroll
    for (int j = 0; j < PPL; ++j)
      if (d2[j] < bv) { bv = d2[j]; bi = j * 64 + lane; }
    #pragma unroll
    for (int off = 32; off; off >>= 1) {
      float ov = __shfl_xor(bv, off);
      int oi = __shfl_xor(bi, off);
      if (ov < bv || (ov == bv && oi < bi)) { bv = ov; bi = oi; }
    }
    if (lane == 0) idxK[(size_t)q * 24 + k] = bi;
    #pragma unroll
    for (int j = 0; j < PPL; ++j)
      if (j * 64 + lane == bi) d2[j] = 3.4e38f;
  }
}

// ---------------- gather X rows at fi; emit new_pts -------------------------
__global__ __launch_bounds__(128) void gather_fi_kernel(const u16* __restrict__ Xsrc,
                                                        const float* __restrict__ pts,
                                                        const int* __restrict__ fi,
                                                        u16* __restrict__ Xg,
                                                        float* __restrict__ npts,
                                                        int Np, int S) {
  int q = blockIdx.x;
  int b = q / S;
  int t = threadIdx.x;
  int r = fi[q];
  const u32x4* src = (const u32x4*)(Xsrc + ((size_t)b * Np + r) * KP);
  u32x4* dst = (u32x4*)(Xg + (size_t)q * KP);
  dst[t] = src[t];
  int t2 = t + 128;
  if (t2 < 132) dst[t2] = src[t2];
  if (t == 0) {
    npts[(size_t)q * 2] = pts[((size_t)b * Np + r) * 2];
    npts[(size_t)q * 2 + 1] = pts[((size_t)b * Np + r) * 2 + 1];
  }
}

// ---------------- weight prep ----------------------------------------------
__global__ __launch_bounds__(256) void wd_transpose_kernel(const float* __restrict__ Wd,
                                                           u16* __restrict__ WdT) {
  __shared__ float tbuf[32][33];
  int tx = threadIdx.x & 31, ty = threadIdx.x >> 5;
  int ot = blockIdx.x * 32, dt = blockIdx.y * 32;
  #pragma unroll
  for (int j = 0; j < 4; ++j) {
    int o = ot + ty + 8 * j, d = dt + tx;
    tbuf[ty + 8 * j][tx] = (o < 1026 && d < 1026) ? Wd[(size_t)o * 1026 + d] : 0.f;
  }
  __syncthreads();
  #pragma unroll
  for (int j = 0; j < 4; ++j) {
    int d = dt + ty + 8 * j, o = ot + tx;
    if (o < KP) WdT[(size_t)d * KP + o] = f2bf(tbuf[tx][ty + 8 * j]);
  }
}

__global__ __launch_bounds__(256) void wagg_convert_kernel(const float* __restrict__ Wagg,
                                                           u16* __restrict__ Wa1,
                                                           u16* __restrict__ Wa2) {
  int c = blockIdx.x, t = threadIdx.x;
  const float* row = Wagg + (size_t)c * 2052;
  for (int d = t; d < KP; d += 256) {
    Wa1[(size_t)c * KP + d] = (d < 1026) ? f2bf(row[d]) : (u16)0;
    Wa2[(size_t)c * KP + d] = (d < 1026) ? f2bf(row[1026 + d]) : (u16)0;
  }
}

__global__ __launch_bounds__(256) void czero_kernel(const float* __restrict__ bdiff,
                                                    const float* __restrict__ Wagg,
                                                    const float* __restrict__ bagg,
                                                    float* __restrict__ czero) {
  int lane = threadIdx.x & 63, wv = threadIdx.x >> 6;
  int c = blockIdx.x * 4 + wv;
  float acc = 0.f;
  for (int o = lane; o < 1026; o += 64) acc += bdiff[o] * Wagg[(size_t)c * 2052 + o];
  #pragma unroll
  for (int off = 32; off; off >>= 1) acc += __shfl_xor(acc, off);
  if (lane == 0) czero[c] = acc + bagg[c];
}

// ---------------- bf16 MFMA GEMM: C[M,N] = A[M,K] @ Bt[N,K]^T ---------------
template <int BF16OUT>
__global__ __launch_bounds__(256) void gemm_bt_kernel(const u16* __restrict__ A,
                                                      const u16* __restrict__ Bt,
                                                      void* __restrict__ Cout,
                                                      int M, int N, int K, int ldc, int nvalid) {
  __shared__ __align__(16) u16 As[128 * 32];
  __shared__ __align__(16) u16 Bs[128 * 32];
  const int tid = threadIdx.x;
  const int lane = tid & 63;
  const int wv = tid >> 6;
  const int m0 = blockIdx.y * 128;
  const int n0 = blockIdx.x * 128;
  const int wm = (wv >> 1) * 64;
  const int wn = (wv & 1) * 64;

  f32x4 acc[4][4];
  #pragma unroll
  for (int i = 0; i < 4; ++i)
    #pragma unroll
    for (int j = 0; j < 4; ++j)
      #pragma unroll
      for (int c = 0; c < 4; ++c) acc[i][j][c] = 0.f;

  const int ch0 = wv * 2;
  const int rin = lane >> 2;
  const int cin = (lane & 3) * 8;

  for (int k0 = 0; k0 < K; k0 += 32) {
    #pragma unroll
    for (int i = 0; i < 2; ++i) {
      const int ch = ch0 + i;
      const int row = ch * 16 + rin;
      const u16* ga = A + (size_t)(m0 + row) * K + (k0 + cin);
      const u16* gb = Bt + (size_t)(n0 + row) * K + (k0 + cin);
      __builtin_amdgcn_global_load_lds((gvp)ga, (svp)(As + ch * 512), 16, 0, 0);
      __builtin_amdgcn_global_load_lds((gvp)gb, (svp)(Bs + ch * 512), 16, 0, 0);
    }
    __syncthreads();
    const int rf = lane & 15;
    const int qf = (lane >> 4) * 8;
    bf16x8 af[4], bfv[4];
    #pragma unroll
    for (int mi = 0; mi < 4; ++mi)
      af[mi] = *(const bf16x8*)(As + (wm + mi * 16 + rf) * 32 + qf);
    #pragma unroll
    for (int ni = 0; ni < 4; ++ni)
      bfv[ni] = *(const bf16x8*)(Bs + (wn + ni * 16 + rf) * 32 + qf);
    #pragma unroll
    for (int mi = 0; mi < 4; ++mi)
      #pragma unroll
      for (int ni = 0; ni < 4; ++ni)
        acc[mi][ni] = __builtin_amdgcn_mfma_f32_16x16x32_bf16(af[mi], bfv[ni], acc[mi][ni], 0, 0, 0);
    __syncthreads();
  }

  const int rq = (lane >> 4) * 4;
  const int cf = lane & 15;
  #pragma unroll
  for (int mi = 0; mi < 4; ++mi) {
    #pragma unroll
    for (int ni = 0; ni < 4; ++ni) {
      const int col = n0 + wn + ni * 16 + cf;
      #pragma unroll
      for (int r = 0; r < 4; ++r) {
        const int row = m0 + wm + mi * 16 + rq + r;
        const float v = acc[mi][ni][r];
        if (BF16OUT) {
          if (col < nvalid) ((u16*)Cout)[(size_t)row * ldc + col] = f2bf(v);
        } else {
          ((float*)Cout)[(size_t)row * ldc + col] = v;
        }
      }
    }
  }
}

// ---------------- fused gather + relu + LN + mean_k -------------------------
// MODE 0: bf16 X-row output (KP stride, pts tail)   MODE 1: bf16 flat 1024
template <int MODE>
__global__ __launch_bounds__(256) void h_epilogue_kernel(const float* __restrict__ Z1,
                                                         const float* __restrict__ Z2g,
                                                         const float* __restrict__ czero,
                                                         const int* __restrict__ idxK,
                                                         const int* __restrict__ fi,
                                                         const float* __restrict__ g,
                                                         const float* __restrict__ bb,
                                                         const float* __restrict__ npts,
                                                         void* __restrict__ outp,
                                                         int Np, int S) {
  __shared__ float r1[4];
  __shared__ float r2[4];
  int q = blockIdx.x;
  int b = q / S;
  int t = threadIdx.x;
  int lane = t & 63, wv = t >> 6;
  int fiv = fi[q];
  const f32x4* z2 = (const f32x4*)(Z2g + (size_t)q * 1024);
  const f32x4* zf = (const f32x4*)(Z1 + ((size_t)b * Np + fiv) * 1024);
  const f32x4* cz = (const f32x4*)czero;
  f32x4 base = z2[t] + cz[t] - zf[t];
  f32x4 gv = ((const f32x4*)g)[t];
  f32x4 bv = ((const f32x4*)bb)[t];
  f32x4 acc;
  #pragma unroll
  for (int c = 0; c < 4; ++c) acc[c] = 0.f;
  for (int k = 0; k < 24; ++k) {
    int n = idxK[(size_t)q * 24 + k];
    const f32x4* zr = (const f32x4*)(Z1 + ((size_t)b * Np + n) * 1024);
    f32x4 v = zr[t] + base;
    #pragma unroll
    for (int c = 0; c < 4; ++c) v[c] = fmaxf(v[c], 0.f);
    float s1 = v[0] + v[1] + v[2] + v[3];
    float s2 = v[0] * v[0] + v[1] * v[1] + v[2] * v[2] + v[3] * v[3];
    #pragma unroll
    for (int off = 32; off; off >>= 1) {
      s1 += __shfl_xor(s1, off);
      s2 += __shfl_xor(s2, off);
    }
    if (lane == 0) { r1[wv] = s1; r2[wv] = s2; }
    __syncthreads();
    s1 = r1[0] + r1[1] + r1[2] + r1[3];
    s2 = r2[0] + r2[1] + r2[2] + r2[3];
    __syncthreads();
    float m = s1 * (1.f / 1024.f);
    float var = s2 * (1.f / 1024.f) - m * m;
    float rs = rsqrtf(var + 1e-5f);
    #pragma unroll
    for (int c = 0; c < 4; ++c) acc[c] += (v[c] - m) * rs * gv[c] + bv[c];
  }
  #pragma unroll
  for (int c = 0; c < 4; ++c) acc[c] *= (1.f / 24.f);
  u16x4 o4;
  #pragma unroll
  for (int c = 0; c < 4; ++c) o4[c] = f2bf(acc[c]);
  if (MODE == 0) {
    u16* X = (u16*)outp;
    size_t ro = (size_t)q * KP;
    *(u16x4*)(X + ro + t * 4) = o4;
    if (t == 0) {
      X[ro + 1024] = f2bf(npts[(size_t)q * 2]);
      X[ro + 1025] = f2bf(npts[(size_t)q * 2 + 1]);
    }
    if (t < 15) ((u32*)(X + ro + 1026))[t] = 0;
  } else {
    *(u16x4*)((u16*)outp + (size_t)q * 1024 + t * 4) = o4;
  }
}

// ---------------- MLP MFMA GEMM: P[blk] = W_tile(fp32->bf16) @ Fb^T ---------
// W fp32 [M,K]; Fb bf16 [32,K]; grid = (M/128) << KSBITS blocks.
// A staged via global_load_lds (XOR-swizzled 16B groups, conflict-free);
// converted to bf16 fragments in-register. Partials P[blk][128][32] fp32.
template <int KSBITS, int NST>
__global__ __launch_bounds__(256, 4) void mlp_mfma_kernel(const float* __restrict__ W,
                                                          const u16* __restrict__ Fb,
                                                          float* __restrict__ P, int K) {
  __shared__ __align__(16) float Asf[128 * 32];
  __shared__ __align__(16) u16 Fsb[32 * 40];
  const int tid = threadIdx.x, lane = tid & 63, wv = tid >> 6;
  const int ot = blockIdx.x >> KSBITS;
  const int ks = blockIdx.x & ((1 << KSBITS) - 1);
  const int m0 = ot * 128;
  const int k0b = ks * (NST * 32);
  const int arow = lane >> 3;
  const int agrp = lane & 7;
  const int rf = lane & 15, quad = lane >> 4;

  f32x4 acc[2][2];
  #pragma unroll
  for (int i = 0; i < 2; ++i)
    #pragma unroll
    for (int j = 0; j < 2; ++j)
      #pragma unroll
      for (int c = 0; c < 4; ++c) acc[i][j][c] = 0.f;

  for (int st = 0; st < NST; ++st) {
    const int k0 = k0b + st * 32;
    #pragma unroll
    for (int i = 0; i < 4; ++i) {
      const int row = wv * 32 + i * 8 + arow;
      const int g = agrp ^ (row & 7);
      const float* ga = W + (size_t)(m0 + row) * K + k0 + g * 4;
      __builtin_amdgcn_global_load_lds((gvp)ga, (svp)(Asf + (wv * 32 + i * 8) * 32), 16, 0, 0);
    }
    if (tid < 128) {
      const int fr = tid >> 2, fc = (tid & 3) * 8;
      u32x4 tmp = *(const u32x4*)(Fb + (size_t)fr * K + k0 + fc);
      *(u32x4*)(Fsb + fr * 40 + fc) = tmp;
    }
    __syncthreads();
    bf16x8 bfr[2];
    #pragma unroll
    for (int ni = 0; ni < 2; ++ni)
      bfr[ni] = *(const bf16x8*)(Fsb + (ni * 16 + rf) * 40 + quad * 8);
    #pragma unroll
    for (int mi = 0; mi < 2; ++mi) {
      const float* ap = Asf + (size_t)(wv * 32 + mi * 16 + rf) * 32;
      f32x4 a0 = *(const f32x4*)(ap + (((quad * 2) ^ (rf & 7)) * 4));
      f32x4 a1 = *(const f32x4*)(ap + (((quad * 2 + 1) ^ (rf & 7)) * 4));
      union { bf16x8 v; u16 h[8]; } af;
      #pragma unroll
      for (int c = 0; c < 4; ++c) { af.h[c] = f2bf(a0[c]); af.h[4 + c] = f2bf(a1[c]); }
      #pragma unroll
      for (int ni = 0; ni < 2; ++ni)
        acc[mi][ni] = __builtin_amdgcn_mfma_f32_16x16x32_bf16(af.v, bfr[ni], acc[mi][ni], 0, 0, 0);
    }
    __syncthreads();
  }

  float* Pb = P + (size_t)blockIdx.x * 4096;
  const int rq = (lane >> 4) * 4, cf = lane & 15;
  #pragma unroll
  for (int mi = 0; mi < 2; ++mi)
    #pragma unroll
    for (int ni = 0; ni < 2; ++ni)
      #pragma unroll
      for (int r = 0; r < 4; ++r)
        Pb[(wv * 32 + mi * 16 + rq + r) * 32 + ni * 16 + cf] = acc[mi][ni][r];
}

// ---------------- K-split partial reductions (bias fused) -------------------
__global__ __launch_bounds__(256) void reduce_flat_kernel(const float* __restrict__ P,
                                                          const float* __restrict__ bias,
                                                          u16* __restrict__ x1bf) {
  int idx = blockIdx.x * 256 + threadIdx.x;  // 32768
  int o = idx >> 5, b = idx & 31;
  float s = bias[o];
  const float* p = P + ((size_t)(o >> 7) * 64) * 4096 + (o & 127) * 32 + b;
  #pragma unroll 8
  for (int ks = 0; ks < 64; ++ks) s += p[(size_t)ks * 4096];
  x1bf[(size_t)b * 1024 + o] = f2bf(s);
}

__global__ __launch_bounds__(256) void reduce_dim_kernel(const float* __restrict__ P,
                                                         const float* __restrict__ bias,
                                                         float* __restrict__ out) {
  int idx = blockIdx.x * 256 + threadIdx.x;  // 131072
  int o = idx >> 5, b = idx & 31;
  float s = bias[o];
  const float* p = P + ((size_t)(o >> 7) * 8) * 4096 + (o & 127) * 32 + b;
  #pragma unroll
  for (int ks = 0; ks < 8; ++ks) s += p[(size_t)ks * 4096];
  out[(size_t)b * 4096 + o] = s;
}

// ---------------------------------------------------------------------------
extern "C" void kernel_launch(void* const* d_in, const int* in_sizes, int n_in,
                              void* d_out, int out_size, void* d_ws, size_t ws_size,
                              hipStream_t stream) {
  const float* fmap  = (const float*)d_in[0];
  const float* pts   = (const float*)d_in[1];
  const float* Wdiff = (const float*)d_in[2];
  const float* bdiff = (const float*)d_in[3];
  const float* Wagg  = (const float*)d_in[4];
  const float* bagg  = (const float*)d_in[5];
  const float* lng   = (const float*)d_in[6];
  const float* lnb   = (const float*)d_in[7];
  const float* Wflat = (const float*)d_in[8];
  const float* bflat = (const float*)d_in[9];
  const float* Wdim  = (const float*)d_in[10];
  const float* bdim  = (const float*)d_in[11];
  float* out = (float*)d_out;

  char* w = (char*)d_ws;
  size_t off = 0;
  auto alloc = [&](size_t n) { char* p = w + off; off += (n + 255) & ~(size_t)255; return p; };

  float* Z1    = (float*)alloc(16384ull * 1024 * 4);  // 67.1 MB
  float* Z2g   = (float*)alloc(4096ull * 1024 * 4);   // 16.8 MB
  u16* Xbf0  = (u16*)alloc(16384ull * KP * 2);
  u16* X1bf  = (u16*)alloc(4096ull * KP * 2);
  u16* Xg    = (u16*)alloc(4096ull * KP * 2);
  u16* WdT   = (u16*)alloc((size_t)NP0 * KP * 2);
  u16* Wa1   = (u16*)alloc(1024ull * KP * 2);
  u16* Wa2   = (u16*)alloc(1024ull * KP * 2);
  u16* Wcomb = (u16*)alloc(1024ull * KP * 2);
  float* czero = (float*)alloc(1024 * 4);
  int* fi0   = (int*)alloc(32 * 128 * 4);
  int* fi1   = (int*)alloc(32 * 32 * 4);
  int* idx0  = (int*)alloc(32 * 128 * 24 * 4);
  int* idx1  = (int*)alloc(32 * 32 * 24 * 4);
  float* npts0 = (float*)alloc(32 * 128 * 2 * 4);
  float* npts1 = (float*)alloc(32 * 32 * 2 * 4);
  u16* fea2bf = (u16*)alloc(32ull * 32768 * 2);       // 2 MB bf16
  u16* x1bf   = (u16*)alloc(32ull * 1024 * 2);        // 64 KB bf16
  float* Pf   = (float*)alloc(512ull * 4096 * 4);     // 8 MB partials (flat)
  float* Pd   = (float*)alloc(256ull * 4096 * 4);     // 4 MB partials (dim)

  // ---- stage-0 inputs
  bilinear_fused_kernel<<<dim3(32, 32), 256, 0, stream>>>(fmap, pts, Xbf0);

  // ---- stage 0 (Np=512, S=128)
  fps_kernel<8, 2><<<32, 64, 0, stream>>>(pts, fi0, 512, 128);
  gather_fi_kernel<<<4096, 128, 0, stream>>>(Xbf0, pts, fi0, Xg, npts0, 512, 128);
  knn_kernel<8><<<1024, 256, 0, stream>>>(npts0, pts, idx0, 512, 128);
  wd_transpose_kernel<<<dim3(33, 36), 256, 0, stream>>>(Wdiff, WdT);
  wagg_convert_kernel<<<1024, 256, 0, stream>>>(Wagg, Wa1, Wa2);
  czero_kernel<<<256, 256, 0, stream>>>(bdiff, Wagg, bagg, czero);
  gemm_bt_kernel<1><<<dim3(9, 8), 256, 0, stream>>>(Wa1, WdT, Wcomb, 1024, NP0, KP, KP, KP);
  gemm_bt_kernel<0><<<dim3(8, 128), 256, 0, stream>>>(Xbf0, Wcomb, Z1, 16384, 1024, KP, 1024, 1024);
  gemm_bt_kernel<0><<<dim3(8, 32), 256, 0, stream>>>(Xg, Wa2, Z2g, 4096, 1024, KP, 1024, 1024);
  h_epilogue_kernel<0><<<4096, 256, 0, stream>>>(Z1, Z2g, czero, idx0, fi0, lng, lnb, npts0,
                                                 X1bf, 512, 128);

  // ---- stage 1 (Np=128, S=32)
  fps_kernel<2, 1><<<32, 64, 0, stream>>>(npts0, fi1, 128, 32);
  gather_fi_kernel<<<1024, 128, 0, stream>>>(X1bf, npts0, fi1, Xg, npts1, 128, 32);
  knn_kernel<2><<<256, 256, 0, stream>>>(npts1, npts0, idx1, 128, 32);
  wd_transpose_kernel<<<dim3(33, 36), 256, 0, stream>>>(Wdiff + 1026 * 1026, WdT);
  wagg_convert_kernel<<<1024, 256, 0, stream>>>(Wagg + 1024 * 2052, Wa1, Wa2);
  czero_kernel<<<256, 256, 0, stream>>>(bdiff + 1026, Wagg + 1024 * 2052, bagg + 1024, czero);
  gemm_bt_kernel<1><<<dim3(9, 8), 256, 0, stream>>>(Wa1, WdT, Wcomb, 1024, NP0, KP, KP, KP);
  gemm_bt_kernel<0><<<dim3(8, 32), 256, 0, stream>>>(X1bf, Wcomb, Z1, 4096, 1024, KP, 1024, 1024);
  gemm_bt_kernel<0><<<dim3(8, 8), 256, 0, stream>>>(Xg, Wa2, Z2g, 1024, 1024, KP, 1024, 1024);
  h_epilogue_kernel<1><<<1024, 256, 0, stream>>>(Z1, Z2g, czero, idx1, fi1, lng + 1024, lnb + 1024,
                                                 npts1, fea2bf, 128, 32);

  // ---- final MLP (MFMA, K-split partials + reduce)
  mlp_mfma_kernel<6, 16><<<512, 256, 0, stream>>>(Wflat, fea2bf, Pf, 32768);
  reduce_flat_kernel<<<128, 256, 0, stream>>>(Pf, bflat, x1bf);
  mlp_mfma_kernel<3, 4><<<256, 256, 0, stream>>>(Wdim, x1bf, Pd, 1024);
  reduce_dim_kernel<<<512, 256, 0, stream>>>(Pd, bdim, out);
}

// Round 2
// 792.658 us; speedup vs baseline: 1.0275x; 1.0172x over previous
//
#include <hip/hip_runtime.h>

// ---------------------------------------------------------------------------
// GeoRegionSampler: restructured pipeline
//   X = [bilinear_fea | pts] (bf16, padded 1026->1056); bilinear fused with
//   fmap channel-tile staging in LDS.
//   Wcomb = Wa1 @ Wd   (bf16 MFMA GEMM)
//   Z1 = X @ Wcomb^T ; Z2 = X[fi] @ Wa2^T ; czero = b_diff@Wa1^T + b_agg
//   h[b,s,k] = relu(Z1[idx]-Z1[fi]+Z2[s]+czero) -> LN -> mean_k  (fused;
//   emits fea2 as bf16)
//   final MLP: MFMA GEMMs streaming W as fp32 via global_load_lds (XOR-
//   swizzled LDS) with in-register fp32->bf16 convert; K-split partials +
//   reduce kernels.
// FPS/kNN: fp32 bit-exact (fp contract off), first-index tie-break.
// R6: fps was still #1 (89.6us = 1680 cyc/iter). The 6-step __shfl_xor
//   butterfly runs on the LDS pipe (ds_bpermute ~120+ cyc dependent
//   latency each step). Replaced with DPP reduction (row_shr 1/2/4/8 +
//   row_bcast15/31, identity injected via update_dpp old-operand) -- pure
//   VALU, few cycles/step; result in lane 63, broadcast via v_readlane.
//   Per-lane argmax chain flattened to a pairwise tree. Same (bit-exact)
//   monoid: max value, min index on ties. knn_kernel gets the same DPP
//   argmin treatment + register-buffered idxK output.
// ---------------------------------------------------------------------------

typedef float f32x4 __attribute__((ext_vector_type(4)));
typedef short bf16x8 __attribute__((ext_vector_type(8)));
typedef unsigned short u16;
typedef u16 u16x4 __attribute__((ext_vector_type(4)));
typedef unsigned int u32;
typedef u32 u32x4 __attribute__((ext_vector_type(4)));

typedef const void __attribute__((address_space(1)))* gvp;
typedef void __attribute__((address_space(3)))* svp;

__device__ __forceinline__ u16 f2bf(float f) {
  union { float f; u32 u; } x; x.f = f;
  u32 r = x.u + 0x7fffu + ((x.u >> 16) & 1u);
  return (u16)(r >> 16);
}

#define KP 1056   // padded Dp (1026 -> 33*32)
#define NP0 1152  // padded N for weight-combine GEMM (9*128)

// ---- DPP cross-lane reduction helpers (VALU pipe, not LDS pipe) -----------
// dpp_ctrl: 0x111..0x118 = row_shr 1..8, 0x142 = row_bcast15, 0x143 = row_bcast31
// update_dpp(old, src, ...): lanes with invalid source get `old` (identity).

__device__ __forceinline__ float rl_f(float v, int lane) {
  return __int_as_float(__builtin_amdgcn_readlane(__float_as_int(v), lane));
}

template <int CTRL>
__device__ __forceinline__ void argmax_step(float& bv, int& bi, float& bx, float& by) {
  float ov = __int_as_float(__builtin_amdgcn_update_dpp(
      __float_as_int(-1.0f), __float_as_int(bv), CTRL, 0xf, 0xf, false));
  int oi = __builtin_amdgcn_update_dpp(1 << 30, bi, CTRL, 0xf, 0xf, false);
  float ox = __int_as_float(__builtin_amdgcn_update_dpp(
      0, __float_as_int(bx), CTRL, 0xf, 0xf, false));
  float oy = __int_as_float(__builtin_amdgcn_update_dpp(
      0, __float_as_int(by), CTRL, 0xf, 0xf, false));
  if (ov > bv || (ov == bv && oi < bi)) { bv = ov; bi = oi; bx = ox; by = oy; }
}

template <int CTRL>
__device__ __forceinline__ void argmin_step(float& bv, int& bi) {
  float ov = __int_as_float(__builtin_amdgcn_update_dpp(
      0x7F7FFFFF /* FLT_MAX bits */, __float_as_int(bv), CTRL, 0xf, 0xf, false));
  int oi = __builtin_amdgcn_update_dpp(1 << 30, bi, CTRL, 0xf, 0xf, false);
  if (ov < bv || (ov == bv && oi < bi)) { bv = ov; bi = oi; }
}

// ------- fused bilinear: stage fmap[b][ct*32..+31][:] in LDS, interp -------
__global__ __launch_bounds__(256, 2) void bilinear_fused_kernel(const float* __restrict__ fmap,
                                                                const float* __restrict__ pts,
                                                                u16* __restrict__ X) {
  __shared__ float fmS[32][580];
  const int ct = blockIdx.x, b = blockIdx.y;
  const int t = threadIdx.x;
  const float* src = fmap + ((size_t)b * 1024 + ct * 32) * 576;
  const int tr = t >> 3, ti = t & 7;
  #pragma unroll
  for (int j = 0; j < 18; ++j) {
    int c4 = j * 8 + ti;
    *(f32x4*)&fmS[tr][c4 * 4] = *(const f32x4*)(src + (size_t)tr * 576 + c4 * 4);
  }
  __syncthreads();
  #pragma unroll
  for (int pass = 0; pass < 2; ++pass) {
    const int n = pass * 256 + t;
    const int pidx = b * 512 + n;
    float p0 = pts[(size_t)pidx * 2], p1 = pts[(size_t)pidx * 2 + 1];
    float gy = p0 * 23.f, gx = p1 * 23.f;
    float y0f = floorf(gy), x0f = floorf(gx);
    float wy = gy - y0f, wx = gx - x0f;
    int y0 = (int)y0f; y0 = y0 < 0 ? 0 : (y0 > 23 ? 23 : y0);
    int x0 = (int)x0f; x0 = x0 < 0 ? 0 : (x0 > 23 ? 23 : x0);
    int y1 = y0 + 1 > 23 ? 23 : y0 + 1;
    int x1 = x0 + 1 > 23 ? 23 : x0 + 1;
    float w00 = (1.f - wy) * (1.f - wx), w01 = (1.f - wy) * wx;
    float w10 = wy * (1.f - wx), w11 = wy * wx;
    const int i00 = y0 * 24 + x0, i01 = y0 * 24 + x1;
    const int i10 = y1 * 24 + x0, i11 = y1 * 24 + x1;
    size_t ro = (size_t)pidx * KP + ct * 32;
    #pragma unroll
    for (int cq = 0; cq < 8; ++cq) {
      u16x4 o4;
      #pragma unroll
      for (int cc = 0; cc < 4; ++cc) {
        int c = cq * 4 + cc;
        float v = w00 * fmS[c][i00] + w01 * fmS[c][i01] +
                  w10 * fmS[c][i10] + w11 * fmS[c][i11];
        o4[cc] = f2bf(v);
      }
      *(u16x4*)(X + ro + cq * 4) = o4;
    }
    if (ct == 31) {
      size_t rb = (size_t)pidx * KP;
      X[rb + 1024] = f2bf(p0);
      X[rb + 1025] = f2bf(p1);
      #pragma unroll
      for (int z = 0; z < 15; ++z) ((u32*)(X + rb + 1026))[z] = 0;
    }
  }
}

// ---------------- FPS: one wave per batch, bit-exact ------------------------
// No global memory ops inside the S-loop; cross-lane argmax via DPP (VALU),
// result broadcast via readlane; fi buffered in registers.
template <int PPL, int HS>
__global__ void fps_kernel(const float* __restrict__ pts, int* __restrict__ fi,
                           int Np, int S) {
  #pragma clang fp contract(off)
  int b = blockIdx.x;
  int lane = threadIdx.x;
  float px[PPL], py[PPL], dist[PPL];
  #pragma unroll
  for (int j = 0; j < PPL; ++j) {
    int n = j * 64 + lane;
    px[j] = pts[((size_t)b * Np + n) * 2];
    py[j] = pts[((size_t)b * Np + n) * 2 + 1];
    dist[j] = 1e10f;
  }
  int hist[HS];
  #pragma unroll
  for (int h = 0; h < HS; ++h) hist[h] = 0;
  int far = 0;
  float cx = rl_f(px[0], 0);
  float cy = rl_f(py[0], 0);
  for (int s = 0; s < S; ++s) {
    // record current far (static hist index per rule #20)
    #pragma unroll
    for (int h = 0; h < HS; ++h)
      if ((s >> 6) == h && (s & 63) == lane) hist[h] = far;
    // distance update (independent across j)
    float tv[PPL]; int ti[PPL]; float tx[PPL], ty[PPL];
    #pragma unroll
    for (int j = 0; j < PPL; ++j) {
      float dx = px[j] - cx, dy = py[j] - cy;
      float d = dx * dx + dy * dy;
      float nd = fminf(dist[j], d);
      dist[j] = nd;
      tv[j] = nd; ti[j] = j * 64 + lane; tx[j] = px[j]; ty[j] = py[j];
    }
    // lane-local argmax tree (ties -> lower j = lower index; strict >)
    #pragma unroll
    for (int w = PPL; w > 1; w >>= 1)
      #pragma unroll
      for (int j = 0; j < (w >> 1); ++j)
        if (tv[j + (w >> 1)] > tv[j]) {
          tv[j] = tv[j + (w >> 1)]; ti[j] = ti[j + (w >> 1)];
          tx[j] = tx[j + (w >> 1)]; ty[j] = ty[j + (w >> 1)];
        }
    float bv = tv[0]; int bi = ti[0]; float bx = tx[0], by = ty[0];
    // cross-lane reduce: DPP scan, total lands in lane 63
    argmax_step<0x111>(bv, bi, bx, by);  // row_shr:1
    argmax_step<0x112>(bv, bi, bx, by);  // row_shr:2
    argmax_step<0x114>(bv, bi, bx, by);  // row_shr:4
    argmax_step<0x118>(bv, bi, bx, by);  // row_shr:8
    argmax_step<0x142>(bv, bi, bx, by);  // row_bcast15
    argmax_step<0x143>(bv, bi, bx, by);  // row_bcast31
    far = __builtin_amdgcn_readlane(bi, 63);
    cx = rl_f(bx, 63);
    cy = rl_f(by, 63);
  }
  #pragma unroll
  for (int h = 0; h < HS; ++h) {
    int s = h * 64 + lane;
    if (s < S) fi[b * S + s] = hist[h];
  }
}

// ---------------- kNN: one wave per (b,s), bit-exact ------------------------
// DPP argmin per k; idxK buffered in one register (lane-indexed), stored once.
template <int PPL>
__global__ __launch_bounds__(256) void knn_kernel(const float* __restrict__ qpts,
                                                  const float* __restrict__ rpts,
                                                  int* __restrict__ idxK, int Np, int S) {
  #pragma clang fp contract(off)
  int lane = threadIdx.x & 63, wv = threadIdx.x >> 6;
  int q = blockIdx.x * 4 + wv;
  int b = q / S;
  float ax = qpts[(size_t)q * 2], ay = qpts[(size_t)q * 2 + 1];
  float a2 = ax * ax + ay * ay;
  float d2[PPL];
  #pragma unroll
  for (int j = 0; j < PPL; ++j) {
    int n = j * 64 + lane;
    float bx = rpts[((size_t)b * Np + n) * 2];
    float by = rpts[((size_t)b * Np + n) * 2 + 1];
    float b2 = bx * bx + by * by;
    float dot = ax * bx + ay * by;
    float t = a2 + b2;
    float m2 = 2.f * dot;
    d2[j] = t - m2;
  }
  int kreg = 0;
  for (int k = 0; k < 24; ++k) {
    // lane-local argmin tree (ties -> lower j; strict <)
    float tv[PPL]; int ti[PPL];
    #pragma unroll
    for (int j = 0; j < PPL; ++j) { tv[j] = d2[j]; ti[j] = j * 64 + lane; }
    #pragma unroll
    for (int w = PPL; w > 1; w >>= 1)
      #pragma unroll
      for (int j = 0; j < (w >> 1); ++j)
        if (tv[j + (w >> 1)] < tv[j]) {
          tv[j] = tv[j + (w >> 1)]; ti[j] = ti[j + (w >> 1)];
        }
    float bv = tv[0]; int bi = ti[0];
    argmin_step<0x111>(bv, bi);
    argmin_step<0x112>(bv, bi);
    argmin_step<0x114>(bv, bi);
    argmin_step<0x118>(bv, bi);
    argmin_step<0x142>(bv, bi);
    argmin_step<0x143>(bv, bi);
    int bs = __builtin_amdgcn_readlane(bi, 63);
    if (lane == k) kreg = bs;
    #pragma unroll
    for (int j = 0; j < PPL; ++j)
      if (j * 64 + lane == bs) d2[j] = 3.4e38f;
  }
  if (lane < 24) idxK[(size_t)q * 24 + lane] = kreg;
}

// ---------------- gather X rows at fi; emit new_pts -------------------------
__global__ __launch_bounds__(128) void gather_fi_kernel(const u16* __restrict__ Xsrc,
                                                        const float* __restrict__ pts,
                                                        const int* __restrict__ fi,
                                                        u16* __restrict__ Xg,
                                                        float* __restrict__ npts,
                                                        int Np, int S) {
  int q = blockIdx.x;
  int b = q / S;
  int t = threadIdx.x;
  int r = fi[q];
  const u32x4* src = (const u32x4*)(Xsrc + ((size_t)b * Np + r) * KP);
  u32x4* dst = (u32x4*)(Xg + (size_t)q * KP);
  dst[t] = src[t];
  int t2 = t + 128;
  if (t2 < 132) dst[t2] = src[t2];
  if (t == 0) {
    npts[(size_t)q * 2] = pts[((size_t)b * Np + r) * 2];
    npts[(size_t)q * 2 + 1] = pts[((size_t)b * Np + r) * 2 + 1];
  }
}

// ---------------- weight prep ----------------------------------------------
__global__ __launch_bounds__(256) void wd_transpose_kernel(const float* __restrict__ Wd,
                                                           u16* __restrict__ WdT) {
  __shared__ float tbuf[32][33];
  int tx = threadIdx.x & 31, ty = threadIdx.x >> 5;
  int ot = blockIdx.x * 32, dt = blockIdx.y * 32;
  #pragma unroll
  for (int j = 0; j < 4; ++j) {
    int o = ot + ty + 8 * j, d = dt + tx;
    tbuf[ty + 8 * j][tx] = (o < 1026 && d < 1026) ? Wd[(size_t)o * 1026 + d] : 0.f;
  }
  __syncthreads();
  #pragma unroll
  for (int j = 0; j < 4; ++j) {
    int d = dt + ty + 8 * j, o = ot + tx;
    if (o < KP) WdT[(size_t)d * KP + o] = f2bf(tbuf[tx][ty + 8 * j]);
  }
}

__global__ __launch_bounds__(256) void wagg_convert_kernel(const float* __restrict__ Wagg,
                                                           u16* __restrict__ Wa1,
                                                           u16* __restrict__ Wa2) {
  int c = blockIdx.x, t = threadIdx.x;
  const float* row = Wagg + (size_t)c * 2052;
  for (int d = t; d < KP; d += 256) {
    Wa1[(size_t)c * KP + d] = (d < 1026) ? f2bf(row[d]) : (u16)0;
    Wa2[(size_t)c * KP + d] = (d < 1026) ? f2bf(row[1026 + d]) : (u16)0;
  }
}

__global__ __launch_bounds__(256) void czero_kernel(const float* __restrict__ bdiff,
                                                    const float* __restrict__ Wagg,
                                                    const float* __restrict__ bagg,
                                                    float* __restrict__ czero) {
  int lane = threadIdx.x & 63, wv = threadIdx.x >> 6;
  int c = blockIdx.x * 4 + wv;
  float acc = 0.f;
  for (int o = lane; o < 1026; o += 64) acc += bdiff[o] * Wagg[(size_t)c * 2052 + o];
  #pragma unroll
  for (int off = 32; off; off >>= 1) acc += __shfl_xor(acc, off);
  if (lane == 0) czero[c] = acc + bagg[c];
}

// ---------------- bf16 MFMA GEMM: C[M,N] = A[M,K] @ Bt[N,K]^T ---------------
template <int BF16OUT>
__global__ __launch_bounds__(256) void gemm_bt_kernel(const u16* __restrict__ A,
                                                      const u16* __restrict__ Bt,
                                                      void* __restrict__ Cout,
                                                      int M, int N, int K, int ldc, int nvalid) {
  __shared__ __align__(16) u16 As[128 * 32];
  __shared__ __align__(16) u16 Bs[128 * 32];
  const int tid = threadIdx.x;
  const int lane = tid & 63;
  const int wv = tid >> 6;
  const int m0 = blockIdx.y * 128;
  const int n0 = blockIdx.x * 128;
  const int wm = (wv >> 1) * 64;
  const int wn = (wv & 1) * 64;

  f32x4 acc[4][4];
  #pragma unroll
  for (int i = 0; i < 4; ++i)
    #pragma unroll
    for (int j = 0; j < 4; ++j)
      #pragma unroll
      for (int c = 0; c < 4; ++c) acc[i][j][c] = 0.f;

  const int ch0 = wv * 2;
  const int rin = lane >> 2;
  const int cin = (lane & 3) * 8;

  for (int k0 = 0; k0 < K; k0 += 32) {
    #pragma unroll
    for (int i = 0; i < 2; ++i) {
      const int ch = ch0 + i;
      const int row = ch * 16 + rin;
      const u16* ga = A + (size_t)(m0 + row) * K + (k0 + cin);
      const u16* gb = Bt + (size_t)(n0 + row) * K + (k0 + cin);
      __builtin_amdgcn_global_load_lds((gvp)ga, (svp)(As + ch * 512), 16, 0, 0);
      __builtin_amdgcn_global_load_lds((gvp)gb, (svp)(Bs + ch * 512), 16, 0, 0);
    }
    __syncthreads();
    const int rf = lane & 15;
    const int qf = (lane >> 4) * 8;
    bf16x8 af[4], bfv[4];
    #pragma unroll
    for (int mi = 0; mi < 4; ++mi)
      af[mi] = *(const bf16x8*)(As + (wm + mi * 16 + rf) * 32 + qf);
    #pragma unroll
    for (int ni = 0; ni < 4; ++ni)
      bfv[ni] = *(const bf16x8*)(Bs + (wn + ni * 16 + rf) * 32 + qf);
    #pragma unroll
    for (int mi = 0; mi < 4; ++mi)
      #pragma unroll
      for (int ni = 0; ni < 4; ++ni)
        acc[mi][ni] = __builtin_amdgcn_mfma_f32_16x16x32_bf16(af[mi], bfv[ni], acc[mi][ni], 0, 0, 0);
    __syncthreads();
  }

  const int rq = (lane >> 4) * 4;
  const int cf = lane & 15;
  #pragma unroll
  for (int mi = 0; mi < 4; ++mi) {
    #pragma unroll
    for (int ni = 0; ni < 4; ++ni) {
      const int col = n0 + wn + ni * 16 + cf;
      #pragma unroll
      for (int r = 0; r < 4; ++r) {
        const int row = m0 + wm + mi * 16 + rq + r;
        const float v = acc[mi][ni][r];
        if (BF16OUT) {
          if (col < nvalid) ((u16*)Cout)[(size_t)row * ldc + col] = f2bf(v);
        } else {
          ((float*)Cout)[(size_t)row * ldc + col] = v;
        }
      }
    }
  }
}

// ---------------- fused gather + relu + LN + mean_k -------------------------
// MODE 0: bf16 X-row output (KP stride, pts tail)   MODE 1: bf16 flat 1024
template <int MODE>
__global__ __launch_bounds__(256) void h_epilogue_kernel(const float* __restrict__ Z1,
                                                         const float* __restrict__ Z2g,
                                                         const float* __restrict__ czero,
                                                         const int* __restrict__ idxK,
                                                         const int* __restrict__ fi,
                                                         const float* __restrict__ g,
                                                         const float* __restrict__ bb,
                                                         const float* __restrict__ npts,
                                                         void* __restrict__ outp,
                                                         int Np, int S) {
  __shared__ float r1[4];
  __shared__ float r2[4];
  int q = blockIdx.x;
  int b = q / S;
  int t = threadIdx.x;
  int lane = t & 63, wv = t >> 6;
  int fiv = fi[q];
  const f32x4* z2 = (const f32x4*)(Z2g + (size_t)q * 1024);
  const f32x4* zf = (const f32x4*)(Z1 + ((size_t)b * Np + fiv) * 1024);
  const f32x4* cz = (const f32x4*)czero;
  f32x4 base = z2[t] + cz[t] - zf[t];
  f32x4 gv = ((const f32x4*)g)[t];
  f32x4 bv = ((const f32x4*)bb)[t];
  f32x4 acc;
  #pragma unroll
  for (int c = 0; c < 4; ++c) acc[c] = 0.f;
  for (int k = 0; k < 24; ++k) {
    int n = idxK[(size_t)q * 24 + k];
    const f32x4* zr = (const f32x4*)(Z1 + ((size_t)b * Np + n) * 1024);
    f32x4 v = zr[t] + base;
    #pragma unroll
    for (int c = 0; c < 4; ++c) v[c] = fmaxf(v[c], 0.f);
    float s1 = v[0] + v[1] + v[2] + v[3];
    float s2 = v[0] * v[0] + v[1] * v[1] + v[2] * v[2] + v[3] * v[3];
    #pragma unroll
    for (int off = 32; off; off >>= 1) {
      s1 += __shfl_xor(s1, off);
      s2 += __shfl_xor(s2, off);
    }
    if (lane == 0) { r1[wv] = s1; r2[wv] = s2; }
    __syncthreads();
    s1 = r1[0] + r1[1] + r1[2] + r1[3];
    s2 = r2[0] + r2[1] + r2[2] + r2[3];
    __syncthreads();
    float m = s1 * (1.f / 1024.f);
    float var = s2 * (1.f / 1024.f) - m * m;
    float rs = rsqrtf(var + 1e-5f);
    #pragma unroll
    for (int c = 0; c < 4; ++c) acc[c] += (v[c] - m) * rs * gv[c] + bv[c];
  }
  #pragma unroll
  for (int c = 0; c < 4; ++c) acc[c] *= (1.f / 24.f);
  u16x4 o4;
  #pragma unroll
  for (int c = 0; c < 4; ++c) o4[c] = f2bf(acc[c]);
  if (MODE == 0) {
    u16* X = (u16*)outp;
    size_t ro = (size_t)q * KP;
    *(u16x4*)(X + ro + t * 4) = o4;
    if (t == 0) {
      X[ro + 1024] = f2bf(npts[(size_t)q * 2]);
      X[ro + 1025] = f2bf(npts[(size_t)q * 2 + 1]);
    }
    if (t < 15) ((u32*)(X + ro + 1026))[t] = 0;
  } else {
    *(u16x4*)((u16*)outp + (size_t)q * 1024 + t * 4) = o4;
  }
}

// ---------------- MLP MFMA GEMM: P[blk] = W_tile(fp32->bf16) @ Fb^T ---------
// W fp32 [M,K]; Fb bf16 [32,K]; grid = (M/128) << KSBITS blocks.
// A staged via global_load_lds (XOR-swizzled 16B groups, conflict-free);
// converted to bf16 fragments in-register. Partials P[blk][128][32] fp32.
template <int KSBITS, int NST>
__global__ __launch_bounds__(256, 4) void mlp_mfma_kernel(const float* __restrict__ W,
                                                          const u16* __restrict__ Fb,
                                                          float* __restrict__ P, int K) {
  __shared__ __align__(16) float Asf[128 * 32];
  __shared__ __align__(16) u16 Fsb[32 * 40];
  const int tid = threadIdx.x, lane = tid & 63, wv = tid >> 6;
  const int ot = blockIdx.x >> KSBITS;
  const int ks = blockIdx.x & ((1 << KSBITS) - 1);
  const int m0 = ot * 128;
  const int k0b = ks * (NST * 32);
  const int arow = lane >> 3;
  const int agrp = lane & 7;
  const int rf = lane & 15, quad = lane >> 4;

  f32x4 acc[2][2];
  #pragma unroll
  for (int i = 0; i < 2; ++i)
    #pragma unroll
    for (int j = 0; j < 2; ++j)
      #pragma unroll
      for (int c = 0; c < 4; ++c) acc[i][j][c] = 0.f;

  for (int st = 0; st < NST; ++st) {
    const int k0 = k0b + st * 32;
    #pragma unroll
    for (int i = 0; i < 4; ++i) {
      const int row = wv * 32 + i * 8 + arow;
      const int g = agrp ^ (row & 7);
      const float* ga = W + (size_t)(m0 + row) * K + k0 + g * 4;
      __builtin_amdgcn_global_load_lds((gvp)ga, (svp)(Asf + (wv * 32 + i * 8) * 32), 16, 0, 0);
    }
    if (tid < 128) {
      const int fr = tid >> 2, fc = (tid & 3) * 8;
      u32x4 tmp = *(const u32x4*)(Fb + (size_t)fr * K + k0 + fc);
      *(u32x4*)(Fsb + fr * 40 + fc) = tmp;
    }
    __syncthreads();
    bf16x8 bfr[2];
    #pragma unroll
    for (int ni = 0; ni < 2; ++ni)
      bfr[ni] = *(const bf16x8*)(Fsb + (ni * 16 + rf) * 40 + quad * 8);
    #pragma unroll
    for (int mi = 0; mi < 2; ++mi) {
      const float* ap = Asf + (size_t)(wv * 32 + mi * 16 + rf) * 32;
      f32x4 a0 = *(const f32x4*)(ap + (((quad * 2) ^ (rf & 7)) * 4));
      f32x4 a1 = *(const f32x4*)(ap + (((quad * 2 + 1) ^ (rf & 7)) * 4));
      union { bf16x8 v; u16 h[8]; } af;
      #pragma unroll
      for (int c = 0; c < 4; ++c) { af.h[c] = f2bf(a0[c]); af.h[4 + c] = f2bf(a1[c]); }
      #pragma unroll
      for (int ni = 0; ni < 2; ++ni)
        acc[mi][ni] = __builtin_amdgcn_mfma_f32_16x16x32_bf16(af.v, bfr[ni], acc[mi][ni], 0, 0, 0);
    }
    __syncthreads();
  }

  float* Pb = P + (size_t)blockIdx.x * 4096;
  const int rq = (lane >> 4) * 4, cf = lane & 15;
  #pragma unroll
  for (int mi = 0; mi < 2; ++mi)
    #pragma unroll
    for (int ni = 0; ni < 2; ++ni)
      #pragma unroll
      for (int r = 0; r < 4; ++r)
        Pb[(wv * 32 + mi * 16 + rq + r) * 32 + ni * 16 + cf] = acc[mi][ni][r];
}

// ---------------- K-split partial reductions (bias fused) -------------------
__global__ __launch_bounds__(256) void reduce_flat_kernel(const float* __restrict__ P,
                                                          const float* __restrict__ bias,
                                                          u16* __restrict__ x1bf) {
  int idx = blockIdx.x * 256 + threadIdx.x;  // 32768
  int o = idx >> 5, b = idx & 31;
  float s = bias[o];
  const float* p = P + ((size_t)(o >> 7) * 64) * 4096 + (o & 127) * 32 + b;
  #pragma unroll 8
  for (int ks = 0; ks < 64; ++ks) s += p[(size_t)ks * 4096];
  x1bf[(size_t)b * 1024 + o] = f2bf(s);
}

__global__ __launch_bounds__(256) void reduce_dim_kernel(const float* __restrict__ P,
                                                         const float* __restrict__ bias,
                                                         float* __restrict__ out) {
  int idx = blockIdx.x * 256 + threadIdx.x;  // 131072
  int o = idx >> 5, b = idx & 31;
  float s = bias[o];
  const float* p = P + ((size_t)(o >> 7) * 8) * 4096 + (o & 127) * 32 + b;
  #pragma unroll
  for (int ks = 0; ks < 8; ++ks) s += p[(size_t)ks * 4096];
  out[(size_t)b * 4096 + o] = s;
}

// ---------------------------------------------------------------------------
extern "C" void kernel_launch(void* const* d_in, const int* in_sizes, int n_in,
                              void* d_out, int out_size, void* d_ws, size_t ws_size,
                              hipStream_t stream) {
  const float* fmap  = (const float*)d_in[0];
  const float* pts   = (const float*)d_in[1];
  const float* Wdiff = (const float*)d_in[2];
  const float* bdiff = (const float*)d_in[3];
  const float* Wagg  = (const float*)d_in[4];
  const float* bagg  = (const float*)d_in[5];
  const float* lng   = (const float*)d_in[6];
  const float* lnb   = (const float*)d_in[7];
  const float* Wflat = (const float*)d_in[8];
  const float* bflat = (const float*)d_in[9];
  const float* Wdim  = (const float*)d_in[10];
  const float* bdim  = (const float*)d_in[11];
  float* out = (float*)d_out;

  char* w = (char*)d_ws;
  size_t off = 0;
  auto alloc = [&](size_t n) { char* p = w + off; off += (n + 255) & ~(size_t)255; return p; };

  float* Z1    = (float*)alloc(16384ull * 1024 * 4);  // 67.1 MB
  float* Z2g   = (float*)alloc(4096ull * 1024 * 4);   // 16.8 MB
  u16* Xbf0  = (u16*)alloc(16384ull * KP * 2);
  u16* X1bf  = (u16*)alloc(4096ull * KP * 2);
  u16* Xg    = (u16*)alloc(4096ull * KP * 2);
  u16* WdT   = (u16*)alloc((size_t)NP0 * KP * 2);
  u16* Wa1   = (u16*)alloc(1024ull * KP * 2);
  u16* Wa2   = (u16*)alloc(1024ull * KP * 2);
  u16* Wcomb = (u16*)alloc(1024ull * KP * 2);
  float* czero = (float*)alloc(1024 * 4);
  int* fi0   = (int*)alloc(32 * 128 * 4);
  int* fi1   = (int*)alloc(32 * 32 * 4);
  int* idx0  = (int*)alloc(32 * 128 * 24 * 4);
  int* idx1  = (int*)alloc(32 * 32 * 24 * 4);
  float* npts0 = (float*)alloc(32 * 128 * 2 * 4);
  float* npts1 = (float*)alloc(32 * 32 * 2 * 4);
  u16* fea2bf = (u16*)alloc(32ull * 32768 * 2);       // 2 MB bf16
  u16* x1bf   = (u16*)alloc(32ull * 1024 * 2);        // 64 KB bf16
  float* Pf   = (float*)alloc(512ull * 4096 * 4);     // 8 MB partials (flat)
  float* Pd   = (float*)alloc(256ull * 4096 * 4);     // 4 MB partials (dim)

  // ---- stage-0 inputs
  bilinear_fused_kernel<<<dim3(32, 32), 256, 0, stream>>>(fmap, pts, Xbf0);

  // ---- stage 0 (Np=512, S=128)
  fps_kernel<8, 2><<<32, 64, 0, stream>>>(pts, fi0, 512, 128);
  gather_fi_kernel<<<4096, 128, 0, stream>>>(Xbf0, pts, fi0, Xg, npts0, 512, 128);
  knn_kernel<8><<<1024, 256, 0, stream>>>(npts0, pts, idx0, 512, 128);
  wd_transpose_kernel<<<dim3(33, 36), 256, 0, stream>>>(Wdiff, WdT);
  wagg_convert_kernel<<<1024, 256, 0, stream>>>(Wagg, Wa1, Wa2);
  czero_kernel<<<256, 256, 0, stream>>>(bdiff, Wagg, bagg, czero);
  gemm_bt_kernel<1><<<dim3(9, 8), 256, 0, stream>>>(Wa1, WdT, Wcomb, 1024, NP0, KP, KP, KP);
  gemm_bt_kernel<0><<<dim3(8, 128), 256, 0, stream>>>(Xbf0, Wcomb, Z1, 16384, 1024, KP, 1024, 1024);
  gemm_bt_kernel<0><<<dim3(8, 32), 256, 0, stream>>>(Xg, Wa2, Z2g, 4096, 1024, KP, 1024, 1024);
  h_epilogue_kernel<0><<<4096, 256, 0, stream>>>(Z1, Z2g, czero, idx0, fi0, lng, lnb, npts0,
                                                 X1bf, 512, 128);

  // ---- stage 1 (Np=128, S=32)
  fps_kernel<2, 1><<<32, 64, 0, stream>>>(npts0, fi1, 128, 32);
  gather_fi_kernel<<<1024, 128, 0, stream>>>(X1bf, npts0, fi1, Xg, npts1, 128, 32);
  knn_kernel<2><<<256, 256, 0, stream>>>(npts1, npts0, idx1, 128, 32);
  wd_transpose_kernel<<<dim3(33, 36), 256, 0, stream>>>(Wdiff + 1026 * 1026, WdT);
  wagg_convert_kernel<<<1024, 256, 0, stream>>>(Wagg + 1024 * 2052, Wa1, Wa2);
  czero_kernel<<<256, 256, 0, stream>>>(bdiff + 1026, Wagg + 1024 * 2052, bagg + 1024, czero);
  gemm_bt_kernel<1><<<dim3(9, 8), 256, 0, stream>>>(Wa1, WdT, Wcomb, 1024, NP0, KP, KP, KP);
  gemm_bt_kernel<0><<<dim3(8, 32), 256, 0, stream>>>(X1bf, Wcomb, Z1, 4096, 1024, KP, 1024, 1024);
  gemm_bt_kernel<0><<<dim3(8, 8), 256, 0, stream>>>(Xg, Wa2, Z2g, 1024, 1024, KP, 1024, 1024);
  h_epilogue_kernel<1><<<1024, 256, 0, stream>>>(Z1, Z2g, czero, idx1, fi1, lng + 1024, lnb + 1024,
                                                 npts1, fea2bf, 128, 32);

  // ---- final MLP (MFMA, K-split partials + reduce)
  mlp_mfma_kernel<6, 16><<<512, 256, 0, stream>>>(Wflat, fea2bf, Pf, 32768);
  reduce_flat_kernel<<<128, 256, 0, stream>>>(Pf, bflat, x1bf);
  mlp_mfma_kernel<3, 4><<<256, 256, 0, stream>>>(Wdim, x1bf, Pd, 1024);
  reduce_dim_kernel<<<512, 256, 0, stream>>>(Pd, bdim, out);
}

// Round 3
// 687.050 us; speedup vs baseline: 1.1854x; 1.1537x over previous
//
#include <hip/hip_runtime.h>

// ---------------------------------------------------------------------------
// GeoRegionSampler: restructured pipeline
//   X = [bilinear_fea | pts] (bf16, padded 1026->1056); bilinear fused with
//   fmap channel-tile staging in LDS.
//   Wcomb = Wa1 @ Wd   (bf16 MFMA GEMM)
//   Z1 = X @ Wcomb^T ; Z2 = X[fi] @ Wa2^T ; czero = b_diff@Wa1^T + b_agg
//   h[b,s,k] = relu(Z1[idx]-Z1[fi]+Z2[s]+czero) -> LN -> mean_k  (fused;
//   emits fea2 as bf16)
//   final MLP: MFMA GEMMs streaming W as fp32 via global_load_lds.
// FPS/kNN: fp32 bit-exact (fp contract off), first-index tie-break.
// R7: R6's DPP select-scan did NOT speed fps (90us both ways) -- the
//   dependent cross-lane chain depth is the floor, and 32 waves leave 224
//   CUs idle. Two fixes:
//   (1) fps is FUSED into the big Z1 GEMM as an extra blockIdx.y==0 row
//       (8 blocks x 4 waves = 32 batches) -- runs concurrently with the
//       1024 MFMA blocks, off the critical path. Launch order rearranged
//       (weight prep before Z1; gather/knn/Z2 after).
//   (2) fps/knn argmax chain shortened: value-only DPP fmax/fmin scan
//       (single-instr steps) + readlane(63) + ballot + s_ff1 to find the
//       winner lane; idx/x/y via readlane. Rare multi-tie slow path keeps
//       the exact max-value/min-index monoid (dists >= +0, no NaN/-0).
// ---------------------------------------------------------------------------

typedef float f32x4 __attribute__((ext_vector_type(4)));
typedef short bf16x8 __attribute__((ext_vector_type(8)));
typedef unsigned short u16;
typedef u16 u16x4 __attribute__((ext_vector_type(4)));
typedef unsigned int u32;
typedef u32 u32x4 __attribute__((ext_vector_type(4)));
typedef unsigned long long u64;

typedef const void __attribute__((address_space(1)))* gvp;
typedef void __attribute__((address_space(3)))* svp;

__device__ __forceinline__ u16 f2bf(float f) {
  union { float f; u32 u; } x; x.f = f;
  u32 r = x.u + 0x7fffu + ((x.u >> 16) & 1u);
  return (u16)(r >> 16);
}

#define KP 1056   // padded Dp (1026 -> 33*32)
#define NP0 1152  // padded N for weight-combine GEMM (9*128)

// ---- DPP value-only reduction helpers (single-instruction-fusable) --------
__device__ __forceinline__ float rl_f(float v, int lane) {
  return __int_as_float(__builtin_amdgcn_readlane(__float_as_int(v), lane));
}

template <int CTRL>
__device__ __forceinline__ float dpp_fmax(float v) {
  float o = __int_as_float(__builtin_amdgcn_update_dpp(
      (int)0xff800000 /* -inf */, __float_as_int(v), CTRL, 0xf, 0xf, false));
  return fmaxf(v, o);
}

template <int CTRL>
__device__ __forceinline__ float dpp_fmin(float v) {
  float o = __int_as_float(__builtin_amdgcn_update_dpp(
      0x7f800000 /* +inf */, __float_as_int(v), CTRL, 0xf, 0xf, false));
  return fminf(v, o);
}

__device__ __forceinline__ float wave_fmax63(float v) {
  v = dpp_fmax<0x111>(v);  // row_shr:1
  v = dpp_fmax<0x112>(v);  // row_shr:2
  v = dpp_fmax<0x114>(v);  // row_shr:4
  v = dpp_fmax<0x118>(v);  // row_shr:8
  v = dpp_fmax<0x142>(v);  // row_bcast15
  v = dpp_fmax<0x143>(v);  // row_bcast31
  return rl_f(v, 63);
}

__device__ __forceinline__ float wave_fmin63(float v) {
  v = dpp_fmin<0x111>(v);
  v = dpp_fmin<0x112>(v);
  v = dpp_fmin<0x114>(v);
  v = dpp_fmin<0x118>(v);
  v = dpp_fmin<0x142>(v);
  v = dpp_fmin<0x143>(v);
  return rl_f(v, 63);
}

// ---------------- FPS core: one wave per batch, bit-exact -------------------
template <int PPL, int HS>
__device__ void fps_core(const float* __restrict__ pts, int* __restrict__ fi,
                         int Np, int S, int b, int lane) {
  #pragma clang fp contract(off)
  float px[PPL], py[PPL], dist[PPL];
  #pragma unroll
  for (int j = 0; j < PPL; ++j) {
    int n = j * 64 + lane;
    px[j] = pts[((size_t)b * Np + n) * 2];
    py[j] = pts[((size_t)b * Np + n) * 2 + 1];
    dist[j] = 1e10f;
  }
  int hist[HS];
  #pragma unroll
  for (int h = 0; h < HS; ++h) hist[h] = 0;
  int far = 0;
  float cx = rl_f(px[0], 0);
  float cy = rl_f(py[0], 0);
  for (int s = 0; s < S; ++s) {
    #pragma unroll
    for (int h = 0; h < HS; ++h)
      if ((s >> 6) == h && (s & 63) == lane) hist[h] = far;
    // distance update (independent across j)
    float tv[PPL]; int ti[PPL]; float tx[PPL], ty[PPL];
    #pragma unroll
    for (int j = 0; j < PPL; ++j) {
      float dx = px[j] - cx, dy = py[j] - cy;
      float d = dx * dx + dy * dy;
      float nd = fminf(dist[j], d);
      dist[j] = nd;
      tv[j] = nd; ti[j] = j * 64 + lane; tx[j] = px[j]; ty[j] = py[j];
    }
    // lane-local argmax tree (ties -> lower j = lower index; strict >)
    #pragma unroll
    for (int w = PPL; w > 1; w >>= 1)
      #pragma unroll
      for (int j = 0; j < (w >> 1); ++j)
        if (tv[j + (w >> 1)] > tv[j]) {
          tv[j] = tv[j + (w >> 1)]; ti[j] = ti[j + (w >> 1)];
          tx[j] = tx[j + (w >> 1)]; ty[j] = ty[j + (w >> 1)];
        }
    // value-only cross-lane max, then locate winner lane via ballot
    float smax = wave_fmax63(tv[0]);
    u64 mask = __ballot(tv[0] == smax);
    int L = __builtin_ctzll(mask);
    int fidx = __builtin_amdgcn_readlane(ti[0], L);
    float fx = rl_f(tx[0], L), fy = rl_f(ty[0], L);
    u64 rest = mask & (mask - 1);
    if (__builtin_expect(rest != 0, 0)) {
      // rare: multiple lanes hold the max value -> exact min-index tiebreak
      while (rest) {
        int L2 = __builtin_ctzll(rest);
        int c = __builtin_amdgcn_readlane(ti[0], L2);
        if (c < fidx) {
          fidx = c; fx = rl_f(tx[0], L2); fy = rl_f(ty[0], L2);
        }
        rest &= rest - 1;
      }
    }
    far = fidx; cx = fx; cy = fy;
  }
  #pragma unroll
  for (int h = 0; h < HS; ++h) {
    int s = h * 64 + lane;
    if (s < S) fi[b * S + s] = hist[h];
  }
}

// ------- fused bilinear: stage fmap[b][ct*32..+31][:] in LDS, interp -------
__global__ __launch_bounds__(256, 2) void bilinear_fused_kernel(const float* __restrict__ fmap,
                                                                const float* __restrict__ pts,
                                                                u16* __restrict__ X) {
  __shared__ float fmS[32][580];
  const int ct = blockIdx.x, b = blockIdx.y;
  const int t = threadIdx.x;
  const float* src = fmap + ((size_t)b * 1024 + ct * 32) * 576;
  const int tr = t >> 3, ti = t & 7;
  #pragma unroll
  for (int j = 0; j < 18; ++j) {
    int c4 = j * 8 + ti;
    *(f32x4*)&fmS[tr][c4 * 4] = *(const f32x4*)(src + (size_t)tr * 576 + c4 * 4);
  }
  __syncthreads();
  #pragma unroll
  for (int pass = 0; pass < 2; ++pass) {
    const int n = pass * 256 + t;
    const int pidx = b * 512 + n;
    float p0 = pts[(size_t)pidx * 2], p1 = pts[(size_t)pidx * 2 + 1];
    float gy = p0 * 23.f, gx = p1 * 23.f;
    float y0f = floorf(gy), x0f = floorf(gx);
    float wy = gy - y0f, wx = gx - x0f;
    int y0 = (int)y0f; y0 = y0 < 0 ? 0 : (y0 > 23 ? 23 : y0);
    int x0 = (int)x0f; x0 = x0 < 0 ? 0 : (x0 > 23 ? 23 : x0);
    int y1 = y0 + 1 > 23 ? 23 : y0 + 1;
    int x1 = x0 + 1 > 23 ? 23 : x0 + 1;
    float w00 = (1.f - wy) * (1.f - wx), w01 = (1.f - wy) * wx;
    float w10 = wy * (1.f - wx), w11 = wy * wx;
    const int i00 = y0 * 24 + x0, i01 = y0 * 24 + x1;
    const int i10 = y1 * 24 + x0, i11 = y1 * 24 + x1;
    size_t ro = (size_t)pidx * KP + ct * 32;
    #pragma unroll
    for (int cq = 0; cq < 8; ++cq) {
      u16x4 o4;
      #pragma unroll
      for (int cc = 0; cc < 4; ++cc) {
        int c = cq * 4 + cc;
        float v = w00 * fmS[c][i00] + w01 * fmS[c][i01] +
                  w10 * fmS[c][i10] + w11 * fmS[c][i11];
        o4[cc] = f2bf(v);
      }
      *(u16x4*)(X + ro + cq * 4) = o4;
    }
    if (ct == 31) {
      size_t rb = (size_t)pidx * KP;
      X[rb + 1024] = f2bf(p0);
      X[rb + 1025] = f2bf(p1);
      #pragma unroll
      for (int z = 0; z < 15; ++z) ((u32*)(X + rb + 1026))[z] = 0;
    }
  }
}

// ---------------- kNN: one wave per (b,s), bit-exact ------------------------
// value-only DPP fmin scan + ballot winner-lane location per k.
template <int PPL>
__global__ __launch_bounds__(256) void knn_kernel(const float* __restrict__ qpts,
                                                  const float* __restrict__ rpts,
                                                  int* __restrict__ idxK, int Np, int S) {
  #pragma clang fp contract(off)
  int lane = threadIdx.x & 63, wv = threadIdx.x >> 6;
  int q = blockIdx.x * 4 + wv;
  int b = q / S;
  float ax = qpts[(size_t)q * 2], ay = qpts[(size_t)q * 2 + 1];
  float a2 = ax * ax + ay * ay;
  float d2[PPL];
  #pragma unroll
  for (int j = 0; j < PPL; ++j) {
    int n = j * 64 + lane;
    float bx = rpts[((size_t)b * Np + n) * 2];
    float by = rpts[((size_t)b * Np + n) * 2 + 1];
    float b2 = bx * bx + by * by;
    float dot = ax * bx + ay * by;
    float t = a2 + b2;
    float m2 = 2.f * dot;
    d2[j] = t - m2;
  }
  int kreg = 0;
  for (int k = 0; k < 24; ++k) {
    float tv[PPL]; int ti[PPL];
    #pragma unroll
    for (int j = 0; j < PPL; ++j) { tv[j] = d2[j]; ti[j] = j * 64 + lane; }
    #pragma unroll
    for (int w = PPL; w > 1; w >>= 1)
      #pragma unroll
      for (int j = 0; j < (w >> 1); ++j)
        if (tv[j + (w >> 1)] < tv[j]) {
          tv[j] = tv[j + (w >> 1)]; ti[j] = ti[j + (w >> 1)];
        }
    float smin = wave_fmin63(tv[0]);
    u64 mask = __ballot(tv[0] == smin);
    int L = __builtin_ctzll(mask);
    int bs = __builtin_amdgcn_readlane(ti[0], L);
    u64 rest = mask & (mask - 1);
    if (__builtin_expect(rest != 0, 0)) {
      while (rest) {
        int L2 = __builtin_ctzll(rest);
        int c = __builtin_amdgcn_readlane(ti[0], L2);
        if (c < bs) bs = c;
        rest &= rest - 1;
      }
    }
    if (lane == k) kreg = bs;
    #pragma unroll
    for (int j = 0; j < PPL; ++j)
      if (j * 64 + lane == bs) d2[j] = 3.4e38f;
  }
  if (lane < 24) idxK[(size_t)q * 24 + lane] = kreg;
}

// ---------------- gather X rows at fi; emit new_pts -------------------------
__global__ __launch_bounds__(128) void gather_fi_kernel(const u16* __restrict__ Xsrc,
                                                        const float* __restrict__ pts,
                                                        const int* __restrict__ fi,
                                                        u16* __restrict__ Xg,
                                                        float* __restrict__ npts,
                                                        int Np, int S) {
  int q = blockIdx.x;
  int b = q / S;
  int t = threadIdx.x;
  int r = fi[q];
  const u32x4* src = (const u32x4*)(Xsrc + ((size_t)b * Np + r) * KP);
  u32x4* dst = (u32x4*)(Xg + (size_t)q * KP);
  dst[t] = src[t];
  int t2 = t + 128;
  if (t2 < 132) dst[t2] = src[t2];
  if (t == 0) {
    npts[(size_t)q * 2] = pts[((size_t)b * Np + r) * 2];
    npts[(size_t)q * 2 + 1] = pts[((size_t)b * Np + r) * 2 + 1];
  }
}

// ---------------- weight prep ----------------------------------------------
__global__ __launch_bounds__(256) void wd_transpose_kernel(const float* __restrict__ Wd,
                                                           u16* __restrict__ WdT) {
  __shared__ float tbuf[32][33];
  int tx = threadIdx.x & 31, ty = threadIdx.x >> 5;
  int ot = blockIdx.x * 32, dt = blockIdx.y * 32;
  #pragma unroll
  for (int j = 0; j < 4; ++j) {
    int o = ot + ty + 8 * j, d = dt + tx;
    tbuf[ty + 8 * j][tx] = (o < 1026 && d < 1026) ? Wd[(size_t)o * 1026 + d] : 0.f;
  }
  __syncthreads();
  #pragma unroll
  for (int j = 0; j < 4; ++j) {
    int d = dt + ty + 8 * j, o = ot + tx;
    if (o < KP) WdT[(size_t)d * KP + o] = f2bf(tbuf[tx][ty + 8 * j]);
  }
}

__global__ __launch_bounds__(256) void wagg_convert_kernel(const float* __restrict__ Wagg,
                                                           u16* __restrict__ Wa1,
                                                           u16* __restrict__ Wa2) {
  int c = blockIdx.x, t = threadIdx.x;
  const float* row = Wagg + (size_t)c * 2052;
  for (int d = t; d < KP; d += 256) {
    Wa1[(size_t)c * KP + d] = (d < 1026) ? f2bf(row[d]) : (u16)0;
    Wa2[(size_t)c * KP + d] = (d < 1026) ? f2bf(row[1026 + d]) : (u16)0;
  }
}

__global__ __launch_bounds__(256) void czero_kernel(const float* __restrict__ bdiff,
                                                    const float* __restrict__ Wagg,
                                                    const float* __restrict__ bagg,
                                                    float* __restrict__ czero) {
  int lane = threadIdx.x & 63, wv = threadIdx.x >> 6;
  int c = blockIdx.x * 4 + wv;
  float acc = 0.f;
  for (int o = lane; o < 1026; o += 64) acc += bdiff[o] * Wagg[(size_t)c * 2052 + o];
  #pragma unroll
  for (int off = 32; off; off >>= 1) acc += __shfl_xor(acc, off);
  if (lane == 0) czero[c] = acc + bagg[c];
}

// ---------------- bf16 MFMA GEMM: C[M,N] = A[M,K] @ Bt[N,K]^T ---------------
// FPS_PPL > 0: blockIdx.y==0 row runs fps_core (8 blocks x 4 waves = 32
// batches) concurrently with the GEMM blocks; GEMM rows shift down by 1.
template <int BF16OUT, int FPS_PPL, int FPS_HS>
__global__ __launch_bounds__(256) void gemm_bt_kernel(const u16* __restrict__ A,
                                                      const u16* __restrict__ Bt,
                                                      void* __restrict__ Cout,
                                                      int M, int N, int K, int ldc, int nvalid,
                                                      const float* __restrict__ fpts,
                                                      int* __restrict__ ffi,
                                                      int fNp, int fS) {
  const int tid = threadIdx.x;
  const int lane = tid & 63;
  const int wv = tid >> 6;
  if (FPS_PPL > 0 && blockIdx.y == 0) {
    fps_core<FPS_PPL ? FPS_PPL : 1, FPS_HS>(fpts, ffi, fNp, fS, blockIdx.x * 4 + wv, lane);
    return;
  }
  __shared__ __align__(16) u16 As[128 * 32];
  __shared__ __align__(16) u16 Bs[128 * 32];
  const int m0 = (blockIdx.y - (FPS_PPL > 0 ? 1 : 0)) * 128;
  const int n0 = blockIdx.x * 128;
  const int wm = (wv >> 1) * 64;
  const int wn = (wv & 1) * 64;

  f32x4 acc[4][4];
  #pragma unroll
  for (int i = 0; i < 4; ++i)
    #pragma unroll
    for (int j = 0; j < 4; ++j)
      #pragma unroll
      for (int c = 0; c < 4; ++c) acc[i][j][c] = 0.f;

  const int ch0 = wv * 2;
  const int rin = lane >> 2;
  const int cin = (lane & 3) * 8;

  for (int k0 = 0; k0 < K; k0 += 32) {
    #pragma unroll
    for (int i = 0; i < 2; ++i) {
      const int ch = ch0 + i;
      const int row = ch * 16 + rin;
      const u16* ga = A + (size_t)(m0 + row) * K + (k0 + cin);
      const u16* gb = Bt + (size_t)(n0 + row) * K + (k0 + cin);
      __builtin_amdgcn_global_load_lds((gvp)ga, (svp)(As + ch * 512), 16, 0, 0);
      __builtin_amdgcn_global_load_lds((gvp)gb, (svp)(Bs + ch * 512), 16, 0, 0);
    }
    __syncthreads();
    const int rf = lane & 15;
    const int qf = (lane >> 4) * 8;
    bf16x8 af[4], bfv[4];
    #pragma unroll
    for (int mi = 0; mi < 4; ++mi)
      af[mi] = *(const bf16x8*)(As + (wm + mi * 16 + rf) * 32 + qf);
    #pragma unroll
    for (int ni = 0; ni < 4; ++ni)
      bfv[ni] = *(const bf16x8*)(Bs + (wn + ni * 16 + rf) * 32 + qf);
    #pragma unroll
    for (int mi = 0; mi < 4; ++mi)
      #pragma unroll
      for (int ni = 0; ni < 4; ++ni)
        acc[mi][ni] = __builtin_amdgcn_mfma_f32_16x16x32_bf16(af[mi], bfv[ni], acc[mi][ni], 0, 0, 0);
    __syncthreads();
  }

  const int rq = (lane >> 4) * 4;
  const int cf = lane & 15;
  #pragma unroll
  for (int mi = 0; mi < 4; ++mi) {
    #pragma unroll
    for (int ni = 0; ni < 4; ++ni) {
      const int col = n0 + wn + ni * 16 + cf;
      #pragma unroll
      for (int r = 0; r < 4; ++r) {
        const int row = m0 + wm + mi * 16 + rq + r;
        const float v = acc[mi][ni][r];
        if (BF16OUT) {
          if (col < nvalid) ((u16*)Cout)[(size_t)row * ldc + col] = f2bf(v);
        } else {
          ((float*)Cout)[(size_t)row * ldc + col] = v;
        }
      }
    }
  }
}

// ---------------- fused gather + relu + LN + mean_k -------------------------
// MODE 0: bf16 X-row output (KP stride, pts tail)   MODE 1: bf16 flat 1024
template <int MODE>
__global__ __launch_bounds__(256) void h_epilogue_kernel(const float* __restrict__ Z1,
                                                         const float* __restrict__ Z2g,
                                                         const float* __restrict__ czero,
                                                         const int* __restrict__ idxK,
                                                         const int* __restrict__ fi,
                                                         const float* __restrict__ g,
                                                         const float* __restrict__ bb,
                                                         const float* __restrict__ npts,
                                                         void* __restrict__ outp,
                                                         int Np, int S) {
  __shared__ float r1[4];
  __shared__ float r2[4];
  int q = blockIdx.x;
  int b = q / S;
  int t = threadIdx.x;
  int lane = t & 63, wv = t >> 6;
  int fiv = fi[q];
  const f32x4* z2 = (const f32x4*)(Z2g + (size_t)q * 1024);
  const f32x4* zf = (const f32x4*)(Z1 + ((size_t)b * Np + fiv) * 1024);
  const f32x4* cz = (const f32x4*)czero;
  f32x4 base = z2[t] + cz[t] - zf[t];
  f32x4 gv = ((const f32x4*)g)[t];
  f32x4 bv = ((const f32x4*)bb)[t];
  f32x4 acc;
  #pragma unroll
  for (int c = 0; c < 4; ++c) acc[c] = 0.f;
  for (int k = 0; k < 24; ++k) {
    int n = idxK[(size_t)q * 24 + k];
    const f32x4* zr = (const f32x4*)(Z1 + ((size_t)b * Np + n) * 1024);
    f32x4 v = zr[t] + base;
    #pragma unroll
    for (int c = 0; c < 4; ++c) v[c] = fmaxf(v[c], 0.f);
    float s1 = v[0] + v[1] + v[2] + v[3];
    float s2 = v[0] * v[0] + v[1] * v[1] + v[2] * v[2] + v[3] * v[3];
    #pragma unroll
    for (int off = 32; off; off >>= 1) {
      s1 += __shfl_xor(s1, off);
      s2 += __shfl_xor(s2, off);
    }
    if (lane == 0) { r1[wv] = s1; r2[wv] = s2; }
    __syncthreads();
    s1 = r1[0] + r1[1] + r1[2] + r1[3];
    s2 = r2[0] + r2[1] + r2[2] + r2[3];
    __syncthreads();
    float m = s1 * (1.f / 1024.f);
    float var = s2 * (1.f / 1024.f) - m * m;
    float rs = rsqrtf(var + 1e-5f);
    #pragma unroll
    for (int c = 0; c < 4; ++c) acc[c] += (v[c] - m) * rs * gv[c] + bv[c];
  }
  #pragma unroll
  for (int c = 0; c < 4; ++c) acc[c] *= (1.f / 24.f);
  u16x4 o4;
  #pragma unroll
  for (int c = 0; c < 4; ++c) o4[c] = f2bf(acc[c]);
  if (MODE == 0) {
    u16* X = (u16*)outp;
    size_t ro = (size_t)q * KP;
    *(u16x4*)(X + ro + t * 4) = o4;
    if (t == 0) {
      X[ro + 1024] = f2bf(npts[(size_t)q * 2]);
      X[ro + 1025] = f2bf(npts[(size_t)q * 2 + 1]);
    }
    if (t < 15) ((u32*)(X + ro + 1026))[t] = 0;
  } else {
    *(u16x4*)((u16*)outp + (size_t)q * 1024 + t * 4) = o4;
  }
}

// ---------------- MLP MFMA GEMM: P[blk] = W_tile(fp32->bf16) @ Fb^T ---------
template <int KSBITS, int NST>
__global__ __launch_bounds__(256, 4) void mlp_mfma_kernel(const float* __restrict__ W,
                                                          const u16* __restrict__ Fb,
                                                          float* __restrict__ P, int K) {
  __shared__ __align__(16) float Asf[128 * 32];
  __shared__ __align__(16) u16 Fsb[32 * 40];
  const int tid = threadIdx.x, lane = tid & 63, wv = tid >> 6;
  const int ot = blockIdx.x >> KSBITS;
  const int ks = blockIdx.x & ((1 << KSBITS) - 1);
  const int m0 = ot * 128;
  const int k0b = ks * (NST * 32);
  const int arow = lane >> 3;
  const int agrp = lane & 7;
  const int rf = lane & 15, quad = lane >> 4;

  f32x4 acc[2][2];
  #pragma unroll
  for (int i = 0; i < 2; ++i)
    #pragma unroll
    for (int j = 0; j < 2; ++j)
      #pragma unroll
      for (int c = 0; c < 4; ++c) acc[i][j][c] = 0.f;

  for (int st = 0; st < NST; ++st) {
    const int k0 = k0b + st * 32;
    #pragma unroll
    for (int i = 0; i < 4; ++i) {
      const int row = wv * 32 + i * 8 + arow;
      const int g = agrp ^ (row & 7);
      const float* ga = W + (size_t)(m0 + row) * K + k0 + g * 4;
      __builtin_amdgcn_global_load_lds((gvp)ga, (svp)(Asf + (wv * 32 + i * 8) * 32), 16, 0, 0);
    }
    if (tid < 128) {
      const int fr = tid >> 2, fc = (tid & 3) * 8;
      u32x4 tmp = *(const u32x4*)(Fb + (size_t)fr * K + k0 + fc);
      *(u32x4*)(Fsb + fr * 40 + fc) = tmp;
    }
    __syncthreads();
    bf16x8 bfr[2];
    #pragma unroll
    for (int ni = 0; ni < 2; ++ni)
      bfr[ni] = *(const bf16x8*)(Fsb + (ni * 16 + rf) * 40 + quad * 8);
    #pragma unroll
    for (int mi = 0; mi < 2; ++mi) {
      const float* ap = Asf + (size_t)(wv * 32 + mi * 16 + rf) * 32;
      f32x4 a0 = *(const f32x4*)(ap + (((quad * 2) ^ (rf & 7)) * 4));
      f32x4 a1 = *(const f32x4*)(ap + (((quad * 2 + 1) ^ (rf & 7)) * 4));
      union { bf16x8 v; u16 h[8]; } af;
      #pragma unroll
      for (int c = 0; c < 4; ++c) { af.h[c] = f2bf(a0[c]); af.h[4 + c] = f2bf(a1[c]); }
      #pragma unroll
      for (int ni = 0; ni < 2; ++ni)
        acc[mi][ni] = __builtin_amdgcn_mfma_f32_16x16x32_bf16(af.v, bfr[ni], acc[mi][ni], 0, 0, 0);
    }
    __syncthreads();
  }

  float* Pb = P + (size_t)blockIdx.x * 4096;
  const int rq = (lane >> 4) * 4, cf = lane & 15;
  #pragma unroll
  for (int mi = 0; mi < 2; ++mi)
    #pragma unroll
    for (int ni = 0; ni < 2; ++ni)
      #pragma unroll
      for (int r = 0; r < 4; ++r)
        Pb[(wv * 32 + mi * 16 + rq + r) * 32 + ni * 16 + cf] = acc[mi][ni][r];
}

// ---------------- K-split partial reductions (bias fused) -------------------
__global__ __launch_bounds__(256) void reduce_flat_kernel(const float* __restrict__ P,
                                                          const float* __restrict__ bias,
                                                          u16* __restrict__ x1bf) {
  int idx = blockIdx.x * 256 + threadIdx.x;  // 32768
  int o = idx >> 5, b = idx & 31;
  float s = bias[o];
  const float* p = P + ((size_t)(o >> 7) * 64) * 4096 + (o & 127) * 32 + b;
  #pragma unroll 8
  for (int ks = 0; ks < 64; ++ks) s += p[(size_t)ks * 4096];
  x1bf[(size_t)b * 1024 + o] = f2bf(s);
}

__global__ __launch_bounds__(256) void reduce_dim_kernel(const float* __restrict__ P,
                                                         const float* __restrict__ bias,
                                                         float* __restrict__ out) {
  int idx = blockIdx.x * 256 + threadIdx.x;  // 131072
  int o = idx >> 5, b = idx & 31;
  float s = bias[o];
  const float* p = P + ((size_t)(o >> 7) * 8) * 4096 + (o & 127) * 32 + b;
  #pragma unroll
  for (int ks = 0; ks < 8; ++ks) s += p[(size_t)ks * 4096];
  out[(size_t)b * 4096 + o] = s;
}

// ---------------------------------------------------------------------------
extern "C" void kernel_launch(void* const* d_in, const int* in_sizes, int n_in,
                              void* d_out, int out_size, void* d_ws, size_t ws_size,
                              hipStream_t stream) {
  const float* fmap  = (const float*)d_in[0];
  const float* pts   = (const float*)d_in[1];
  const float* Wdiff = (const float*)d_in[2];
  const float* bdiff = (const float*)d_in[3];
  const float* Wagg  = (const float*)d_in[4];
  const float* bagg  = (const float*)d_in[5];
  const float* lng   = (const float*)d_in[6];
  const float* lnb   = (const float*)d_in[7];
  const float* Wflat = (const float*)d_in[8];
  const float* bflat = (const float*)d_in[9];
  const float* Wdim  = (const float*)d_in[10];
  const float* bdim  = (const float*)d_in[11];
  float* out = (float*)d_out;

  char* w = (char*)d_ws;
  size_t off = 0;
  auto alloc = [&](size_t n) { char* p = w + off; off += (n + 255) & ~(size_t)255; return p; };

  float* Z1    = (float*)alloc(16384ull * 1024 * 4);  // 67.1 MB
  float* Z2g   = (float*)alloc(4096ull * 1024 * 4);   // 16.8 MB
  u16* Xbf0  = (u16*)alloc(16384ull * KP * 2);
  u16* X1bf  = (u16*)alloc(4096ull * KP * 2);
  u16* Xg    = (u16*)alloc(4096ull * KP * 2);
  u16* WdT   = (u16*)alloc((size_t)NP0 * KP * 2);
  u16* Wa1   = (u16*)alloc(1024ull * KP * 2);
  u16* Wa2   = (u16*)alloc(1024ull * KP * 2);
  u16* Wcomb = (u16*)alloc(1024ull * KP * 2);
  float* czero = (float*)alloc(1024 * 4);
  int* fi0   = (int*)alloc(32 * 128 * 4);
  int* fi1   = (int*)alloc(32 * 32 * 4);
  int* idx0  = (int*)alloc(32 * 128 * 24 * 4);
  int* idx1  = (int*)alloc(32 * 32 * 24 * 4);
  float* npts0 = (float*)alloc(32 * 128 * 2 * 4);
  float* npts1 = (float*)alloc(32 * 32 * 2 * 4);
  u16* fea2bf = (u16*)alloc(32ull * 32768 * 2);       // 2 MB bf16
  u16* x1bf   = (u16*)alloc(32ull * 1024 * 2);        // 64 KB bf16
  float* Pf   = (float*)alloc(512ull * 4096 * 4);     // 8 MB partials (flat)
  float* Pd   = (float*)alloc(256ull * 4096 * 4);     // 4 MB partials (dim)

  // ---- stage-0 inputs
  bilinear_fused_kernel<<<dim3(32, 32), 256, 0, stream>>>(fmap, pts, Xbf0);

  // ---- stage 0 (Np=512, S=128): weight prep first, then Z1 GEMM with fps
  //      fused as the blockIdx.y==0 row (off the critical path).
  wd_transpose_kernel<<<dim3(33, 36), 256, 0, stream>>>(Wdiff, WdT);
  wagg_convert_kernel<<<1024, 256, 0, stream>>>(Wagg, Wa1, Wa2);
  czero_kernel<<<256, 256, 0, stream>>>(bdiff, Wagg, bagg, czero);
  gemm_bt_kernel<1, 0, 1><<<dim3(9, 8), 256, 0, stream>>>(Wa1, WdT, Wcomb, 1024, NP0, KP, KP, KP,
                                                          nullptr, nullptr, 0, 0);
  gemm_bt_kernel<0, 8, 2><<<dim3(8, 129), 256, 0, stream>>>(Xbf0, Wcomb, Z1, 16384, 1024, KP,
                                                            1024, 1024, pts, fi0, 512, 128);
  gather_fi_kernel<<<4096, 128, 0, stream>>>(Xbf0, pts, fi0, Xg, npts0, 512, 128);
  knn_kernel<8><<<1024, 256, 0, stream>>>(npts0, pts, idx0, 512, 128);
  gemm_bt_kernel<0, 0, 1><<<dim3(8, 32), 256, 0, stream>>>(Xg, Wa2, Z2g, 4096, 1024, KP,
                                                           1024, 1024, nullptr, nullptr, 0, 0);
  h_epilogue_kernel<0><<<4096, 256, 0, stream>>>(Z1, Z2g, czero, idx0, fi0, lng, lnb, npts0,
                                                 X1bf, 512, 128);

  // ---- stage 1 (Np=128, S=32): same structure; fps1 fused into Z1' GEMM
  wd_transpose_kernel<<<dim3(33, 36), 256, 0, stream>>>(Wdiff + 1026 * 1026, WdT);
  wagg_convert_kernel<<<1024, 256, 0, stream>>>(Wagg + 1024 * 2052, Wa1, Wa2);
  czero_kernel<<<256, 256, 0, stream>>>(bdiff + 1026, Wagg + 1024 * 2052, bagg + 1024, czero);
  gemm_bt_kernel<1, 0, 1><<<dim3(9, 8), 256, 0, stream>>>(Wa1, WdT, Wcomb, 1024, NP0, KP, KP, KP,
                                                          nullptr, nullptr, 0, 0);
  gemm_bt_kernel<0, 2, 1><<<dim3(8, 33), 256, 0, stream>>>(X1bf, Wcomb, Z1, 4096, 1024, KP,
                                                           1024, 1024, npts0, fi1, 128, 32);
  gather_fi_kernel<<<1024, 128, 0, stream>>>(X1bf, npts0, fi1, Xg, npts1, 128, 32);
  knn_kernel<2><<<256, 256, 0, stream>>>(npts1, npts0, idx1, 128, 32);
  gemm_bt_kernel<0, 0, 1><<<dim3(8, 8), 256, 0, stream>>>(Xg, Wa2, Z2g, 1024, 1024, KP,
                                                          1024, 1024, nullptr, nullptr, 0, 0);
  h_epilogue_kernel<1><<<1024, 256, 0, stream>>>(Z1, Z2g, czero, idx1, fi1, lng + 1024, lnb + 1024,
                                                 npts1, fea2bf, 128, 32);

  // ---- final MLP (MFMA, K-split partials + reduce)
  mlp_mfma_kernel<6, 16><<<512, 256, 0, stream>>>(Wflat, fea2bf, Pf, 32768);
  reduce_flat_kernel<<<128, 256, 0, stream>>>(Pf, bflat, x1bf);
  mlp_mfma_kernel<3, 4><<<256, 256, 0, stream>>>(Wdim, x1bf, Pd, 1024);
  reduce_dim_kernel<<<512, 256, 0, stream>>>(Pd, bdim, out);
}

// Round 4
// 643.648 us; speedup vs baseline: 1.2654x; 1.0674x over previous
//
#include <hip/hip_runtime.h>

// ---------------------------------------------------------------------------
// GeoRegionSampler: restructured pipeline
//   X = [bilinear_fea | pts] (bf16, padded 1026->1056); bilinear fused with
//   fmap channel-tile staging in LDS.
//   Wcomb = Wa1 @ Wd   (bf16 MFMA GEMM)
//   Z1 = X @ Wcomb^T ; Z2 = X[fi] @ Wa2^T ; czero = b_diff@Wa1^T + b_agg
//   h[b,s,k] = relu(Z1[idx]-Z1[fi]+Z2[s]+czero) -> LN -> mean_k  (fused;
//   emits fea2 as bf16)
//   final MLP: MFMA GEMMs streaming W as fp32 via global_load_lds.
// FPS/kNN: fp32 bit-exact (fp contract off), first-index tie-break.
// R7: fps fused into Z1 GEMM as blockIdx.y==0 row (off critical path);
//   value-only DPP fmax/fmin scan + ballot winner-lane location.
// R8: h_epilogue was #1 (78us; VALUBusy 44%, HBM 31%, FETCH 184MB vs 67MB
//   unique Z1). Rewritten wave-per-q: 16 ch/lane, LN mean/var via in-wave
//   DPP add-scan (row_shr1/2/4/8+bcast15/31, old=0) + readlane(63) -- zero
//   barriers, zero LDS, idxK preloaded lane-indexed + readlane per k.
//   XCD-bijective block swizzle ((bid&7)*cpx + bid>>3) keeps each batch's
//   Z1 slice resident in one XCD's L2 (kills the 2.7x over-fetch).
// ---------------------------------------------------------------------------

typedef float f32x4 __attribute__((ext_vector_type(4)));
typedef short bf16x8 __attribute__((ext_vector_type(8)));
typedef unsigned short u16;
typedef u16 u16x4 __attribute__((ext_vector_type(4)));
typedef unsigned int u32;
typedef u32 u32x4 __attribute__((ext_vector_type(4)));
typedef unsigned long long u64;

typedef const void __attribute__((address_space(1)))* gvp;
typedef void __attribute__((address_space(3)))* svp;

__device__ __forceinline__ u16 f2bf(float f) {
  union { float f; u32 u; } x; x.f = f;
  u32 r = x.u + 0x7fffu + ((x.u >> 16) & 1u);
  return (u16)(r >> 16);
}

#define KP 1056   // padded Dp (1026 -> 33*32)
#define NP0 1152  // padded N for weight-combine GEMM (9*128)

// ---- DPP cross-lane helpers (VALU pipe) -----------------------------------
__device__ __forceinline__ float rl_f(float v, int lane) {
  return __int_as_float(__builtin_amdgcn_readlane(__float_as_int(v), lane));
}

template <int CTRL>
__device__ __forceinline__ float dpp_fmax(float v) {
  float o = __int_as_float(__builtin_amdgcn_update_dpp(
      (int)0xff800000 /* -inf */, __float_as_int(v), CTRL, 0xf, 0xf, false));
  return fmaxf(v, o);
}

template <int CTRL>
__device__ __forceinline__ float dpp_fmin(float v) {
  float o = __int_as_float(__builtin_amdgcn_update_dpp(
      0x7f800000 /* +inf */, __float_as_int(v), CTRL, 0xf, 0xf, false));
  return fminf(v, o);
}

template <int CTRL>
__device__ __forceinline__ float dpp_add(float v) {
  float o = __int_as_float(__builtin_amdgcn_update_dpp(
      0, __float_as_int(v), CTRL, 0xf, 0xf, false));
  return v + o;
}

__device__ __forceinline__ float wave_fmax63(float v) {
  v = dpp_fmax<0x111>(v);  // row_shr:1
  v = dpp_fmax<0x112>(v);  // row_shr:2
  v = dpp_fmax<0x114>(v);  // row_shr:4
  v = dpp_fmax<0x118>(v);  // row_shr:8
  v = dpp_fmax<0x142>(v);  // row_bcast15
  v = dpp_fmax<0x143>(v);  // row_bcast31
  return rl_f(v, 63);
}

__device__ __forceinline__ float wave_fmin63(float v) {
  v = dpp_fmin<0x111>(v);
  v = dpp_fmin<0x112>(v);
  v = dpp_fmin<0x114>(v);
  v = dpp_fmin<0x118>(v);
  v = dpp_fmin<0x142>(v);
  v = dpp_fmin<0x143>(v);
  return rl_f(v, 63);
}

// full-wave sum, total lands in lane 63 (old=0 identity on invalid lanes:
// rows 0/2 unchanged by bcast15, rows 0/1 unchanged by bcast31 -> each
// contribution added exactly once).
__device__ __forceinline__ float wave_sum63(float v) {
  v = dpp_add<0x111>(v);
  v = dpp_add<0x112>(v);
  v = dpp_add<0x114>(v);
  v = dpp_add<0x118>(v);
  v = dpp_add<0x142>(v);
  v = dpp_add<0x143>(v);
  return v;
}

// ---------------- FPS core: one wave per batch, bit-exact -------------------
template <int PPL, int HS>
__device__ void fps_core(const float* __restrict__ pts, int* __restrict__ fi,
                         int Np, int S, int b, int lane) {
  #pragma clang fp contract(off)
  float px[PPL], py[PPL], dist[PPL];
  #pragma unroll
  for (int j = 0; j < PPL; ++j) {
    int n = j * 64 + lane;
    px[j] = pts[((size_t)b * Np + n) * 2];
    py[j] = pts[((size_t)b * Np + n) * 2 + 1];
    dist[j] = 1e10f;
  }
  int hist[HS];
  #pragma unroll
  for (int h = 0; h < HS; ++h) hist[h] = 0;
  int far = 0;
  float cx = rl_f(px[0], 0);
  float cy = rl_f(py[0], 0);
  for (int s = 0; s < S; ++s) {
    #pragma unroll
    for (int h = 0; h < HS; ++h)
      if ((s >> 6) == h && (s & 63) == lane) hist[h] = far;
    // distance update (independent across j)
    float tv[PPL]; int ti[PPL]; float tx[PPL], ty[PPL];
    #pragma unroll
    for (int j = 0; j < PPL; ++j) {
      float dx = px[j] - cx, dy = py[j] - cy;
      float d = dx * dx + dy * dy;
      float nd = fminf(dist[j], d);
      dist[j] = nd;
      tv[j] = nd; ti[j] = j * 64 + lane; tx[j] = px[j]; ty[j] = py[j];
    }
    // lane-local argmax tree (ties -> lower j = lower index; strict >)
    #pragma unroll
    for (int w = PPL; w > 1; w >>= 1)
      #pragma unroll
      for (int j = 0; j < (w >> 1); ++j)
        if (tv[j + (w >> 1)] > tv[j]) {
          tv[j] = tv[j + (w >> 1)]; ti[j] = ti[j + (w >> 1)];
          tx[j] = tx[j + (w >> 1)]; ty[j] = ty[j + (w >> 1)];
        }
    // value-only cross-lane max, then locate winner lane via ballot
    float smax = wave_fmax63(tv[0]);
    u64 mask = __ballot(tv[0] == smax);
    int L = __builtin_ctzll(mask);
    int fidx = __builtin_amdgcn_readlane(ti[0], L);
    float fx = rl_f(tx[0], L), fy = rl_f(ty[0], L);
    u64 rest = mask & (mask - 1);
    if (__builtin_expect(rest != 0, 0)) {
      // rare: multiple lanes hold the max value -> exact min-index tiebreak
      while (rest) {
        int L2 = __builtin_ctzll(rest);
        int c = __builtin_amdgcn_readlane(ti[0], L2);
        if (c < fidx) {
          fidx = c; fx = rl_f(tx[0], L2); fy = rl_f(ty[0], L2);
        }
        rest &= rest - 1;
      }
    }
    far = fidx; cx = fx; cy = fy;
  }
  #pragma unroll
  for (int h = 0; h < HS; ++h) {
    int s = h * 64 + lane;
    if (s < S) fi[b * S + s] = hist[h];
  }
}

// ------- fused bilinear: stage fmap[b][ct*32..+31][:] in LDS, interp -------
__global__ __launch_bounds__(256, 2) void bilinear_fused_kernel(const float* __restrict__ fmap,
                                                                const float* __restrict__ pts,
                                                                u16* __restrict__ X) {
  __shared__ float fmS[32][580];
  const int ct = blockIdx.x, b = blockIdx.y;
  const int t = threadIdx.x;
  const float* src = fmap + ((size_t)b * 1024 + ct * 32) * 576;
  const int tr = t >> 3, ti = t & 7;
  #pragma unroll
  for (int j = 0; j < 18; ++j) {
    int c4 = j * 8 + ti;
    *(f32x4*)&fmS[tr][c4 * 4] = *(const f32x4*)(src + (size_t)tr * 576 + c4 * 4);
  }
  __syncthreads();
  #pragma unroll
  for (int pass = 0; pass < 2; ++pass) {
    const int n = pass * 256 + t;
    const int pidx = b * 512 + n;
    float p0 = pts[(size_t)pidx * 2], p1 = pts[(size_t)pidx * 2 + 1];
    float gy = p0 * 23.f, gx = p1 * 23.f;
    float y0f = floorf(gy), x0f = floorf(gx);
    float wy = gy - y0f, wx = gx - x0f;
    int y0 = (int)y0f; y0 = y0 < 0 ? 0 : (y0 > 23 ? 23 : y0);
    int x0 = (int)x0f; x0 = x0 < 0 ? 0 : (x0 > 23 ? 23 : x0);
    int y1 = y0 + 1 > 23 ? 23 : y0 + 1;
    int x1 = x0 + 1 > 23 ? 23 : x0 + 1;
    float w00 = (1.f - wy) * (1.f - wx), w01 = (1.f - wy) * wx;
    float w10 = wy * (1.f - wx), w11 = wy * wx;
    const int i00 = y0 * 24 + x0, i01 = y0 * 24 + x1;
    const int i10 = y1 * 24 + x0, i11 = y1 * 24 + x1;
    size_t ro = (size_t)pidx * KP + ct * 32;
    #pragma unroll
    for (int cq = 0; cq < 8; ++cq) {
      u16x4 o4;
      #pragma unroll
      for (int cc = 0; cc < 4; ++cc) {
        int c = cq * 4 + cc;
        float v = w00 * fmS[c][i00] + w01 * fmS[c][i01] +
                  w10 * fmS[c][i10] + w11 * fmS[c][i11];
        o4[cc] = f2bf(v);
      }
      *(u16x4*)(X + ro + cq * 4) = o4;
    }
    if (ct == 31) {
      size_t rb = (size_t)pidx * KP;
      X[rb + 1024] = f2bf(p0);
      X[rb + 1025] = f2bf(p1);
      #pragma unroll
      for (int z = 0; z < 15; ++z) ((u32*)(X + rb + 1026))[z] = 0;
    }
  }
}

// ---------------- kNN: one wave per (b,s), bit-exact ------------------------
template <int PPL>
__global__ __launch_bounds__(256) void knn_kernel(const float* __restrict__ qpts,
                                                  const float* __restrict__ rpts,
                                                  int* __restrict__ idxK, int Np, int S) {
  #pragma clang fp contract(off)
  int lane = threadIdx.x & 63, wv = threadIdx.x >> 6;
  int q = blockIdx.x * 4 + wv;
  int b = q / S;
  float ax = qpts[(size_t)q * 2], ay = qpts[(size_t)q * 2 + 1];
  float a2 = ax * ax + ay * ay;
  float d2[PPL];
  #pragma unroll
  for (int j = 0; j < PPL; ++j) {
    int n = j * 64 + lane;
    float bx = rpts[((size_t)b * Np + n) * 2];
    float by = rpts[((size_t)b * Np + n) * 2 + 1];
    float b2 = bx * bx + by * by;
    float dot = ax * bx + ay * by;
    float t = a2 + b2;
    float m2 = 2.f * dot;
    d2[j] = t - m2;
  }
  int kreg = 0;
  for (int k = 0; k < 24; ++k) {
    float tv[PPL]; int ti[PPL];
    #pragma unroll
    for (int j = 0; j < PPL; ++j) { tv[j] = d2[j]; ti[j] = j * 64 + lane; }
    #pragma unroll
    for (int w = PPL; w > 1; w >>= 1)
      #pragma unroll
      for (int j = 0; j < (w >> 1); ++j)
        if (tv[j + (w >> 1)] < tv[j]) {
          tv[j] = tv[j + (w >> 1)]; ti[j] = ti[j + (w >> 1)];
        }
    float smin = wave_fmin63(tv[0]);
    u64 mask = __ballot(tv[0] == smin);
    int L = __builtin_ctzll(mask);
    int bs = __builtin_amdgcn_readlane(ti[0], L);
    u64 rest = mask & (mask - 1);
    if (__builtin_expect(rest != 0, 0)) {
      while (rest) {
        int L2 = __builtin_ctzll(rest);
        int c = __builtin_amdgcn_readlane(ti[0], L2);
        if (c < bs) bs = c;
        rest &= rest - 1;
      }
    }
    if (lane == k) kreg = bs;
    #pragma unroll
    for (int j = 0; j < PPL; ++j)
      if (j * 64 + lane == bs) d2[j] = 3.4e38f;
  }
  if (lane < 24) idxK[(size_t)q * 24 + lane] = kreg;
}

// ---------------- gather X rows at fi; emit new_pts -------------------------
__global__ __launch_bounds__(128) void gather_fi_kernel(const u16* __restrict__ Xsrc,
                                                        const float* __restrict__ pts,
                                                        const int* __restrict__ fi,
                                                        u16* __restrict__ Xg,
                                                        float* __restrict__ npts,
                                                        int Np, int S) {
  int q = blockIdx.x;
  int b = q / S;
  int t = threadIdx.x;
  int r = fi[q];
  const u32x4* src = (const u32x4*)(Xsrc + ((size_t)b * Np + r) * KP);
  u32x4* dst = (u32x4*)(Xg + (size_t)q * KP);
  dst[t] = src[t];
  int t2 = t + 128;
  if (t2 < 132) dst[t2] = src[t2];
  if (t == 0) {
    npts[(size_t)q * 2] = pts[((size_t)b * Np + r) * 2];
    npts[(size_t)q * 2 + 1] = pts[((size_t)b * Np + r) * 2 + 1];
  }
}

// ---------------- weight prep ----------------------------------------------
__global__ __launch_bounds__(256) void wd_transpose_kernel(const float* __restrict__ Wd,
                                                           u16* __restrict__ WdT) {
  __shared__ float tbuf[32][33];
  int tx = threadIdx.x & 31, ty = threadIdx.x >> 5;
  int ot = blockIdx.x * 32, dt = blockIdx.y * 32;
  #pragma unroll
  for (int j = 0; j < 4; ++j) {
    int o = ot + ty + 8 * j, d = dt + tx;
    tbuf[ty + 8 * j][tx] = (o < 1026 && d < 1026) ? Wd[(size_t)o * 1026 + d] : 0.f;
  }
  __syncthreads();
  #pragma unroll
  for (int j = 0; j < 4; ++j) {
    int d = dt + ty + 8 * j, o = ot + tx;
    if (o < KP) WdT[(size_t)d * KP + o] = f2bf(tbuf[tx][ty + 8 * j]);
  }
}

__global__ __launch_bounds__(256) void wagg_convert_kernel(const float* __restrict__ Wagg,
                                                           u16* __restrict__ Wa1,
                                                           u16* __restrict__ Wa2) {
  int c = blockIdx.x, t = threadIdx.x;
  const float* row = Wagg + (size_t)c * 2052;
  for (int d = t; d < KP; d += 256) {
    Wa1[(size_t)c * KP + d] = (d < 1026) ? f2bf(row[d]) : (u16)0;
    Wa2[(size_t)c * KP + d] = (d < 1026) ? f2bf(row[1026 + d]) : (u16)0;
  }
}

__global__ __launch_bounds__(256) void czero_kernel(const float* __restrict__ bdiff,
                                                    const float* __restrict__ Wagg,
                                                    const float* __restrict__ bagg,
                                                    float* __restrict__ czero) {
  int lane = threadIdx.x & 63, wv = threadIdx.x >> 6;
  int c = blockIdx.x * 4 + wv;
  float acc = 0.f;
  for (int o = lane; o < 1026; o += 64) acc += bdiff[o] * Wagg[(size_t)c * 2052 + o];
  #pragma unroll
  for (int off = 32; off; off >>= 1) acc += __shfl_xor(acc, off);
  if (lane == 0) czero[c] = acc + bagg[c];
}

// ---------------- bf16 MFMA GEMM: C[M,N] = A[M,K] @ Bt[N,K]^T ---------------
// FPS_PPL > 0: blockIdx.y==0 row runs fps_core (8 blocks x 4 waves = 32
// batches) concurrently with the GEMM blocks; GEMM rows shift down by 1.
template <int BF16OUT, int FPS_PPL, int FPS_HS>
__global__ __launch_bounds__(256) void gemm_bt_kernel(const u16* __restrict__ A,
                                                      const u16* __restrict__ Bt,
                                                      void* __restrict__ Cout,
                                                      int M, int N, int K, int ldc, int nvalid,
                                                      const float* __restrict__ fpts,
                                                      int* __restrict__ ffi,
                                                      int fNp, int fS) {
  const int tid = threadIdx.x;
  const int lane = tid & 63;
  const int wv = tid >> 6;
  if (FPS_PPL > 0 && blockIdx.y == 0) {
    fps_core<FPS_PPL ? FPS_PPL : 1, FPS_HS>(fpts, ffi, fNp, fS, blockIdx.x * 4 + wv, lane);
    return;
  }
  __shared__ __align__(16) u16 As[128 * 32];
  __shared__ __align__(16) u16 Bs[128 * 32];
  const int m0 = (blockIdx.y - (FPS_PPL > 0 ? 1 : 0)) * 128;
  const int n0 = blockIdx.x * 128;
  const int wm = (wv >> 1) * 64;
  const int wn = (wv & 1) * 64;

  f32x4 acc[4][4];
  #pragma unroll
  for (int i = 0; i < 4; ++i)
    #pragma unroll
    for (int j = 0; j < 4; ++j)
      #pragma unroll
      for (int c = 0; c < 4; ++c) acc[i][j][c] = 0.f;

  const int ch0 = wv * 2;
  const int rin = lane >> 2;
  const int cin = (lane & 3) * 8;

  for (int k0 = 0; k0 < K; k0 += 32) {
    #pragma unroll
    for (int i = 0; i < 2; ++i) {
      const int ch = ch0 + i;
      const int row = ch * 16 + rin;
      const u16* ga = A + (size_t)(m0 + row) * K + (k0 + cin);
      const u16* gb = Bt + (size_t)(n0 + row) * K + (k0 + cin);
      __builtin_amdgcn_global_load_lds((gvp)ga, (svp)(As + ch * 512), 16, 0, 0);
      __builtin_amdgcn_global_load_lds((gvp)gb, (svp)(Bs + ch * 512), 16, 0, 0);
    }
    __syncthreads();
    const int rf = lane & 15;
    const int qf = (lane >> 4) * 8;
    bf16x8 af[4], bfv[4];
    #pragma unroll
    for (int mi = 0; mi < 4; ++mi)
      af[mi] = *(const bf16x8*)(As + (wm + mi * 16 + rf) * 32 + qf);
    #pragma unroll
    for (int ni = 0; ni < 4; ++ni)
      bfv[ni] = *(const bf16x8*)(Bs + (wn + ni * 16 + rf) * 32 + qf);
    #pragma unroll
    for (int mi = 0; mi < 4; ++mi)
      #pragma unroll
      for (int ni = 0; ni < 4; ++ni)
        acc[mi][ni] = __builtin_amdgcn_mfma_f32_16x16x32_bf16(af[mi], bfv[ni], acc[mi][ni], 0, 0, 0);
    __syncthreads();
  }

  const int rq = (lane >> 4) * 4;
  const int cf = lane & 15;
  #pragma unroll
  for (int mi = 0; mi < 4; ++mi) {
    #pragma unroll
    for (int ni = 0; ni < 4; ++ni) {
      const int col = n0 + wn + ni * 16 + cf;
      #pragma unroll
      for (int r = 0; r < 4; ++r) {
        const int row = m0 + wm + mi * 16 + rq + r;
        const float v = acc[mi][ni][r];
        if (BF16OUT) {
          if (col < nvalid) ((u16*)Cout)[(size_t)row * ldc + col] = f2bf(v);
        } else {
          ((float*)Cout)[(size_t)row * ldc + col] = v;
        }
      }
    }
  }
}

// ---------------- fused gather + relu + LN + mean_k -------------------------
// Wave-per-q: 16 ch/lane (4x f32x4 coalesced), LN reductions via in-wave DPP
// add-scan + readlane(63). No barriers, no LDS. XCD-bijective block swizzle.
// MODE 0: bf16 X-row output (KP stride, pts tail)   MODE 1: bf16 flat 1024
template <int MODE>
__global__ __launch_bounds__(256) void h_epilogue_kernel(const float* __restrict__ Z1,
                                                         const float* __restrict__ Z2g,
                                                         const float* __restrict__ czero,
                                                         const int* __restrict__ idxK,
                                                         const int* __restrict__ fi,
                                                         const float* __restrict__ g,
                                                         const float* __restrict__ bb,
                                                         const float* __restrict__ npts,
                                                         void* __restrict__ outp,
                                                         int Np, int S, int cpx) {
  const int bid = blockIdx.x;
  const int sw = (bid & 7) * cpx + (bid >> 3);  // XCD-contiguous q ranges
  const int t = threadIdx.x;
  const int lane = t & 63, wv = t >> 6;
  const int q = sw * 4 + wv;
  const int b = q / S;
  const int fiv = fi[q];
  const float* z2 = Z2g + (size_t)q * 1024;
  const float* zf = Z1 + ((size_t)b * Np + fiv) * 1024;
  const int ch = lane * 4;  // + j*256

  f32x4 base[4], gv[4], bv[4], acc[4];
  #pragma unroll
  for (int j = 0; j < 4; ++j) {
    f32x4 a = *(const f32x4*)(z2 + j * 256 + ch);
    f32x4 c = *(const f32x4*)(czero + j * 256 + ch);
    f32x4 f = *(const f32x4*)(zf + j * 256 + ch);
    #pragma unroll
    for (int c2 = 0; c2 < 4; ++c2) base[j][c2] = a[c2] + c[c2] - f[c2];
    gv[j] = *(const f32x4*)(g + j * 256 + ch);
    bv[j] = *(const f32x4*)(bb + j * 256 + ch);
    #pragma unroll
    for (int c2 = 0; c2 < 4; ++c2) acc[j][c2] = 0.f;
  }
  int nk = 0;
  if (lane < 24) nk = idxK[(size_t)q * 24 + lane];

  for (int k = 0; k < 24; ++k) {
    const int n = __builtin_amdgcn_readlane(nk, k);
    const float* zr = Z1 + ((size_t)b * Np + n) * 1024;
    f32x4 v[4];
    float s1 = 0.f, s2 = 0.f;
    #pragma unroll
    for (int j = 0; j < 4; ++j) {
      f32x4 r = *(const f32x4*)(zr + j * 256 + ch);
      #pragma unroll
      for (int c2 = 0; c2 < 4; ++c2) {
        float x = fmaxf(r[c2] + base[j][c2], 0.f);
        v[j][c2] = x;
        s1 += x;
        s2 += x * x;
      }
    }
    s1 = wave_sum63(s1);
    s2 = wave_sum63(s2);
    const float S1 = rl_f(s1, 63);
    const float S2 = rl_f(s2, 63);
    const float m = S1 * (1.f / 1024.f);
    const float var = S2 * (1.f / 1024.f) - m * m;
    const float rs = rsqrtf(var + 1e-5f);
    #pragma unroll
    for (int j = 0; j < 4; ++j)
      #pragma unroll
      for (int c2 = 0; c2 < 4; ++c2)
        acc[j][c2] += (v[j][c2] - m) * rs * gv[j][c2] + bv[j][c2];
  }

  u16x4 o4[4];
  #pragma unroll
  for (int j = 0; j < 4; ++j)
    #pragma unroll
    for (int c2 = 0; c2 < 4; ++c2) o4[j][c2] = f2bf(acc[j][c2] * (1.f / 24.f));

  if (MODE == 0) {
    u16* X = (u16*)outp;
    size_t ro = (size_t)q * KP;
    #pragma unroll
    for (int j = 0; j < 4; ++j) *(u16x4*)(X + ro + j * 256 + ch) = o4[j];
    if (lane == 0) {
      X[ro + 1024] = f2bf(npts[(size_t)q * 2]);
      X[ro + 1025] = f2bf(npts[(size_t)q * 2 + 1]);
    }
    if (lane < 15) ((u32*)(X + ro + 1026))[lane] = 0;
  } else {
    u16* X = (u16*)outp + (size_t)q * 1024;
    #pragma unroll
    for (int j = 0; j < 4; ++j) *(u16x4*)(X + j * 256 + ch) = o4[j];
  }
}

// ---------------- MLP MFMA GEMM: P[blk] = W_tile(fp32->bf16) @ Fb^T ---------
template <int KSBITS, int NST>
__global__ __launch_bounds__(256, 4) void mlp_mfma_kernel(const float* __restrict__ W,
                                                          const u16* __restrict__ Fb,
                                                          float* __restrict__ P, int K) {
  __shared__ __align__(16) float Asf[128 * 32];
  __shared__ __align__(16) u16 Fsb[32 * 40];
  const int tid = threadIdx.x, lane = tid & 63, wv = tid >> 6;
  const int ot = blockIdx.x >> KSBITS;
  const int ks = blockIdx.x & ((1 << KSBITS) - 1);
  const int m0 = ot * 128;
  const int k0b = ks * (NST * 32);
  const int arow = lane >> 3;
  const int agrp = lane & 7;
  const int rf = lane & 15, quad = lane >> 4;

  f32x4 acc[2][2];
  #pragma unroll
  for (int i = 0; i < 2; ++i)
    #pragma unroll
    for (int j = 0; j < 2; ++j)
      #pragma unroll
      for (int c = 0; c < 4; ++c) acc[i][j][c] = 0.f;

  for (int st = 0; st < NST; ++st) {
    const int k0 = k0b + st * 32;
    #pragma unroll
    for (int i = 0; i < 4; ++i) {
      const int row = wv * 32 + i * 8 + arow;
      const int g = agrp ^ (row & 7);
      const float* ga = W + (size_t)(m0 + row) * K + k0 + g * 4;
      __builtin_amdgcn_global_load_lds((gvp)ga, (svp)(Asf + (wv * 32 + i * 8) * 32), 16, 0, 0);
    }
    if (tid < 128) {
      const int fr = tid >> 2, fc = (tid & 3) * 8;
      u32x4 tmp = *(const u32x4*)(Fb + (size_t)fr * K + k0 + fc);
      *(u32x4*)(Fsb + fr * 40 + fc) = tmp;
    }
    __syncthreads();
    bf16x8 bfr[2];
    #pragma unroll
    for (int ni = 0; ni < 2; ++ni)
      bfr[ni] = *(const bf16x8*)(Fsb + (ni * 16 + rf) * 40 + quad * 8);
    #pragma unroll
    for (int mi = 0; mi < 2; ++mi) {
      const float* ap = Asf + (size_t)(wv * 32 + mi * 16 + rf) * 32;
      f32x4 a0 = *(const f32x4*)(ap + (((quad * 2) ^ (rf & 7)) * 4));
      f32x4 a1 = *(const f32x4*)(ap + (((quad * 2 + 1) ^ (rf & 7)) * 4));
      union { bf16x8 v; u16 h[8]; } af;
      #pragma unroll
      for (int c = 0; c < 4; ++c) { af.h[c] = f2bf(a0[c]); af.h[4 + c] = f2bf(a1[c]); }
      #pragma unroll
      for (int ni = 0; ni < 2; ++ni)
        acc[mi][ni] = __builtin_amdgcn_mfma_f32_16x16x32_bf16(af.v, bfr[ni], acc[mi][ni], 0, 0, 0);
    }
    __syncthreads();
  }

  float* Pb = P + (size_t)blockIdx.x * 4096;
  const int rq = (lane >> 4) * 4, cf = lane & 15;
  #pragma unroll
  for (int mi = 0; mi < 2; ++mi)
    #pragma unroll
    for (int ni = 0; ni < 2; ++ni)
      #pragma unroll
      for (int r = 0; r < 4; ++r)
        Pb[(wv * 32 + mi * 16 + rq + r) * 32 + ni * 16 + cf] = acc[mi][ni][r];
}

// ---------------- K-split partial reductions (bias fused) -------------------
__global__ __launch_bounds__(256) void reduce_flat_kernel(const float* __restrict__ P,
                                                          const float* __restrict__ bias,
                                                          u16* __restrict__ x1bf) {
  int idx = blockIdx.x * 256 + threadIdx.x;  // 32768
  int o = idx >> 5, b = idx & 31;
  float s = bias[o];
  const float* p = P + ((size_t)(o >> 7) * 64) * 4096 + (o & 127) * 32 + b;
  #pragma unroll 8
  for (int ks = 0; ks < 64; ++ks) s += p[(size_t)ks * 4096];
  x1bf[(size_t)b * 1024 + o] = f2bf(s);
}

__global__ __launch_bounds__(256) void reduce_dim_kernel(const float* __restrict__ P,
                                                         const float* __restrict__ bias,
                                                         float* __restrict__ out) {
  int idx = blockIdx.x * 256 + threadIdx.x;  // 131072
  int o = idx >> 5, b = idx & 31;
  float s = bias[o];
  const float* p = P + ((size_t)(o >> 7) * 8) * 4096 + (o & 127) * 32 + b;
  #pragma unroll
  for (int ks = 0; ks < 8; ++ks) s += p[(size_t)ks * 4096];
  out[(size_t)b * 4096 + o] = s;
}

// ---------------------------------------------------------------------------
extern "C" void kernel_launch(void* const* d_in, const int* in_sizes, int n_in,
                              void* d_out, int out_size, void* d_ws, size_t ws_size,
                              hipStream_t stream) {
  const float* fmap  = (const float*)d_in[0];
  const float* pts   = (const float*)d_in[1];
  const float* Wdiff = (const float*)d_in[2];
  const float* bdiff = (const float*)d_in[3];
  const float* Wagg  = (const float*)d_in[4];
  const float* bagg  = (const float*)d_in[5];
  const float* lng   = (const float*)d_in[6];
  const float* lnb   = (const float*)d_in[7];
  const float* Wflat = (const float*)d_in[8];
  const float* bflat = (const float*)d_in[9];
  const float* Wdim  = (const float*)d_in[10];
  const float* bdim  = (const float*)d_in[11];
  float* out = (float*)d_out;

  char* w = (char*)d_ws;
  size_t off = 0;
  auto alloc = [&](size_t n) { char* p = w + off; off += (n + 255) & ~(size_t)255; return p; };

  float* Z1    = (float*)alloc(16384ull * 1024 * 4);  // 67.1 MB
  float* Z2g   = (float*)alloc(4096ull * 1024 * 4);   // 16.8 MB
  u16* Xbf0  = (u16*)alloc(16384ull * KP * 2);
  u16* X1bf  = (u16*)alloc(4096ull * KP * 2);
  u16* Xg    = (u16*)alloc(4096ull * KP * 2);
  u16* WdT   = (u16*)alloc((size_t)NP0 * KP * 2);
  u16* Wa1   = (u16*)alloc(1024ull * KP * 2);
  u16* Wa2   = (u16*)alloc(1024ull * KP * 2);
  u16* Wcomb = (u16*)alloc(1024ull * KP * 2);
  float* czero = (float*)alloc(1024 * 4);
  int* fi0   = (int*)alloc(32 * 128 * 4);
  int* fi1   = (int*)alloc(32 * 32 * 4);
  int* idx0  = (int*)alloc(32 * 128 * 24 * 4);
  int* idx1  = (int*)alloc(32 * 32 * 24 * 4);
  float* npts0 = (float*)alloc(32 * 128 * 2 * 4);
  float* npts1 = (float*)alloc(32 * 32 * 2 * 4);
  u16* fea2bf = (u16*)alloc(32ull * 32768 * 2);       // 2 MB bf16
  u16* x1bf   = (u16*)alloc(32ull * 1024 * 2);        // 64 KB bf16
  float* Pf   = (float*)alloc(512ull * 4096 * 4);     // 8 MB partials (flat)
  float* Pd   = (float*)alloc(256ull * 4096 * 4);     // 4 MB partials (dim)

  // ---- stage-0 inputs
  bilinear_fused_kernel<<<dim3(32, 32), 256, 0, stream>>>(fmap, pts, Xbf0);

  // ---- stage 0 (Np=512, S=128): weight prep first, then Z1 GEMM with fps
  //      fused as the blockIdx.y==0 row (off the critical path).
  wd_transpose_kernel<<<dim3(33, 36), 256, 0, stream>>>(Wdiff, WdT);
  wagg_convert_kernel<<<1024, 256, 0, stream>>>(Wagg, Wa1, Wa2);
  czero_kernel<<<256, 256, 0, stream>>>(bdiff, Wagg, bagg, czero);
  gemm_bt_kernel<1, 0, 1><<<dim3(9, 8), 256, 0, stream>>>(Wa1, WdT, Wcomb, 1024, NP0, KP, KP, KP,
                                                          nullptr, nullptr, 0, 0);
  gemm_bt_kernel<0, 8, 2><<<dim3(8, 129), 256, 0, stream>>>(Xbf0, Wcomb, Z1, 16384, 1024, KP,
                                                            1024, 1024, pts, fi0, 512, 128);
  gather_fi_kernel<<<4096, 128, 0, stream>>>(Xbf0, pts, fi0, Xg, npts0, 512, 128);
  knn_kernel<8><<<1024, 256, 0, stream>>>(npts0, pts, idx0, 512, 128);
  gemm_bt_kernel<0, 0, 1><<<dim3(8, 32), 256, 0, stream>>>(Xg, Wa2, Z2g, 4096, 1024, KP,
                                                           1024, 1024, nullptr, nullptr, 0, 0);
  h_epilogue_kernel<0><<<1024, 256, 0, stream>>>(Z1, Z2g, czero, idx0, fi0, lng, lnb, npts0,
                                                 X1bf, 512, 128, 128);

  // ---- stage 1 (Np=128, S=32): same structure; fps1 fused into Z1' GEMM
  wd_transpose_kernel<<<dim3(33, 36), 256, 0, stream>>>(Wdiff + 1026 * 1026, WdT);
  wagg_convert_kernel<<<1024, 256, 0, stream>>>(Wagg + 1024 * 2052, Wa1, Wa2);
  czero_kernel<<<256, 256, 0, stream>>>(bdiff + 1026, Wagg + 1024 * 2052, bagg + 1024, czero);
  gemm_bt_kernel<1, 0, 1><<<dim3(9, 8), 256, 0, stream>>>(Wa1, WdT, Wcomb, 1024, NP0, KP, KP, KP,
                                                          nullptr, nullptr, 0, 0);
  gemm_bt_kernel<0, 2, 1><<<dim3(8, 33), 256, 0, stream>>>(X1bf, Wcomb, Z1, 4096, 1024, KP,
                                                           1024, 1024, npts0, fi1, 128, 32);
  gather_fi_kernel<<<1024, 128, 0, stream>>>(X1bf, npts0, fi1, Xg, npts1, 128, 32);
  knn_kernel<2><<<256, 256, 0, stream>>>(npts1, npts0, idx1, 128, 32);
  gemm_bt_kernel<0, 0, 1><<<dim3(8, 8), 256, 0, stream>>>(Xg, Wa2, Z2g, 1024, 1024, KP,
                                                          1024, 1024, nullptr, nullptr, 0, 0);
  h_epilogue_kernel<1><<<256, 256, 0, stream>>>(Z1, Z2g, czero, idx1, fi1, lng + 1024, lnb + 1024,
                                                npts1, fea2bf, 128, 32, 32);

  // ---- final MLP (MFMA, K-split partials + reduce)
  mlp_mfma_kernel<6, 16><<<512, 256, 0, stream>>>(Wflat, fea2bf, Pf, 32768);
  reduce_flat_kernel<<<128, 256, 0, stream>>>(Pf, bflat, x1bf);
  mlp_mfma_kernel<3, 4><<<256, 256, 0, stream>>>(Wdim, x1bf, Pd, 1024);
  reduce_dim_kernel<<<512, 256, 0, stream>>>(Pd, bdim, out);
}

// Round 5
// 623.906 us; speedup vs baseline: 1.3054x; 1.0316x over previous
//
#include <hip/hip_runtime.h>

// ---------------------------------------------------------------------------
// GeoRegionSampler: restructured pipeline
//   X = [bilinear_fea | pts] (bf16, padded 1026->1056)
//   Wcomb = Wa1 @ Wd ; Z1 = X @ Wcomb^T ; Z2 = X[fi] @ Wa2^T
//   h = relu(Z1[idx]-Z1[fi]+Z2+czero) -> LN -> mean_k (wave-per-q, DPP)
//   final MLP: MFMA GEMMs + K-split reduce.
// R9 (this round):
//   - fps0 chain SPLIT: iters [0,48) fused into bilinear (y==0 row), state
//     (dist/far) spilled bit-exact to scratch; iters [48,128) resume in the
//     Z1 GEMM's y==0 row. fps1 [0,32) moves under h_epilogue<0>'s shadow.
//     (The ~1680cyc/iter chain itself is at the lone-wave issue floor --
//     R1/R2 both failed to shorten it; we hide it instead.)
//   - gemm_bt: LDS bank conflicts (4.3M, 8-way on ds_read_b128) fixed via
//     both-sides XOR swizzle: global source col8 ^= (row&3)^((row>>2)&3),
//     linear LDS dest (rule #21), same involution on the read slot.
//   - gemm_bt: XCD-bijective tile remap (mt = xcd*(MT/8) + r>>3, nt = r&7)
//     so the 8 n-blocks sharing an A-tile land on one XCD's L2
//     (FETCH 142MB -> ~60MB expected).
//   - knn fused into Z2 GEMM dispatches (extra y rows) -- overlaps ~15us
//     of knn under ~18us of GEMM instead of serializing.
// ---------------------------------------------------------------------------

typedef float f32x4 __attribute__((ext_vector_type(4)));
typedef short bf16x8 __attribute__((ext_vector_type(8)));
typedef unsigned short u16;
typedef u16 u16x4 __attribute__((ext_vector_type(4)));
typedef unsigned int u32;
typedef u32 u32x4 __attribute__((ext_vector_type(4)));
typedef unsigned long long u64;

typedef const void __attribute__((address_space(1)))* gvp;
typedef void __attribute__((address_space(3)))* svp;

__device__ __forceinline__ u16 f2bf(float f) {
  union { float f; u32 u; } x; x.f = f;
  u32 r = x.u + 0x7fffu + ((x.u >> 16) & 1u);
  return (u16)(r >> 16);
}

#define KP 1056   // padded Dp (1026 -> 33*32)
#define NP0 1152  // padded N for weight-combine GEMM (9*128)

// ---- DPP cross-lane helpers (VALU pipe) -----------------------------------
__device__ __forceinline__ float rl_f(float v, int lane) {
  return __int_as_float(__builtin_amdgcn_readlane(__float_as_int(v), lane));
}

template <int CTRL>
__device__ __forceinline__ float dpp_fmax(float v) {
  float o = __int_as_float(__builtin_amdgcn_update_dpp(
      (int)0xff800000 /* -inf */, __float_as_int(v), CTRL, 0xf, 0xf, false));
  return fmaxf(v, o);
}

template <int CTRL>
__device__ __forceinline__ float dpp_fmin(float v) {
  float o = __int_as_float(__builtin_amdgcn_update_dpp(
      0x7f800000 /* +inf */, __float_as_int(v), CTRL, 0xf, 0xf, false));
  return fminf(v, o);
}

template <int CTRL>
__device__ __forceinline__ float dpp_add(float v) {
  float o = __int_as_float(__builtin_amdgcn_update_dpp(
      0, __float_as_int(v), CTRL, 0xf, 0xf, false));
  return v + o;
}

__device__ __forceinline__ float wave_fmax63(float v) {
  v = dpp_fmax<0x111>(v);
  v = dpp_fmax<0x112>(v);
  v = dpp_fmax<0x114>(v);
  v = dpp_fmax<0x118>(v);
  v = dpp_fmax<0x142>(v);
  v = dpp_fmax<0x143>(v);
  return rl_f(v, 63);
}

__device__ __forceinline__ float wave_fmin63(float v) {
  v = dpp_fmin<0x111>(v);
  v = dpp_fmin<0x112>(v);
  v = dpp_fmin<0x114>(v);
  v = dpp_fmin<0x118>(v);
  v = dpp_fmin<0x142>(v);
  v = dpp_fmin<0x143>(v);
  return rl_f(v, 63);
}

__device__ __forceinline__ float wave_sum63(float v) {
  v = dpp_add<0x111>(v);
  v = dpp_add<0x112>(v);
  v = dpp_add<0x114>(v);
  v = dpp_add<0x118>(v);
  v = dpp_add<0x142>(v);
  v = dpp_add<0x143>(v);
  return v;
}

// ---------------- FPS core: one wave per batch, bit-exact -------------------
// Resumable: runs iterations [s0,s1); dist/far state spilled/reloaded as raw
// fp32 bits (exact). hist entries only for its own range.
template <int PPL, int HS>
__device__ void fps_core(const float* __restrict__ pts, int* __restrict__ fi,
                         int Np, int S, int b, int lane, int s0, int s1,
                         float* __restrict__ dsave, int* __restrict__ fsave) {
  #pragma clang fp contract(off)
  float px[PPL], py[PPL], dist[PPL];
  #pragma unroll
  for (int j = 0; j < PPL; ++j) {
    int n = j * 64 + lane;
    px[j] = pts[((size_t)b * Np + n) * 2];
    py[j] = pts[((size_t)b * Np + n) * 2 + 1];
  }
  int far; float cx, cy;
  if (s0 == 0) {
    #pragma unroll
    for (int j = 0; j < PPL; ++j) dist[j] = 1e10f;
    far = 0;
    cx = rl_f(px[0], 0);
    cy = rl_f(py[0], 0);
  } else {
    #pragma unroll
    for (int j = 0; j < PPL; ++j) dist[j] = dsave[(size_t)b * Np + j * 64 + lane];
    far = fsave[b];
    cx = pts[((size_t)b * Np + far) * 2];
    cy = pts[((size_t)b * Np + far) * 2 + 1];
  }
  int hist[HS];
  #pragma unroll
  for (int h = 0; h < HS; ++h) hist[h] = 0;
  for (int s = s0; s < s1; ++s) {
    #pragma unroll
    for (int h = 0; h < HS; ++h)
      if ((s >> 6) == h && (s & 63) == lane) hist[h] = far;
    float tv[PPL]; int ti[PPL]; float tx[PPL], ty[PPL];
    #pragma unroll
    for (int j = 0; j < PPL; ++j) {
      float dx = px[j] - cx, dy = py[j] - cy;
      float d = dx * dx + dy * dy;
      float nd = fminf(dist[j], d);
      dist[j] = nd;
      tv[j] = nd; ti[j] = j * 64 + lane; tx[j] = px[j]; ty[j] = py[j];
    }
    #pragma unroll
    for (int w = PPL; w > 1; w >>= 1)
      #pragma unroll
      for (int j = 0; j < (w >> 1); ++j)
        if (tv[j + (w >> 1)] > tv[j]) {
          tv[j] = tv[j + (w >> 1)]; ti[j] = ti[j + (w >> 1)];
          tx[j] = tx[j + (w >> 1)]; ty[j] = ty[j + (w >> 1)];
        }
    float smax = wave_fmax63(tv[0]);
    u64 mask = __ballot(tv[0] == smax);
    int L = __builtin_ctzll(mask);
    int fidx = __builtin_amdgcn_readlane(ti[0], L);
    float fx = rl_f(tx[0], L), fy = rl_f(ty[0], L);
    u64 rest = mask & (mask - 1);
    if (__builtin_expect(rest != 0, 0)) {
      while (rest) {
        int L2 = __builtin_ctzll(rest);
        int c = __builtin_amdgcn_readlane(ti[0], L2);
        if (c < fidx) {
          fidx = c; fx = rl_f(tx[0], L2); fy = rl_f(ty[0], L2);
        }
        rest &= rest - 1;
      }
    }
    far = fidx; cx = fx; cy = fy;
  }
  if (s1 < S) {
    #pragma unroll
    for (int j = 0; j < PPL; ++j) dsave[(size_t)b * Np + j * 64 + lane] = dist[j];
    if (lane == 0) fsave[b] = far;
  }
  #pragma unroll
  for (int h = 0; h < HS; ++h) {
    int s = h * 64 + lane;
    if (s >= s0 && s < s1) fi[b * S + s] = hist[h];
  }
}

// ---------------- kNN core: one wave per q, bit-exact -----------------------
template <int PPL>
__device__ void knn_core(const float* __restrict__ qpts,
                         const float* __restrict__ rpts,
                         int* __restrict__ idxK, int Np, int S, int q, int lane) {
  #pragma clang fp contract(off)
  int b = q / S;
  float ax = qpts[(size_t)q * 2], ay = qpts[(size_t)q * 2 + 1];
  float a2 = ax * ax + ay * ay;
  float d2[PPL];
  #pragma unroll
  for (int j = 0; j < PPL; ++j) {
    int n = j * 64 + lane;
    float bx = rpts[((size_t)b * Np + n) * 2];
    float by = rpts[((size_t)b * Np + n) * 2 + 1];
    float b2 = bx * bx + by * by;
    float dot = ax * bx + ay * by;
    float t = a2 + b2;
    float m2 = 2.f * dot;
    d2[j] = t - m2;
  }
  int kreg = 0;
  for (int k = 0; k < 24; ++k) {
    float tv[PPL]; int ti[PPL];
    #pragma unroll
    for (int j = 0; j < PPL; ++j) { tv[j] = d2[j]; ti[j] = j * 64 + lane; }
    #pragma unroll
    for (int w = PPL; w > 1; w >>= 1)
      #pragma unroll
      for (int j = 0; j < (w >> 1); ++j)
        if (tv[j + (w >> 1)] < tv[j]) {
          tv[j] = tv[j + (w >> 1)]; ti[j] = ti[j + (w >> 1)];
        }
    float smin = wave_fmin63(tv[0]);
    u64 mask = __ballot(tv[0] == smin);
    int L = __builtin_ctzll(mask);
    int bs = __builtin_amdgcn_readlane(ti[0], L);
    u64 rest = mask & (mask - 1);
    if (__builtin_expect(rest != 0, 0)) {
      while (rest) {
        int L2 = __builtin_ctzll(rest);
        int c = __builtin_amdgcn_readlane(ti[0], L2);
        if (c < bs) bs = c;
        rest &= rest - 1;
      }
    }
    if (lane == k) kreg = bs;
    #pragma unroll
    for (int j = 0; j < PPL; ++j)
      if (j * 64 + lane == bs) d2[j] = 3.4e38f;
  }
  if (lane < 24) idxK[(size_t)q * 24 + lane] = kreg;
}

// ------- fused bilinear + fps0 segment [0,48) (y==0 row) -------------------
__global__ __launch_bounds__(256, 2) void bilinear_fused_kernel(const float* __restrict__ fmap,
                                                                const float* __restrict__ pts,
                                                                u16* __restrict__ X,
                                                                int* __restrict__ fi0,
                                                                float* __restrict__ fdist,
                                                                int* __restrict__ ffar) {
  if (blockIdx.y == 0) {
    if (blockIdx.x < 8)
      fps_core<8, 2>(pts, fi0, 512, 128, blockIdx.x * 4 + (threadIdx.x >> 6),
                     threadIdx.x & 63, 0, 48, fdist, ffar);
    return;
  }
  __shared__ float fmS[32][580];
  const int ct = blockIdx.x, b = blockIdx.y - 1;
  const int t = threadIdx.x;
  const float* src = fmap + ((size_t)b * 1024 + ct * 32) * 576;
  const int tr = t >> 3, ti = t & 7;
  #pragma unroll
  for (int j = 0; j < 18; ++j) {
    int c4 = j * 8 + ti;
    *(f32x4*)&fmS[tr][c4 * 4] = *(const f32x4*)(src + (size_t)tr * 576 + c4 * 4);
  }
  __syncthreads();
  #pragma unroll
  for (int pass = 0; pass < 2; ++pass) {
    const int n = pass * 256 + t;
    const int pidx = b * 512 + n;
    float p0 = pts[(size_t)pidx * 2], p1 = pts[(size_t)pidx * 2 + 1];
    float gy = p0 * 23.f, gx = p1 * 23.f;
    float y0f = floorf(gy), x0f = floorf(gx);
    float wy = gy - y0f, wx = gx - x0f;
    int y0 = (int)y0f; y0 = y0 < 0 ? 0 : (y0 > 23 ? 23 : y0);
    int x0 = (int)x0f; x0 = x0 < 0 ? 0 : (x0 > 23 ? 23 : x0);
    int y1 = y0 + 1 > 23 ? 23 : y0 + 1;
    int x1 = x0 + 1 > 23 ? 23 : x0 + 1;
    float w00 = (1.f - wy) * (1.f - wx), w01 = (1.f - wy) * wx;
    float w10 = wy * (1.f - wx), w11 = wy * wx;
    const int i00 = y0 * 24 + x0, i01 = y0 * 24 + x1;
    const int i10 = y1 * 24 + x0, i11 = y1 * 24 + x1;
    size_t ro = (size_t)pidx * KP + ct * 32;
    #pragma unroll
    for (int cq = 0; cq < 8; ++cq) {
      u16x4 o4;
      #pragma unroll
      for (int cc = 0; cc < 4; ++cc) {
        int c = cq * 4 + cc;
        float v = w00 * fmS[c][i00] + w01 * fmS[c][i01] +
                  w10 * fmS[c][i10] + w11 * fmS[c][i11];
        o4[cc] = f2bf(v);
      }
      *(u16x4*)(X + ro + cq * 4) = o4;
    }
    if (ct == 31) {
      size_t rb = (size_t)pidx * KP;
      X[rb + 1024] = f2bf(p0);
      X[rb + 1025] = f2bf(p1);
      #pragma unroll
      for (int z = 0; z < 15; ++z) ((u32*)(X + rb + 1026))[z] = 0;
    }
  }
}

// ---------------- gather X rows at fi; emit new_pts -------------------------
__global__ __launch_bounds__(128) void gather_fi_kernel(const u16* __restrict__ Xsrc,
                                                        const float* __restrict__ pts,
                                                        const int* __restrict__ fi,
                                                        u16* __restrict__ Xg,
                                                        float* __restrict__ npts,
                                                        int Np, int S) {
  int q = blockIdx.x;
  int b = q / S;
  int t = threadIdx.x;
  int r = fi[q];
  const u32x4* src = (const u32x4*)(Xsrc + ((size_t)b * Np + r) * KP);
  u32x4* dst = (u32x4*)(Xg + (size_t)q * KP);
  dst[t] = src[t];
  int t2 = t + 128;
  if (t2 < 132) dst[t2] = src[t2];
  if (t == 0) {
    npts[(size_t)q * 2] = pts[((size_t)b * Np + r) * 2];
    npts[(size_t)q * 2 + 1] = pts[((size_t)b * Np + r) * 2 + 1];
  }
}

// ---------------- weight prep ----------------------------------------------
__global__ __launch_bounds__(256) void wd_transpose_kernel(const float* __restrict__ Wd,
                                                           u16* __restrict__ WdT) {
  __shared__ float tbuf[32][33];
  int tx = threadIdx.x & 31, ty = threadIdx.x >> 5;
  int ot = blockIdx.x * 32, dt = blockIdx.y * 32;
  #pragma unroll
  for (int j = 0; j < 4; ++j) {
    int o = ot + ty + 8 * j, d = dt + tx;
    tbuf[ty + 8 * j][tx] = (o < 1026 && d < 1026) ? Wd[(size_t)o * 1026 + d] : 0.f;
  }
  __syncthreads();
  #pragma unroll
  for (int j = 0; j < 4; ++j) {
    int d = dt + ty + 8 * j, o = ot + tx;
    if (o < KP) WdT[(size_t)d * KP + o] = f2bf(tbuf[tx][ty + 8 * j]);
  }
}

__global__ __launch_bounds__(256) void wagg_convert_kernel(const float* __restrict__ Wagg,
                                                           u16* __restrict__ Wa1,
                                                           u16* __restrict__ Wa2) {
  int c = blockIdx.x, t = threadIdx.x;
  const float* row = Wagg + (size_t)c * 2052;
  for (int d = t; d < KP; d += 256) {
    Wa1[(size_t)c * KP + d] = (d < 1026) ? f2bf(row[d]) : (u16)0;
    Wa2[(size_t)c * KP + d] = (d < 1026) ? f2bf(row[1026 + d]) : (u16)0;
  }
}

__global__ __launch_bounds__(256) void czero_kernel(const float* __restrict__ bdiff,
                                                    const float* __restrict__ Wagg,
                                                    const float* __restrict__ bagg,
                                                    float* __restrict__ czero) {
  int lane = threadIdx.x & 63, wv = threadIdx.x >> 6;
  int c = blockIdx.x * 4 + wv;
  float acc = 0.f;
  for (int o = lane; o < 1026; o += 64) acc += bdiff[o] * Wagg[(size_t)c * 2052 + o];
  #pragma unroll
  for (int off = 32; off; off >>= 1) acc += __shfl_xor(acc, off);
  if (lane == 0) czero[c] = acc + bagg[c];
}

// ---------------- bf16 MFMA GEMM: C[M,N] = A[M,K] @ Bt[N,K]^T ---------------
// FPS_PPL>0: y==0 row runs fps_core segment [fs0,fs1).
// KNN_PPL>0: rows y>=kYoff run knn_core (kb*4+wv -> q).
// SWZ: XCD-bijective tile remap (needs gridDim.x==8, MT%8==0).
// LDS: both-sides XOR swizzle on 16B slots -- global source col8 is
// pre-permuted (c8 = slot ^ x(row)), LDS dest linear (global_load_lds),
// read uses slot = quad ^ x(row); x(r) = (r&3)^((r>>2)&3).
template <int BF16OUT, int FPS_PPL, int FPS_HS, int SWZ, int KNN_PPL>
__global__ __launch_bounds__(256) void gemm_bt_kernel(const u16* __restrict__ A,
                                                      const u16* __restrict__ Bt,
                                                      void* __restrict__ Cout,
                                                      int M, int N, int K, int ldc, int nvalid,
                                                      const float* __restrict__ fpts,
                                                      int* __restrict__ ffi,
                                                      int fNp, int fS, int fs0, int fs1,
                                                      float* __restrict__ fdist,
                                                      int* __restrict__ ffar,
                                                      const float* __restrict__ kq,
                                                      const float* __restrict__ kr,
                                                      int* __restrict__ kidx,
                                                      int kNp, int kS, int kYoff) {
  const int tid = threadIdx.x;
  const int lane = tid & 63;
  const int wv = tid >> 6;
  const int FR = (FPS_PPL > 0) ? 1 : 0;
  if (FPS_PPL > 0 && blockIdx.y == 0) {
    if (blockIdx.x < 8)
      fps_core<FPS_PPL ? FPS_PPL : 1, FPS_HS>(fpts, ffi, fNp, fS,
                                              blockIdx.x * 4 + wv, lane, fs0, fs1,
                                              fdist, ffar);
    return;
  }
  if (KNN_PPL > 0 && (int)blockIdx.y >= kYoff) {
    int kb = ((int)blockIdx.y - kYoff) * gridDim.x + blockIdx.x;
    knn_core<KNN_PPL ? KNN_PPL : 1>(kq, kr, kidx, kNp, kS, kb * 4 + wv, lane);
    return;
  }
  __shared__ __align__(16) u16 As[128 * 32];
  __shared__ __align__(16) u16 Bs[128 * 32];
  int mt, nt;
  if (SWZ) {
    const int g = ((int)blockIdx.y - FR) * gridDim.x + blockIdx.x;
    const int MT = (KNN_PPL > 0 ? kYoff : (int)gridDim.y) - FR;
    const int cpx = MT >> 3;
    const int xcd = g & 7;
    const int r = g >> 3;
    mt = xcd * cpx + (r >> 3);
    nt = r & 7;
  } else {
    mt = (int)blockIdx.y - FR;
    nt = blockIdx.x;
  }
  const int m0 = mt * 128;
  const int n0 = nt * 128;
  const int wm = (wv >> 1) * 64;
  const int wn = (wv & 1) * 64;

  f32x4 acc[4][4];
  #pragma unroll
  for (int i = 0; i < 4; ++i)
    #pragma unroll
    for (int j = 0; j < 4; ++j)
      #pragma unroll
      for (int c = 0; c < 4; ++c) acc[i][j][c] = 0.f;

  const int ch0 = wv * 2;
  const int rin = lane >> 2;
  const int slot = lane & 3;
  const int cin = (slot ^ (rin & 3) ^ ((rin >> 2) & 3)) * 8;  // pre-swizzled src col

  for (int k0 = 0; k0 < K; k0 += 32) {
    #pragma unroll
    for (int i = 0; i < 2; ++i) {
      const int ch = ch0 + i;
      const int row = ch * 16 + rin;
      const u16* ga = A + (size_t)(m0 + row) * K + (k0 + cin);
      const u16* gb = Bt + (size_t)(n0 + row) * K + (k0 + cin);
      __builtin_amdgcn_global_load_lds((gvp)ga, (svp)(As + ch * 512), 16, 0, 0);
      __builtin_amdgcn_global_load_lds((gvp)gb, (svp)(Bs + ch * 512), 16, 0, 0);
    }
    __syncthreads();
    const int rf = lane & 15;
    const int quad = lane >> 4;
    const int qs = (quad ^ (rf & 3) ^ ((rf >> 2) & 3)) * 8;  // swizzled read slot
    bf16x8 af[4], bfv[4];
    #pragma unroll
    for (int mi = 0; mi < 4; ++mi)
      af[mi] = *(const bf16x8*)(As + (wm + mi * 16 + rf) * 32 + qs);
    #pragma unroll
    for (int ni = 0; ni < 4; ++ni)
      bfv[ni] = *(const bf16x8*)(Bs + (wn + ni * 16 + rf) * 32 + qs);
    #pragma unroll
    for (int mi = 0; mi < 4; ++mi)
      #pragma unroll
      for (int ni = 0; ni < 4; ++ni)
        acc[mi][ni] = __builtin_amdgcn_mfma_f32_16x16x32_bf16(af[mi], bfv[ni], acc[mi][ni], 0, 0, 0);
    __syncthreads();
  }

  const int rq = (lane >> 4) * 4;
  const int cf = lane & 15;
  #pragma unroll
  for (int mi = 0; mi < 4; ++mi) {
    #pragma unroll
    for (int ni = 0; ni < 4; ++ni) {
      const int col = n0 + wn + ni * 16 + cf;
      #pragma unroll
      for (int r = 0; r < 4; ++r) {
        const int row = m0 + wm + mi * 16 + rq + r;
        const float v = acc[mi][ni][r];
        if (BF16OUT) {
          if (col < nvalid) ((u16*)Cout)[(size_t)row * ldc + col] = f2bf(v);
        } else {
          ((float*)Cout)[(size_t)row * ldc + col] = v;
        }
      }
    }
  }
}

// ---------------- fused gather + relu + LN + mean_k -------------------------
// Wave-per-q, DPP add-scan LN, XCD-bijective swizzle. FPS_PPL>0: first 8
// blocks run fps_core (full range, no state spill).
template <int MODE, int FPS_PPL, int FPS_HS>
__global__ __launch_bounds__(256) void h_epilogue_kernel(const float* __restrict__ Z1,
                                                         const float* __restrict__ Z2g,
                                                         const float* __restrict__ czero,
                                                         const int* __restrict__ idxK,
                                                         const int* __restrict__ fi,
                                                         const float* __restrict__ g,
                                                         const float* __restrict__ bb,
                                                         const float* __restrict__ npts,
                                                         void* __restrict__ outp,
                                                         int Np, int S, int cpx,
                                                         const float* __restrict__ fpts,
                                                         int* __restrict__ ffi,
                                                         int fNp, int fS) {
  const int t = threadIdx.x;
  const int lane = t & 63, wv = t >> 6;
  if (FPS_PPL > 0 && blockIdx.x < 8) {
    fps_core<FPS_PPL ? FPS_PPL : 1, FPS_HS>(fpts, ffi, fNp, fS,
                                            blockIdx.x * 4 + wv, lane, 0, fS,
                                            nullptr, nullptr);
    return;
  }
  const int bid = blockIdx.x - (FPS_PPL > 0 ? 8 : 0);
  const int sw = (bid & 7) * cpx + (bid >> 3);  // XCD-contiguous q ranges
  const int q = sw * 4 + wv;
  const int b = q / S;
  const int fiv = fi[q];
  const float* z2 = Z2g + (size_t)q * 1024;
  const float* zf = Z1 + ((size_t)b * Np + fiv) * 1024;
  const int ch = lane * 4;  // + j*256

  f32x4 base[4], gv[4], bv[4], acc[4];
  #pragma unroll
  for (int j = 0; j < 4; ++j) {
    f32x4 a = *(const f32x4*)(z2 + j * 256 + ch);
    f32x4 c = *(const f32x4*)(czero + j * 256 + ch);
    f32x4 f = *(const f32x4*)(zf + j * 256 + ch);
    #pragma unroll
    for (int c2 = 0; c2 < 4; ++c2) base[j][c2] = a[c2] + c[c2] - f[c2];
    gv[j] = *(const f32x4*)(g + j * 256 + ch);
    bv[j] = *(const f32x4*)(bb + j * 256 + ch);
    #pragma unroll
    for (int c2 = 0; c2 < 4; ++c2) acc[j][c2] = 0.f;
  }
  int nk = 0;
  if (lane < 24) nk = idxK[(size_t)q * 24 + lane];

  for (int k = 0; k < 24; ++k) {
    const int n = __builtin_amdgcn_readlane(nk, k);
    const float* zr = Z1 + ((size_t)b * Np + n) * 1024;
    f32x4 v[4];
    float s1 = 0.f, s2 = 0.f;
    #pragma unroll
    for (int j = 0; j < 4; ++j) {
      f32x4 r = *(const f32x4*)(zr + j * 256 + ch);
      #pragma unroll
      for (int c2 = 0; c2 < 4; ++c2) {
        float x = fmaxf(r[c2] + base[j][c2], 0.f);
        v[j][c2] = x;
        s1 += x;
        s2 += x * x;
      }
    }
    s1 = wave_sum63(s1);
    s2 = wave_sum63(s2);
    const float S1 = rl_f(s1, 63);
    const float S2 = rl_f(s2, 63);
    const float m = S1 * (1.f / 1024.f);
    const float var = S2 * (1.f / 1024.f) - m * m;
    const float rs = rsqrtf(var + 1e-5f);
    #pragma unroll
    for (int j = 0; j < 4; ++j)
      #pragma unroll
      for (int c2 = 0; c2 < 4; ++c2)
        acc[j][c2] += (v[j][c2] - m) * rs * gv[j][c2] + bv[j][c2];
  }

  u16x4 o4[4];
  #pragma unroll
  for (int j = 0; j < 4; ++j)
    #pragma unroll
    for (int c2 = 0; c2 < 4; ++c2) o4[j][c2] = f2bf(acc[j][c2] * (1.f / 24.f));

  if (MODE == 0) {
    u16* X = (u16*)outp;
    size_t ro = (size_t)q * KP;
    #pragma unroll
    for (int j = 0; j < 4; ++j) *(u16x4*)(X + ro + j * 256 + ch) = o4[j];
    if (lane == 0) {
      X[ro + 1024] = f2bf(npts[(size_t)q * 2]);
      X[ro + 1025] = f2bf(npts[(size_t)q * 2 + 1]);
    }
    if (lane < 15) ((u32*)(X + ro + 1026))[lane] = 0;
  } else {
    u16* X = (u16*)outp + (size_t)q * 1024;
    #pragma unroll
    for (int j = 0; j < 4; ++j) *(u16x4*)(X + j * 256 + ch) = o4[j];
  }
}

// ---------------- MLP MFMA GEMM: P[blk] = W_tile(fp32->bf16) @ Fb^T ---------
template <int KSBITS, int NST>
__global__ __launch_bounds__(256, 4) void mlp_mfma_kernel(const float* __restrict__ W,
                                                          const u16* __restrict__ Fb,
                                                          float* __restrict__ P, int K) {
  __shared__ __align__(16) float Asf[128 * 32];
  __shared__ __align__(16) u16 Fsb[32 * 40];
  const int tid = threadIdx.x, lane = tid & 63, wv = tid >> 6;
  const int ot = blockIdx.x >> KSBITS;
  const int ks = blockIdx.x & ((1 << KSBITS) - 1);
  const int m0 = ot * 128;
  const int k0b = ks * (NST * 32);
  const int arow = lane >> 3;
  const int agrp = lane & 7;
  const int rf = lane & 15, quad = lane >> 4;

  f32x4 acc[2][2];
  #pragma unroll
  for (int i = 0; i < 2; ++i)
    #pragma unroll
    for (int j = 0; j < 2; ++j)
      #pragma unroll
      for (int c = 0; c < 4; ++c) acc[i][j][c] = 0.f;

  for (int st = 0; st < NST; ++st) {
    const int k0 = k0b + st * 32;
    #pragma unroll
    for (int i = 0; i < 4; ++i) {
      const int row = wv * 32 + i * 8 + arow;
      const int g = agrp ^ (row & 7);
      const float* ga = W + (size_t)(m0 + row) * K + k0 + g * 4;
      __builtin_amdgcn_global_load_lds((gvp)ga, (svp)(Asf + (wv * 32 + i * 8) * 32), 16, 0, 0);
    }
    if (tid < 128) {
      const int fr = tid >> 2, fc = (tid & 3) * 8;
      u32x4 tmp = *(const u32x4*)(Fb + (size_t)fr * K + k0 + fc);
      *(u32x4*)(Fsb + fr * 40 + fc) = tmp;
    }
    __syncthreads();
    bf16x8 bfr[2];
    #pragma unroll
    for (int ni = 0; ni < 2; ++ni)
      bfr[ni] = *(const bf16x8*)(Fsb + (ni * 16 + rf) * 40 + quad * 8);
    #pragma unroll
    for (int mi = 0; mi < 2; ++mi) {
      const float* ap = Asf + (size_t)(wv * 32 + mi * 16 + rf) * 32;
      f32x4 a0 = *(const f32x4*)(ap + (((quad * 2) ^ (rf & 7)) * 4));
      f32x4 a1 = *(const f32x4*)(ap + (((quad * 2 + 1) ^ (rf & 7)) * 4));
      union { bf16x8 v; u16 h[8]; } af;
      #pragma unroll
      for (int c = 0; c < 4; ++c) { af.h[c] = f2bf(a0[c]); af.h[4 + c] = f2bf(a1[c]); }
      #pragma unroll
      for (int ni = 0; ni < 2; ++ni)
        acc[mi][ni] = __builtin_amdgcn_mfma_f32_16x16x32_bf16(af.v, bfr[ni], acc[mi][ni], 0, 0, 0);
    }
    __syncthreads();
  }

  float* Pb = P + (size_t)blockIdx.x * 4096;
  const int rq = (lane >> 4) * 4, cf = lane & 15;
  #pragma unroll
  for (int mi = 0; mi < 2; ++mi)
    #pragma unroll
    for (int ni = 0; ni < 2; ++ni)
      #pragma unroll
      for (int r = 0; r < 4; ++r)
        Pb[(wv * 32 + mi * 16 + rq + r) * 32 + ni * 16 + cf] = acc[mi][ni][r];
}

// ---------------- K-split partial reductions (bias fused) -------------------
__global__ __launch_bounds__(256) void reduce_flat_kernel(const float* __restrict__ P,
                                                          const float* __restrict__ bias,
                                                          u16* __restrict__ x1bf) {
  int idx = blockIdx.x * 256 + threadIdx.x;  // 32768
  int o = idx >> 5, b = idx & 31;
  float s = bias[o];
  const float* p = P + ((size_t)(o >> 7) * 64) * 4096 + (o & 127) * 32 + b;
  #pragma unroll 8
  for (int ks = 0; ks < 64; ++ks) s += p[(size_t)ks * 4096];
  x1bf[(size_t)b * 1024 + o] = f2bf(s);
}

__global__ __launch_bounds__(256) void reduce_dim_kernel(const float* __restrict__ P,
                                                         const float* __restrict__ bias,
                                                         float* __restrict__ out) {
  int idx = blockIdx.x * 256 + threadIdx.x;  // 131072
  int o = idx >> 5, b = idx & 31;
  float s = bias[o];
  const float* p = P + ((size_t)(o >> 7) * 8) * 4096 + (o & 127) * 32 + b;
  #pragma unroll
  for (int ks = 0; ks < 8; ++ks) s += p[(size_t)ks * 4096];
  out[(size_t)b * 4096 + o] = s;
}

// ---------------------------------------------------------------------------
extern "C" void kernel_launch(void* const* d_in, const int* in_sizes, int n_in,
                              void* d_out, int out_size, void* d_ws, size_t ws_size,
                              hipStream_t stream) {
  const float* fmap  = (const float*)d_in[0];
  const float* pts   = (const float*)d_in[1];
  const float* Wdiff = (const float*)d_in[2];
  const float* bdiff = (const float*)d_in[3];
  const float* Wagg  = (const float*)d_in[4];
  const float* bagg  = (const float*)d_in[5];
  const float* lng   = (const float*)d_in[6];
  const float* lnb   = (const float*)d_in[7];
  const float* Wflat = (const float*)d_in[8];
  const float* bflat = (const float*)d_in[9];
  const float* Wdim  = (const float*)d_in[10];
  const float* bdim  = (const float*)d_in[11];
  float* out = (float*)d_out;

  char* w = (char*)d_ws;
  size_t off = 0;
  auto alloc = [&](size_t n) { char* p = w + off; off += (n + 255) & ~(size_t)255; return p; };

  float* Z1    = (float*)alloc(16384ull * 1024 * 4);  // 67.1 MB
  float* Z2g   = (float*)alloc(4096ull * 1024 * 4);   // 16.8 MB
  u16* Xbf0  = (u16*)alloc(16384ull * KP * 2);
  u16* X1bf  = (u16*)alloc(4096ull * KP * 2);
  u16* Xg    = (u16*)alloc(4096ull * KP * 2);
  u16* WdT   = (u16*)alloc((size_t)NP0 * KP * 2);
  u16* Wa1   = (u16*)alloc(1024ull * KP * 2);
  u16* Wa2   = (u16*)alloc(1024ull * KP * 2);
  u16* Wcomb = (u16*)alloc(1024ull * KP * 2);
  float* czero = (float*)alloc(1024 * 4);
  int* fi0   = (int*)alloc(32 * 128 * 4);
  int* fi1   = (int*)alloc(32 * 32 * 4);
  int* idx0  = (int*)alloc(32 * 128 * 24 * 4);
  int* idx1  = (int*)alloc(32 * 32 * 24 * 4);
  float* npts0 = (float*)alloc(32 * 128 * 2 * 4);
  float* npts1 = (float*)alloc(32 * 32 * 2 * 4);
  u16* fea2bf = (u16*)alloc(32ull * 32768 * 2);       // 2 MB bf16
  u16* x1bf   = (u16*)alloc(32ull * 1024 * 2);        // 64 KB bf16
  float* Pf   = (float*)alloc(512ull * 4096 * 4);     // 8 MB partials (flat)
  float* Pd   = (float*)alloc(256ull * 4096 * 4);     // 4 MB partials (dim)
  float* fdist = (float*)alloc(32ull * 512 * 4);      // fps0 dist state
  int* ffar    = (int*)alloc(32 * 4);                 // fps0 far state

  // ---- stage-0 inputs + fps0 segment [0,48) fused into bilinear (y==0 row)
  bilinear_fused_kernel<<<dim3(32, 33), 256, 0, stream>>>(fmap, pts, Xbf0, fi0, fdist, ffar);

  // ---- stage 0 (Np=512, S=128): weight prep, then Z1 GEMM with fps0
  //      segment [48,128) resumed in its y==0 row.
  wd_transpose_kernel<<<dim3(33, 36), 256, 0, stream>>>(Wdiff, WdT);
  wagg_convert_kernel<<<1024, 256, 0, stream>>>(Wagg, Wa1, Wa2);
  czero_kernel<<<256, 256, 0, stream>>>(bdiff, Wagg, bagg, czero);
  gemm_bt_kernel<1, 0, 1, 0, 0><<<dim3(9, 8), 256, 0, stream>>>(
      Wa1, WdT, Wcomb, 1024, NP0, KP, KP, KP,
      nullptr, nullptr, 0, 0, 0, 0, nullptr, nullptr,
      nullptr, nullptr, nullptr, 0, 0, 0);
  gemm_bt_kernel<0, 8, 2, 1, 0><<<dim3(8, 129), 256, 0, stream>>>(
      Xbf0, Wcomb, Z1, 16384, 1024, KP, 1024, 1024,
      pts, fi0, 512, 128, 48, 128, fdist, ffar,
      nullptr, nullptr, nullptr, 0, 0, 0);
  gather_fi_kernel<<<4096, 128, 0, stream>>>(Xbf0, pts, fi0, Xg, npts0, 512, 128);
  // Z2 GEMM (rows y<32) + knn0 (rows y in [32,160)) in one dispatch
  gemm_bt_kernel<0, 0, 1, 1, 8><<<dim3(8, 160), 256, 0, stream>>>(
      Xg, Wa2, Z2g, 4096, 1024, KP, 1024, 1024,
      nullptr, nullptr, 0, 0, 0, 0, nullptr, nullptr,
      npts0, pts, idx0, 512, 128, 32);
  // h_epilogue (q blocks) + fps1 full [0,32) (first 8 blocks)
  h_epilogue_kernel<0, 2, 1><<<1032, 256, 0, stream>>>(
      Z1, Z2g, czero, idx0, fi0, lng, lnb, npts0, X1bf, 512, 128, 128,
      npts0, fi1, 128, 32);

  // ---- stage 1 (Np=128, S=32)
  wd_transpose_kernel<<<dim3(33, 36), 256, 0, stream>>>(Wdiff + 1026 * 1026, WdT);
  wagg_convert_kernel<<<1024, 256, 0, stream>>>(Wagg + 1024 * 2052, Wa1, Wa2);
  czero_kernel<<<256, 256, 0, stream>>>(bdiff + 1026, Wagg + 1024 * 2052, bagg + 1024, czero);
  gemm_bt_kernel<1, 0, 1, 0, 0><<<dim3(9, 8), 256, 0, stream>>>(
      Wa1, WdT, Wcomb, 1024, NP0, KP, KP, KP,
      nullptr, nullptr, 0, 0, 0, 0, nullptr, nullptr,
      nullptr, nullptr, nullptr, 0, 0, 0);
  gemm_bt_kernel<0, 0, 1, 1, 0><<<dim3(8, 32), 256, 0, stream>>>(
      X1bf, Wcomb, Z1, 4096, 1024, KP, 1024, 1024,
      nullptr, nullptr, 0, 0, 0, 0, nullptr, nullptr,
      nullptr, nullptr, nullptr, 0, 0, 0);
  gather_fi_kernel<<<1024, 128, 0, stream>>>(X1bf, npts0, fi1, Xg, npts1, 128, 32);
  // Z2' GEMM (rows y<8) + knn1 (rows y in [8,40)) in one dispatch
  gemm_bt_kernel<0, 0, 1, 1, 2><<<dim3(8, 40), 256, 0, stream>>>(
      Xg, Wa2, Z2g, 1024, 1024, KP, 1024, 1024,
      nullptr, nullptr, 0, 0, 0, 0, nullptr, nullptr,
      npts1, npts0, idx1, 128, 32, 8);
  h_epilogue_kernel<1, 0, 1><<<256, 256, 0, stream>>>(
      Z1, Z2g, czero, idx1, fi1, lng + 1024, lnb + 1024, npts1, fea2bf, 128, 32, 32,
      nullptr, nullptr, 0, 0);

  // ---- final MLP (MFMA, K-split partials + reduce)
  mlp_mfma_kernel<6, 16><<<512, 256, 0, stream>>>(Wflat, fea2bf, Pf, 32768);
  reduce_flat_kernel<<<128, 256, 0, stream>>>(Pf, bflat, x1bf);
  mlp_mfma_kernel<3, 4><<<256, 256, 0, stream>>>(Wdim, x1bf, Pd, 1024);
  reduce_dim_kernel<<<512, 256, 0, stream>>>(Pd, bdim, out);
}

// Round 6
// 551.444 us; speedup vs baseline: 1.4769x; 1.1314x over previous
//
#include <hip/hip_runtime.h>

// ---------------------------------------------------------------------------
// GeoRegionSampler: restructured pipeline
//   X = [bilinear_fea | pts] (bf16, padded 1026->1056)
//   Wcomb = Wa1 @ Wd ; Z1 = X @ Wcomb^T ; Z2 = X[fi] @ Wa2^T (row-indirect)
//   h = relu(Z1[idx]-Z1[fi]+Z2+czero) -> LN -> mean_k (wave-per-q, DPP)
//   final MLP: MFMA GEMMs + K-split reduce.
// R10 (this round): schedule-level restructure, 24 -> 14 dispatches.
//   - fps0 split over THREE hosts: [0,32) bilinear, [32,56) wcomb_dual,
//     [56,128) Z1 GEMM -- each segment fits its host's GEMM shadow
//     (R4's 2-way split leaked ~10us; Z1 was fps-bound).
//   - stage-0 AND stage-1 weight prep merged: wd_transpose z-grid, fused
//     wagg+czero kernel (both stages), both Wcomb GEMMs in one dual
//     dispatch. Stage-1 prep leaves the critical path entirely.
//   - gather_fi DELETED: Z2 GEMMs read A rows via fi[] indirection (the
//     per-lane global source of global_load_lds is already a scatter);
//     npts emitted by fps_core (bit-exact pts copies).
//   - carried: both-sides LDS XOR swizzle, XCD-bijective tile remap,
//     wave-per-q DPP epilogue, knn fused into Z2 dispatches.
// ---------------------------------------------------------------------------

typedef float f32x4 __attribute__((ext_vector_type(4)));
typedef short bf16x8 __attribute__((ext_vector_type(8)));
typedef unsigned short u16;
typedef u16 u16x4 __attribute__((ext_vector_type(4)));
typedef unsigned int u32;
typedef u32 u32x4 __attribute__((ext_vector_type(4)));
typedef unsigned long long u64;

typedef const void __attribute__((address_space(1)))* gvp;
typedef void __attribute__((address_space(3)))* svp;

__device__ __forceinline__ u16 f2bf(float f) {
  union { float f; u32 u; } x; x.f = f;
  u32 r = x.u + 0x7fffu + ((x.u >> 16) & 1u);
  return (u16)(r >> 16);
}

#define KP 1056   // padded Dp (1026 -> 33*32)
#define NP0 1152  // padded N for weight-combine GEMM (9*128)

// ---- DPP cross-lane helpers (VALU pipe) -----------------------------------
__device__ __forceinline__ float rl_f(float v, int lane) {
  return __int_as_float(__builtin_amdgcn_readlane(__float_as_int(v), lane));
}

template <int CTRL>
__device__ __forceinline__ float dpp_fmax(float v) {
  float o = __int_as_float(__builtin_amdgcn_update_dpp(
      (int)0xff800000 /* -inf */, __float_as_int(v), CTRL, 0xf, 0xf, false));
  return fmaxf(v, o);
}

template <int CTRL>
__device__ __forceinline__ float dpp_fmin(float v) {
  float o = __int_as_float(__builtin_amdgcn_update_dpp(
      0x7f800000 /* +inf */, __float_as_int(v), CTRL, 0xf, 0xf, false));
  return fminf(v, o);
}

template <int CTRL>
__device__ __forceinline__ float dpp_add(float v) {
  float o = __int_as_float(__builtin_amdgcn_update_dpp(
      0, __float_as_int(v), CTRL, 0xf, 0xf, false));
  return v + o;
}

__device__ __forceinline__ float wave_fmax63(float v) {
  v = dpp_fmax<0x111>(v);
  v = dpp_fmax<0x112>(v);
  v = dpp_fmax<0x114>(v);
  v = dpp_fmax<0x118>(v);
  v = dpp_fmax<0x142>(v);
  v = dpp_fmax<0x143>(v);
  return rl_f(v, 63);
}

__device__ __forceinline__ float wave_fmin63(float v) {
  v = dpp_fmin<0x111>(v);
  v = dpp_fmin<0x112>(v);
  v = dpp_fmin<0x114>(v);
  v = dpp_fmin<0x118>(v);
  v = dpp_fmin<0x142>(v);
  v = dpp_fmin<0x143>(v);
  return rl_f(v, 63);
}

__device__ __forceinline__ float wave_sum63(float v) {
  v = dpp_add<0x111>(v);
  v = dpp_add<0x112>(v);
  v = dpp_add<0x114>(v);
  v = dpp_add<0x118>(v);
  v = dpp_add<0x142>(v);
  v = dpp_add<0x143>(v);
  return v;
}

// ---------------- FPS core: one wave per batch, bit-exact -------------------
// Resumable [s0,s1); dist/far state spilled as raw fp32 bits (exact).
// Emits fi AND npts (coords copied bit-exact from pts) for its own range.
template <int PPL, int HS>
__device__ void fps_core(const float* __restrict__ pts, int* __restrict__ fi,
                         float* __restrict__ npts,
                         int Np, int S, int b, int lane, int s0, int s1,
                         float* __restrict__ dsave, int* __restrict__ fsave) {
  #pragma clang fp contract(off)
  float px[PPL], py[PPL], dist[PPL];
  #pragma unroll
  for (int j = 0; j < PPL; ++j) {
    int n = j * 64 + lane;
    px[j] = pts[((size_t)b * Np + n) * 2];
    py[j] = pts[((size_t)b * Np + n) * 2 + 1];
  }
  int far; float cx, cy;
  if (s0 == 0) {
    #pragma unroll
    for (int j = 0; j < PPL; ++j) dist[j] = 1e10f;
    far = 0;
    cx = rl_f(px[0], 0);
    cy = rl_f(py[0], 0);
  } else {
    #pragma unroll
    for (int j = 0; j < PPL; ++j) dist[j] = dsave[(size_t)b * Np + j * 64 + lane];
    far = fsave[b];
    cx = pts[((size_t)b * Np + far) * 2];
    cy = pts[((size_t)b * Np + far) * 2 + 1];
  }
  int hist[HS];
  #pragma unroll
  for (int h = 0; h < HS; ++h) hist[h] = 0;
  for (int s = s0; s < s1; ++s) {
    #pragma unroll
    for (int h = 0; h < HS; ++h)
      if ((s >> 6) == h && (s & 63) == lane) hist[h] = far;
    float tv[PPL]; int ti[PPL]; float tx[PPL], ty[PPL];
    #pragma unroll
    for (int j = 0; j < PPL; ++j) {
      float dx = px[j] - cx, dy = py[j] - cy;
      float d = dx * dx + dy * dy;
      float nd = fminf(dist[j], d);
      dist[j] = nd;
      tv[j] = nd; ti[j] = j * 64 + lane; tx[j] = px[j]; ty[j] = py[j];
    }
    #pragma unroll
    for (int w = PPL; w > 1; w >>= 1)
      #pragma unroll
      for (int j = 0; j < (w >> 1); ++j)
        if (tv[j + (w >> 1)] > tv[j]) {
          tv[j] = tv[j + (w >> 1)]; ti[j] = ti[j + (w >> 1)];
          tx[j] = tx[j + (w >> 1)]; ty[j] = ty[j + (w >> 1)];
        }
    float smax = wave_fmax63(tv[0]);
    u64 mask = __ballot(tv[0] == smax);
    int L = __builtin_ctzll(mask);
    int fidx = __builtin_amdgcn_readlane(ti[0], L);
    float fx = rl_f(tx[0], L), fy = rl_f(ty[0], L);
    u64 rest = mask & (mask - 1);
    if (__builtin_expect(rest != 0, 0)) {
      while (rest) {
        int L2 = __builtin_ctzll(rest);
        int c = __builtin_amdgcn_readlane(ti[0], L2);
        if (c < fidx) {
          fidx = c; fx = rl_f(tx[0], L2); fy = rl_f(ty[0], L2);
        }
        rest &= rest - 1;
      }
    }
    far = fidx; cx = fx; cy = fy;
  }
  if (s1 < S) {
    #pragma unroll
    for (int j = 0; j < PPL; ++j) dsave[(size_t)b * Np + j * 64 + lane] = dist[j];
    if (lane == 0) fsave[b] = far;
  }
  #pragma unroll
  for (int h = 0; h < HS; ++h) {
    int s = h * 64 + lane;
    if (s >= s0 && s < s1) {
      int hv = hist[h];
      fi[b * S + s] = hv;
      npts[(size_t)(b * S + s) * 2]     = pts[((size_t)b * Np + hv) * 2];
      npts[(size_t)(b * S + s) * 2 + 1] = pts[((size_t)b * Np + hv) * 2 + 1];
    }
  }
}

// ---------------- kNN core: one wave per q, bit-exact -----------------------
template <int PPL>
__device__ void knn_core(const float* __restrict__ qpts,
                         const float* __restrict__ rpts,
                         int* __restrict__ idxK, int Np, int S, int q, int lane) {
  #pragma clang fp contract(off)
  int b = q / S;
  float ax = qpts[(size_t)q * 2], ay = qpts[(size_t)q * 2 + 1];
  float a2 = ax * ax + ay * ay;
  float d2[PPL];
  #pragma unroll
  for (int j = 0; j < PPL; ++j) {
    int n = j * 64 + lane;
    float bx = rpts[((size_t)b * Np + n) * 2];
    float by = rpts[((size_t)b * Np + n) * 2 + 1];
    float b2 = bx * bx + by * by;
    float dot = ax * bx + ay * by;
    float t = a2 + b2;
    float m2 = 2.f * dot;
    d2[j] = t - m2;
  }
  int kreg = 0;
  for (int k = 0; k < 24; ++k) {
    float tv[PPL]; int ti[PPL];
    #pragma unroll
    for (int j = 0; j < PPL; ++j) { tv[j] = d2[j]; ti[j] = j * 64 + lane; }
    #pragma unroll
    for (int w = PPL; w > 1; w >>= 1)
      #pragma unroll
      for (int j = 0; j < (w >> 1); ++j)
        if (tv[j + (w >> 1)] < tv[j]) {
          tv[j] = tv[j + (w >> 1)]; ti[j] = ti[j + (w >> 1)];
        }
    float smin = wave_fmin63(tv[0]);
    u64 mask = __ballot(tv[0] == smin);
    int L = __builtin_ctzll(mask);
    int bs = __builtin_amdgcn_readlane(ti[0], L);
    u64 rest = mask & (mask - 1);
    if (__builtin_expect(rest != 0, 0)) {
      while (rest) {
        int L2 = __builtin_ctzll(rest);
        int c = __builtin_amdgcn_readlane(ti[0], L2);
        if (c < bs) bs = c;
        rest &= rest - 1;
      }
    }
    if (lane == k) kreg = bs;
    #pragma unroll
    for (int j = 0; j < PPL; ++j)
      if (j * 64 + lane == bs) d2[j] = 3.4e38f;
  }
  if (lane < 24) idxK[(size_t)q * 24 + lane] = kreg;
}

// ---------------- GEMM tile body (shared by all MFMA GEMMs) -----------------
// IND: A rows indexed via find[] (q -> b*iNp + find[q]); C rows stay direct.
// LDS: both-sides XOR swizzle on 16B slots (linear dest for global_load_lds).
template <int BF16OUT, int IND>
__device__ __forceinline__ void gemm_tile_body(const u16* __restrict__ A,
                                               const u16* __restrict__ Bt,
                                               void* __restrict__ Cout,
                                               int K, int ldc, int nvalid,
                                               int m0, int n0,
                                               const int* __restrict__ find,
                                               int iNp, int iS,
                                               u16* __restrict__ As,
                                               u16* __restrict__ Bs) {
  const int tid = threadIdx.x;
  const int lane = tid & 63;
  const int wv = tid >> 6;
  const int wm = (wv >> 1) * 64;
  const int wn = (wv & 1) * 64;

  f32x4 acc[4][4];
  #pragma unroll
  for (int i = 0; i < 4; ++i)
    #pragma unroll
    for (int j = 0; j < 4; ++j)
      #pragma unroll
      for (int c = 0; c < 4; ++c) acc[i][j][c] = 0.f;

  const int ch0 = wv * 2;
  const int rin = lane >> 2;
  const int slot = lane & 3;
  const int cin = (slot ^ (rin & 3) ^ ((rin >> 2) & 3)) * 8;  // pre-swizzled src col

  size_t aro[2];
  #pragma unroll
  for (int i = 0; i < 2; ++i) {
    const int row = (ch0 + i) * 16 + rin;
    if (IND) {
      const int q = m0 + row;
      aro[i] = (size_t)(q / iS) * iNp + find[q];
    } else {
      aro[i] = (size_t)(m0 + row);
    }
  }

  for (int k0 = 0; k0 < K; k0 += 32) {
    #pragma unroll
    for (int i = 0; i < 2; ++i) {
      const int ch = ch0 + i;
      const int row = ch * 16 + rin;
      const u16* ga = A + aro[i] * K + (k0 + cin);
      const u16* gb = Bt + (size_t)(n0 + row) * K + (k0 + cin);
      __builtin_amdgcn_global_load_lds((gvp)ga, (svp)(As + ch * 512), 16, 0, 0);
      __builtin_amdgcn_global_load_lds((gvp)gb, (svp)(Bs + ch * 512), 16, 0, 0);
    }
    __syncthreads();
    const int rf = lane & 15;
    const int quad = lane >> 4;
    const int qs = (quad ^ (rf & 3) ^ ((rf >> 2) & 3)) * 8;  // swizzled read slot
    bf16x8 af[4], bfv[4];
    #pragma unroll
    for (int mi = 0; mi < 4; ++mi)
      af[mi] = *(const bf16x8*)(As + (wm + mi * 16 + rf) * 32 + qs);
    #pragma unroll
    for (int ni = 0; ni < 4; ++ni)
      bfv[ni] = *(const bf16x8*)(Bs + (wn + ni * 16 + rf) * 32 + qs);
    #pragma unroll
    for (int mi = 0; mi < 4; ++mi)
      #pragma unroll
      for (int ni = 0; ni < 4; ++ni)
        acc[mi][ni] = __builtin_amdgcn_mfma_f32_16x16x32_bf16(af[mi], bfv[ni], acc[mi][ni], 0, 0, 0);
    __syncthreads();
  }

  const int rq = (lane >> 4) * 4;
  const int cf = lane & 15;
  #pragma unroll
  for (int mi = 0; mi < 4; ++mi) {
    #pragma unroll
    for (int ni = 0; ni < 4; ++ni) {
      const int col = n0 + wn + ni * 16 + cf;
      #pragma unroll
      for (int r = 0; r < 4; ++r) {
        const int row = m0 + wm + mi * 16 + rq + r;
        const float v = acc[mi][ni][r];
        if (BF16OUT) {
          if (col < nvalid) ((u16*)Cout)[(size_t)row * ldc + col] = f2bf(v);
        } else {
          ((float*)Cout)[(size_t)row * ldc + col] = v;
        }
      }
    }
  }
}

// ------- fused bilinear + fps0 segment [0,32) (y==0 row) -------------------
__global__ __launch_bounds__(256, 2) void bilinear_fused_kernel(const float* __restrict__ fmap,
                                                                const float* __restrict__ pts,
                                                                u16* __restrict__ X,
                                                                int* __restrict__ fi0,
                                                                float* __restrict__ npts0,
                                                                float* __restrict__ fdist,
                                                                int* __restrict__ ffar) {
  if (blockIdx.y == 0) {
    if (blockIdx.x < 8)
      fps_core<8, 2>(pts, fi0, npts0, 512, 128, blockIdx.x * 4 + (threadIdx.x >> 6),
                     threadIdx.x & 63, 0, 32, fdist, ffar);
    return;
  }
  __shared__ float fmS[32][580];
  const int ct = blockIdx.x, b = blockIdx.y - 1;
  const int t = threadIdx.x;
  const float* src = fmap + ((size_t)b * 1024 + ct * 32) * 576;
  const int tr = t >> 3, ti = t & 7;
  #pragma unroll
  for (int j = 0; j < 18; ++j) {
    int c4 = j * 8 + ti;
    *(f32x4*)&fmS[tr][c4 * 4] = *(const f32x4*)(src + (size_t)tr * 576 + c4 * 4);
  }
  __syncthreads();
  #pragma unroll
  for (int pass = 0; pass < 2; ++pass) {
    const int n = pass * 256 + t;
    const int pidx = b * 512 + n;
    float p0 = pts[(size_t)pidx * 2], p1 = pts[(size_t)pidx * 2 + 1];
    float gy = p0 * 23.f, gx = p1 * 23.f;
    float y0f = floorf(gy), x0f = floorf(gx);
    float wy = gy - y0f, wx = gx - x0f;
    int y0 = (int)y0f; y0 = y0 < 0 ? 0 : (y0 > 23 ? 23 : y0);
    int x0 = (int)x0f; x0 = x0 < 0 ? 0 : (x0 > 23 ? 23 : x0);
    int y1 = y0 + 1 > 23 ? 23 : y0 + 1;
    int x1 = x0 + 1 > 23 ? 23 : x0 + 1;
    float w00 = (1.f - wy) * (1.f - wx), w01 = (1.f - wy) * wx;
    float w10 = wy * (1.f - wx), w11 = wy * wx;
    const int i00 = y0 * 24 + x0, i01 = y0 * 24 + x1;
    const int i10 = y1 * 24 + x0, i11 = y1 * 24 + x1;
    size_t ro = (size_t)pidx * KP + ct * 32;
    #pragma unroll
    for (int cq = 0; cq < 8; ++cq) {
      u16x4 o4;
      #pragma unroll
      for (int cc = 0; cc < 4; ++cc) {
        int c = cq * 4 + cc;
        float v = w00 * fmS[c][i00] + w01 * fmS[c][i01] +
                  w10 * fmS[c][i10] + w11 * fmS[c][i11];
        o4[cc] = f2bf(v);
      }
      *(u16x4*)(X + ro + cq * 4) = o4;
    }
    if (ct == 31) {
      size_t rb = (size_t)pidx * KP;
      X[rb + 1024] = f2bf(p0);
      X[rb + 1025] = f2bf(p1);
      #pragma unroll
      for (int z = 0; z < 15; ++z) ((u32*)(X + rb + 1026))[z] = 0;
    }
  }
}

// ---------------- weight prep: both stages in single dispatches -------------
__global__ __launch_bounds__(256) void wd_transpose_kernel(const float* __restrict__ Wd,
                                                           u16* __restrict__ WdT) {
  __shared__ float tbuf[32][33];
  const float* Wds = Wd + (size_t)blockIdx.z * 1026 * 1026;
  u16* WdTs = WdT + (size_t)blockIdx.z * NP0 * KP;
  int tx = threadIdx.x & 31, ty = threadIdx.x >> 5;
  int ot = blockIdx.x * 32, dt = blockIdx.y * 32;
  #pragma unroll
  for (int j = 0; j < 4; ++j) {
    int o = ot + ty + 8 * j, d = dt + tx;
    tbuf[ty + 8 * j][tx] = (o < 1026 && d < 1026) ? Wds[(size_t)o * 1026 + d] : 0.f;
  }
  __syncthreads();
  #pragma unroll
  for (int j = 0; j < 4; ++j) {
    int d = dt + ty + 8 * j, o = ot + tx;
    if (o < KP) WdTs[(size_t)d * KP + o] = f2bf(tbuf[tx][ty + 8 * j]);
  }
}

// wagg convert + czero reduction fused; both stages (2048 blocks).
__global__ __launch_bounds__(256) void waggcz_kernel(const float* __restrict__ Wagg,
                                                     const float* __restrict__ bdiff,
                                                     const float* __restrict__ bagg,
                                                     u16* __restrict__ Wa1,
                                                     u16* __restrict__ Wa2,
                                                     float* __restrict__ czero) {
  __shared__ float red[4];
  const int bid = blockIdx.x;
  const int stage = bid >> 10, c = bid & 1023;
  const float* row = Wagg + (size_t)stage * 1024 * 2052 + (size_t)c * 2052;
  const float* bd = bdiff + stage * 1026;
  u16* wa1 = Wa1 + (size_t)stage * 1024 * KP + (size_t)c * KP;
  u16* wa2 = Wa2 + (size_t)stage * 1024 * KP + (size_t)c * KP;
  const int t = threadIdx.x;
  float acc = 0.f;
  for (int d = t; d < KP; d += 256) {
    if (d < 1026) {
      float v1 = row[d];
      float v2 = row[1026 + d];
      wa1[d] = f2bf(v1);
      wa2[d] = f2bf(v2);
      acc += bd[d] * v1;
    } else {
      wa1[d] = 0;
      wa2[d] = 0;
    }
  }
  float s = wave_sum63(acc);
  const int lane = t & 63, wv = t >> 6;
  if (lane == 63) red[wv] = s;
  __syncthreads();
  if (t == 0)
    czero[(size_t)stage * 1024 + c] = red[0] + red[1] + red[2] + red[3] + bagg[stage * 1024 + c];
}

// Both Wcomb GEMMs (stage0 y in [1,8], stage1 y in [9,16]) + fps0 [32,56).
__global__ __launch_bounds__(256) void wcomb_dual_kernel(const u16* __restrict__ Wa1,
                                                         const u16* __restrict__ WdT,
                                                         u16* __restrict__ Wcomb,
                                                         const float* __restrict__ fpts,
                                                         int* __restrict__ ffi,
                                                         float* __restrict__ fnpts,
                                                         float* __restrict__ fdist,
                                                         int* __restrict__ ffar) {
  __shared__ __align__(16) u16 As[128 * 32];
  __shared__ __align__(16) u16 Bs[128 * 32];
  const int wv = threadIdx.x >> 6, lane = threadIdx.x & 63;
  if (blockIdx.y == 0) {
    if (blockIdx.x < 8)
      fps_core<8, 2>(fpts, ffi, fnpts, 512, 128, blockIdx.x * 4 + wv, lane, 32, 56,
                     fdist, ffar);
    return;
  }
  const int y = blockIdx.y - 1;
  const int stage = y >> 3;
  const int mt = y & 7;
  const u16* A = Wa1 + (size_t)stage * 1024 * KP;
  const u16* B = WdT + (size_t)stage * NP0 * KP;
  u16* C = Wcomb + (size_t)stage * 1024 * KP;
  gemm_tile_body<1, 0>(A, B, C, KP, KP, KP, mt * 128, blockIdx.x * 128,
                       nullptr, 0, 0, As, Bs);
}

// ---------------- general MFMA GEMM dispatch --------------------------------
// FPS_PPL>0: y==0 row runs fps_core segment [fs0,fs1).
// KNN_PPL>0: rows y>=kYoff run knn_core.
// SWZ: XCD-bijective tile remap. IND: A-row indirection via find[].
template <int BF16OUT, int FPS_PPL, int FPS_HS, int SWZ, int KNN_PPL, int IND>
__global__ __launch_bounds__(256) void gemm_bt_kernel(const u16* __restrict__ A,
                                                      const u16* __restrict__ Bt,
                                                      void* __restrict__ Cout,
                                                      int K, int ldc, int nvalid,
                                                      const int* __restrict__ find,
                                                      int iNp, int iS,
                                                      const float* __restrict__ fpts,
                                                      int* __restrict__ ffi,
                                                      float* __restrict__ fnpts,
                                                      int fNp, int fS, int fs0, int fs1,
                                                      float* __restrict__ fdist,
                                                      int* __restrict__ ffar,
                                                      const float* __restrict__ kq,
                                                      const float* __restrict__ kr,
                                                      int* __restrict__ kidx,
                                                      int kNp, int kS, int kYoff) {
  const int tid = threadIdx.x;
  const int lane = tid & 63;
  const int wv = tid >> 6;
  const int FR = (FPS_PPL > 0) ? 1 : 0;
  if (FPS_PPL > 0 && blockIdx.y == 0) {
    if (blockIdx.x < 8)
      fps_core<FPS_PPL ? FPS_PPL : 1, FPS_HS>(fpts, ffi, fnpts, fNp, fS,
                                              blockIdx.x * 4 + wv, lane, fs0, fs1,
                                              fdist, ffar);
    return;
  }
  if (KNN_PPL > 0 && (int)blockIdx.y >= kYoff) {
    int kb = ((int)blockIdx.y - kYoff) * gridDim.x + blockIdx.x;
    knn_core<KNN_PPL ? KNN_PPL : 1>(kq, kr, kidx, kNp, kS, kb * 4 + wv, lane);
    return;
  }
  __shared__ __align__(16) u16 As[128 * 32];
  __shared__ __align__(16) u16 Bs[128 * 32];
  int mt, nt;
  if (SWZ) {
    const int g = ((int)blockIdx.y - FR) * gridDim.x + blockIdx.x;
    const int MT = (KNN_PPL > 0 ? kYoff : (int)gridDim.y) - FR;
    const int cpx = MT >> 3;
    const int xcd = g & 7;
    const int r = g >> 3;
    mt = xcd * cpx + (r >> 3);
    nt = r & 7;
  } else {
    mt = (int)blockIdx.y - FR;
    nt = blockIdx.x;
  }
  gemm_tile_body<BF16OUT, IND>(A, Bt, Cout, K, ldc, nvalid, mt * 128, nt * 128,
                               find, iNp, iS, As, Bs);
}

// ---------------- fused gather + relu + LN + mean_k -------------------------
// Wave-per-q, DPP add-scan LN, XCD-bijective swizzle. FPS_PPL>0: first 8
// blocks run fps_core (full range).
template <int MODE, int FPS_PPL, int FPS_HS>
__global__ __launch_bounds__(256) void h_epilogue_kernel(const float* __restrict__ Z1,
                                                         const float* __restrict__ Z2g,
                                                         const float* __restrict__ czero,
                                                         const int* __restrict__ idxK,
                                                         const int* __restrict__ fi,
                                                         const float* __restrict__ g,
                                                         const float* __restrict__ bb,
                                                         const float* __restrict__ npts,
                                                         void* __restrict__ outp,
                                                         int Np, int S, int cpx,
                                                         const float* __restrict__ fpts,
                                                         int* __restrict__ ffi,
                                                         float* __restrict__ fnpts,
                                                         int fNp, int fS) {
  const int t = threadIdx.x;
  const int lane = t & 63, wv = t >> 6;
  if (FPS_PPL > 0 && blockIdx.x < 8) {
    fps_core<FPS_PPL ? FPS_PPL : 1, FPS_HS>(fpts, ffi, fnpts, fNp, fS,
                                            blockIdx.x * 4 + wv, lane, 0, fS,
                                            nullptr, nullptr);
    return;
  }
  const int bid = blockIdx.x - (FPS_PPL > 0 ? 8 : 0);
  const int sw = (bid & 7) * cpx + (bid >> 3);  // XCD-contiguous q ranges
  const int q = sw * 4 + wv;
  const int b = q / S;
  const int fiv = fi[q];
  const float* z2 = Z2g + (size_t)q * 1024;
  const float* zf = Z1 + ((size_t)b * Np + fiv) * 1024;
  const int ch = lane * 4;  // + j*256

  f32x4 base[4], gv[4], bv[4], acc[4];
  #pragma unroll
  for (int j = 0; j < 4; ++j) {
    f32x4 a = *(const f32x4*)(z2 + j * 256 + ch);
    f32x4 c = *(const f32x4*)(czero + j * 256 + ch);
    f32x4 f = *(const f32x4*)(zf + j * 256 + ch);
    #pragma unroll
    for (int c2 = 0; c2 < 4; ++c2) base[j][c2] = a[c2] + c[c2] - f[c2];
    gv[j] = *(const f32x4*)(g + j * 256 + ch);
    bv[j] = *(const f32x4*)(bb + j * 256 + ch);
    #pragma unroll
    for (int c2 = 0; c2 < 4; ++c2) acc[j][c2] = 0.f;
  }
  int nk = 0;
  if (lane < 24) nk = idxK[(size_t)q * 24 + lane];

  for (int k = 0; k < 24; ++k) {
    const int n = __builtin_amdgcn_readlane(nk, k);
    const float* zr = Z1 + ((size_t)b * Np + n) * 1024;
    f32x4 v[4];
    float s1 = 0.f, s2 = 0.f;
    #pragma unroll
    for (int j = 0; j < 4; ++j) {
      f32x4 r = *(const f32x4*)(zr + j * 256 + ch);
      #pragma unroll
      for (int c2 = 0; c2 < 4; ++c2) {
        float x = fmaxf(r[c2] + base[j][c2], 0.f);
        v[j][c2] = x;
        s1 += x;
        s2 += x * x;
      }
    }
    s1 = wave_sum63(s1);
    s2 = wave_sum63(s2);
    const float S1 = rl_f(s1, 63);
    const float S2 = rl_f(s2, 63);
    const float m = S1 * (1.f / 1024.f);
    const float var = S2 * (1.f / 1024.f) - m * m;
    const float rs = rsqrtf(var + 1e-5f);
    #pragma unroll
    for (int j = 0; j < 4; ++j)
      #pragma unroll
      for (int c2 = 0; c2 < 4; ++c2)
        acc[j][c2] += (v[j][c2] - m) * rs * gv[j][c2] + bv[j][c2];
  }

  u16x4 o4[4];
  #pragma unroll
  for (int j = 0; j < 4; ++j)
    #pragma unroll
    for (int c2 = 0; c2 < 4; ++c2) o4[j][c2] = f2bf(acc[j][c2] * (1.f / 24.f));

  if (MODE == 0) {
    u16* X = (u16*)outp;
    size_t ro = (size_t)q * KP;
    #pragma unroll
    for (int j = 0; j < 4; ++j) *(u16x4*)(X + ro + j * 256 + ch) = o4[j];
    if (lane == 0) {
      X[ro + 1024] = f2bf(npts[(size_t)q * 2]);
      X[ro + 1025] = f2bf(npts[(size_t)q * 2 + 1]);
    }
    if (lane < 15) ((u32*)(X + ro + 1026))[lane] = 0;
  } else {
    u16* X = (u16*)outp + (size_t)q * 1024;
    #pragma unroll
    for (int j = 0; j < 4; ++j) *(u16x4*)(X + j * 256 + ch) = o4[j];
  }
}

// ---------------- MLP MFMA GEMM: P[blk] = W_tile(fp32->bf16) @ Fb^T ---------
template <int KSBITS, int NST>
__global__ __launch_bounds__(256, 4) void mlp_mfma_kernel(const float* __restrict__ W,
                                                          const u16* __restrict__ Fb,
                                                          float* __restrict__ P, int K) {
  __shared__ __align__(16) float Asf[128 * 32];
  __shared__ __align__(16) u16 Fsb[32 * 40];
  const int tid = threadIdx.x, lane = tid & 63, wv = tid >> 6;
  const int ot = blockIdx.x >> KSBITS;
  const int ks = blockIdx.x & ((1 << KSBITS) - 1);
  const int m0 = ot * 128;
  const int k0b = ks * (NST * 32);
  const int arow = lane >> 3;
  const int agrp = lane & 7;
  const int rf = lane & 15, quad = lane >> 4;

  f32x4 acc[2][2];
  #pragma unroll
  for (int i = 0; i < 2; ++i)
    #pragma unroll
    for (int j = 0; j < 2; ++j)
      #pragma unroll
      for (int c = 0; c < 4; ++c) acc[i][j][c] = 0.f;

  for (int st = 0; st < NST; ++st) {
    const int k0 = k0b + st * 32;
    #pragma unroll
    for (int i = 0; i < 4; ++i) {
      const int row = wv * 32 + i * 8 + arow;
      const int g = agrp ^ (row & 7);
      const float* ga = W + (size_t)(m0 + row) * K + k0 + g * 4;
      __builtin_amdgcn_global_load_lds((gvp)ga, (svp)(Asf + (wv * 32 + i * 8) * 32), 16, 0, 0);
    }
    if (tid < 128) {
      const int fr = tid >> 2, fc = (tid & 3) * 8;
      u32x4 tmp = *(const u32x4*)(Fb + (size_t)fr * K + k0 + fc);
      *(u32x4*)(Fsb + fr * 40 + fc) = tmp;
    }
    __syncthreads();
    bf16x8 bfr[2];
    #pragma unroll
    for (int ni = 0; ni < 2; ++ni)
      bfr[ni] = *(const bf16x8*)(Fsb + (ni * 16 + rf) * 40 + quad * 8);
    #pragma unroll
    for (int mi = 0; mi < 2; ++mi) {
      const float* ap = Asf + (size_t)(wv * 32 + mi * 16 + rf) * 32;
      f32x4 a0 = *(const f32x4*)(ap + (((quad * 2) ^ (rf & 7)) * 4));
      f32x4 a1 = *(const f32x4*)(ap + (((quad * 2 + 1) ^ (rf & 7)) * 4));
      union { bf16x8 v; u16 h[8]; } af;
      #pragma unroll
      for (int c = 0; c < 4; ++c) { af.h[c] = f2bf(a0[c]); af.h[4 + c] = f2bf(a1[c]); }
      #pragma unroll
      for (int ni = 0; ni < 2; ++ni)
        acc[mi][ni] = __builtin_amdgcn_mfma_f32_16x16x32_bf16(af.v, bfr[ni], acc[mi][ni], 0, 0, 0);
    }
    __syncthreads();
  }

  float* Pb = P + (size_t)blockIdx.x * 4096;
  const int rq = (lane >> 4) * 4, cf = lane & 15;
  #pragma unroll
  for (int mi = 0; mi < 2; ++mi)
    #pragma unroll
    for (int ni = 0; ni < 2; ++ni)
      #pragma unroll
      for (int r = 0; r < 4; ++r)
        Pb[(wv * 32 + mi * 16 + rq + r) * 32 + ni * 16 + cf] = acc[mi][ni][r];
}

// ---------------- K-split partial reductions (bias fused) -------------------
__global__ __launch_bounds__(256) void reduce_flat_kernel(const float* __restrict__ P,
                                                          const float* __restrict__ bias,
                                                          u16* __restrict__ x1bf) {
  int idx = blockIdx.x * 256 + threadIdx.x;  // 32768
  int o = idx >> 5, b = idx & 31;
  float s = bias[o];
  const float* p = P + ((size_t)(o >> 7) * 64) * 4096 + (o & 127) * 32 + b;
  #pragma unroll 8
  for (int ks = 0; ks < 64; ++ks) s += p[(size_t)ks * 4096];
  x1bf[(size_t)b * 1024 + o] = f2bf(s);
}

__global__ __launch_bounds__(256) void reduce_dim_kernel(const float* __restrict__ P,
                                                         const float* __restrict__ bias,
                                                         float* __restrict__ out) {
  int idx = blockIdx.x * 256 + threadIdx.x;  // 131072
  int o = idx >> 5, b = idx & 31;
  float s = bias[o];
  const float* p = P + ((size_t)(o >> 7) * 8) * 4096 + (o & 127) * 32 + b;
  #pragma unroll
  for (int ks = 0; ks < 8; ++ks) s += p[(size_t)ks * 4096];
  out[(size_t)b * 4096 + o] = s;
}

// ---------------------------------------------------------------------------
extern "C" void kernel_launch(void* const* d_in, const int* in_sizes, int n_in,
                              void* d_out, int out_size, void* d_ws, size_t ws_size,
                              hipStream_t stream) {
  const float* fmap  = (const float*)d_in[0];
  const float* pts   = (const float*)d_in[1];
  const float* Wdiff = (const float*)d_in[2];
  const float* bdiff = (const float*)d_in[3];
  const float* Wagg  = (const float*)d_in[4];
  const float* bagg  = (const float*)d_in[5];
  const float* lng   = (const float*)d_in[6];
  const float* lnb   = (const float*)d_in[7];
  const float* Wflat = (const float*)d_in[8];
  const float* bflat = (const float*)d_in[9];
  const float* Wdim  = (const float*)d_in[10];
  const float* bdim  = (const float*)d_in[11];
  float* out = (float*)d_out;

  char* w = (char*)d_ws;
  size_t off = 0;
  auto alloc = [&](size_t n) { char* p = w + off; off += (n + 255) & ~(size_t)255; return p; };

  float* Z1    = (float*)alloc(16384ull * 1024 * 4);  // 67.1 MB
  float* Z2g   = (float*)alloc(4096ull * 1024 * 4);   // 16.8 MB
  u16* Xbf0  = (u16*)alloc(16384ull * KP * 2);
  u16* X1bf  = (u16*)alloc(4096ull * KP * 2);
  u16* WdT   = (u16*)alloc(2ull * NP0 * KP * 2);      // both stages
  u16* Wa1   = (u16*)alloc(2ull * 1024 * KP * 2);
  u16* Wa2   = (u16*)alloc(2ull * 1024 * KP * 2);
  u16* Wcomb = (u16*)alloc(2ull * 1024 * KP * 2);
  float* czero = (float*)alloc(2 * 1024 * 4);
  int* fi0   = (int*)alloc(32 * 128 * 4);
  int* fi1   = (int*)alloc(32 * 32 * 4);
  int* idx0  = (int*)alloc(32 * 128 * 24 * 4);
  int* idx1  = (int*)alloc(32 * 32 * 24 * 4);
  float* npts0 = (float*)alloc(32 * 128 * 2 * 4);
  float* npts1 = (float*)alloc(32 * 32 * 2 * 4);
  u16* fea2bf = (u16*)alloc(32ull * 32768 * 2);       // 2 MB bf16
  u16* x1bf   = (u16*)alloc(32ull * 1024 * 2);        // 64 KB bf16
  float* Pf   = (float*)alloc(512ull * 4096 * 4);     // 8 MB partials (flat)
  float* Pd   = (float*)alloc(256ull * 4096 * 4);     // 4 MB partials (dim)
  float* fdist = (float*)alloc(32ull * 512 * 4);      // fps0 dist state
  int* ffar    = (int*)alloc(32 * 4);                 // fps0 far state

  // D1: stage-0 inputs + fps0 [0,32)
  bilinear_fused_kernel<<<dim3(32, 33), 256, 0, stream>>>(fmap, pts, Xbf0, fi0, npts0,
                                                          fdist, ffar);
  // D2-D3: both stages' weight prep
  wd_transpose_kernel<<<dim3(33, 36, 2), 256, 0, stream>>>(Wdiff, WdT);
  waggcz_kernel<<<2048, 256, 0, stream>>>(Wagg, bdiff, bagg, Wa1, Wa2, czero);
  // D4: both Wcomb GEMMs + fps0 [32,56)
  wcomb_dual_kernel<<<dim3(9, 17), 256, 0, stream>>>(Wa1, WdT, Wcomb, pts, fi0, npts0,
                                                     fdist, ffar);
  // D5: Z1 (stage0) + fps0 [56,128)
  gemm_bt_kernel<0, 8, 2, 1, 0, 0><<<dim3(8, 129), 256, 0, stream>>>(
      Xbf0, Wcomb, Z1, KP, 1024, 1024,
      nullptr, 0, 0,
      pts, fi0, npts0, 512, 128, 56, 128, fdist, ffar,
      nullptr, nullptr, nullptr, 0, 0, 0);
  // D6: Z2 (A rows via fi0) + knn0
  gemm_bt_kernel<0, 0, 1, 1, 8, 1><<<dim3(8, 160), 256, 0, stream>>>(
      Xbf0, Wa2, Z2g, KP, 1024, 1024,
      fi0, 512, 128,
      nullptr, nullptr, nullptr, 0, 0, 0, 0, nullptr, nullptr,
      npts0, pts, idx0, 512, 128, 32);
  // D7: h_epilogue0 + fps1 full [0,32)
  h_epilogue_kernel<0, 2, 1><<<1032, 256, 0, stream>>>(
      Z1, Z2g, czero, idx0, fi0, lng, lnb, npts0, X1bf, 512, 128, 128,
      npts0, fi1, npts1, 128, 32);
  // D8: Z1' (stage1)
  gemm_bt_kernel<0, 0, 1, 1, 0, 0><<<dim3(8, 32), 256, 0, stream>>>(
      X1bf, Wcomb + 1024ull * KP, Z1, KP, 1024, 1024,
      nullptr, 0, 0,
      nullptr, nullptr, nullptr, 0, 0, 0, 0, nullptr, nullptr,
      nullptr, nullptr, nullptr, 0, 0, 0);
  // D9: Z2' (A rows via fi1) + knn1
  gemm_bt_kernel<0, 0, 1, 1, 2, 1><<<dim3(8, 40), 256, 0, stream>>>(
      X1bf, Wa2 + 1024ull * KP, Z2g, KP, 1024, 1024,
      fi1, 128, 32,
      nullptr, nullptr, nullptr, 0, 0, 0, 0, nullptr, nullptr,
      npts1, npts0, idx1, 128, 32, 8);
  // D10: h_epilogue1
  h_epilogue_kernel<1, 0, 1><<<256, 256, 0, stream>>>(
      Z1, Z2g, czero + 1024, idx1, fi1, lng + 1024, lnb + 1024, npts1, fea2bf,
      128, 32, 32, nullptr, nullptr, nullptr, 0, 0);

  // D11-14: final MLP (MFMA, K-split partials + reduce)
  mlp_mfma_kernel<6, 16><<<512, 256, 0, stream>>>(Wflat, fea2bf, Pf, 32768);
  reduce_flat_kernel<<<128, 256, 0, stream>>>(Pf, bflat, x1bf);
  mlp_mfma_kernel<3, 4><<<256, 256, 0, stream>>>(Wdim, x1bf, Pd, 1024);
  reduce_dim_kernel<<<512, 256, 0, stream>>>(Pd, bdim, out);
}